// Round 1
// baseline (696.503 us; speedup 1.0000x reference)
//
#include <hip/hip_runtime.h>
#include <math.h>

#define N_NODES 50000
#define N_EDGES 800000
#define EPS_F 1e-30f

__device__ __forceinline__ float silu_f(float x) {
    return x / (1.0f + __expf(-x));
}

// Computes a 64x64 output tile: out[i][j] (4x4 per thread) =
//   sum_k A[e][k] * B[k][j]   with e = (t>>4)*4+i, j = (t&15)*4+jj
// A: LDS, row stride astride. B: global, row stride 64.
template<int KDIM>
__device__ __forceinline__ void tile_gemm64(const float* __restrict__ A, int astride,
                                            const float* __restrict__ B,
                                            float acc[4][4], int t)
{
    const int tx = t & 15;
    const int ty = t >> 4;
#pragma unroll
    for (int i = 0; i < 4; ++i)
#pragma unroll
        for (int j = 0; j < 4; ++j) acc[i][j] = 0.0f;

    for (int k = 0; k < (KDIM & ~3); k += 4) {
        float bv[4][4];
#pragma unroll
        for (int kk = 0; kk < 4; ++kk) {
            float4 bq = *(const float4*)(B + (size_t)(k + kk) * 64 + tx * 4);
            bv[kk][0] = bq.x; bv[kk][1] = bq.y; bv[kk][2] = bq.z; bv[kk][3] = bq.w;
        }
#pragma unroll
        for (int i = 0; i < 4; ++i) {
            float4 aq = *(const float4*)(A + (size_t)(ty * 4 + i) * astride + k);
            float av[4] = {aq.x, aq.y, aq.z, aq.w};
#pragma unroll
            for (int kk = 0; kk < 4; ++kk)
#pragma unroll
                for (int j = 0; j < 4; ++j)
                    acc[i][j] = fmaf(av[kk], bv[kk][j], acc[i][j]);
        }
    }
    if (KDIM & 3) {  // remainder of exactly 1 (KDIM=129)
        const int k = KDIM & ~3;
        float4 bq = *(const float4*)(B + (size_t)k * 64 + tx * 4);
        float bv[4] = {bq.x, bq.y, bq.z, bq.w};
#pragma unroll
        for (int i = 0; i < 4; ++i) {
            float a = A[(size_t)(ty * 4 + i) * astride + k];
#pragma unroll
            for (int j = 0; j < 4; ++j)
                acc[i][j] = fmaf(a, bv[j], acc[i][j]);
        }
    }
}

__global__ __launch_bounds__(256, 2)
void egnn_edge_kernel(const float* __restrict__ node_feat,
                      const float* __restrict__ coord,
                      const int* __restrict__ src,
                      const int* __restrict__ dst,
                      const float* __restrict__ We1, const float* __restrict__ be1,
                      const float* __restrict__ We2, const float* __restrict__ be2,
                      const float* __restrict__ Wx1, const float* __restrict__ bx1,
                      const float* __restrict__ Wx2,
                      float* __restrict__ h_neigh,   // [N*64] accum
                      float* __restrict__ x_sum,     // [N*3]  accum
                      float* __restrict__ deg)       // [N]    accum
{
    __shared__ float sF[64][132];   // [h_src(64) | h_dst(64) | radial] padded
    __shared__ float sT[64][68];    // layer-1 activations
    __shared__ float sM[64][68];    // msg_h
    __shared__ float sXd[64][3];    // normalized x_diff
    __shared__ int   sDst[64];

    const int t = threadIdx.x;
    const int e0 = blockIdx.x * 64;   // E = 800000 = 12500*64, no tail

    // ---- gather node features: 4 threads per edge, 16 floats each side ----
    {
        const int e = t >> 2;
        const int sub = t & 3;
        const int gs = src[e0 + e];
        const int gd = dst[e0 + e];
        const float4* rs = (const float4*)(node_feat + (size_t)gs * 64);
        const float4* rd = (const float4*)(node_feat + (size_t)gd * 64);
#pragma unroll
        for (int q = 0; q < 4; ++q) {
            *(float4*)&sF[e][sub * 16 + 4 * q]      = rs[sub * 4 + q];
            *(float4*)&sF[e][64 + sub * 16 + 4 * q] = rd[sub * 4 + q];
        }
    }
    if (t < 64) {
        const int e = t;
        const int gs = src[e0 + e];
        const int gd = dst[e0 + e];
        float dx = coord[(size_t)gs * 3 + 0] - coord[(size_t)gd * 3 + 0];
        float dy = coord[(size_t)gs * 3 + 1] - coord[(size_t)gd * 3 + 1];
        float dz = coord[(size_t)gs * 3 + 2] - coord[(size_t)gd * 3 + 2];
        float radial = dx * dx + dy * dy + dz * dz;
        sF[e][128] = radial;
        float inv = 1.0f / (sqrtf(radial) + EPS_F);
        sXd[e][0] = dx * inv; sXd[e][1] = dy * inv; sXd[e][2] = dz * inv;
        sDst[e] = gd;
    }
    __syncthreads();

    const int tx = t & 15;
    const int ty = t >> 4;
    float acc[4][4];

    // ---- edge_mlp layer 1: [64,129] @ [129,64] + be1, SiLU ----
    tile_gemm64<129>(&sF[0][0], 132, We1, acc, t);
    {
        float4 bq = *(const float4*)(be1 + tx * 4);
        float bv[4] = {bq.x, bq.y, bq.z, bq.w};
#pragma unroll
        for (int i = 0; i < 4; ++i) {
            float4 o;
            o.x = silu_f(acc[i][0] + bv[0]);
            o.y = silu_f(acc[i][1] + bv[1]);
            o.z = silu_f(acc[i][2] + bv[2]);
            o.w = silu_f(acc[i][3] + bv[3]);
            *(float4*)&sT[ty * 4 + i][tx * 4] = o;
        }
    }
    __syncthreads();

    // ---- edge_mlp layer 2: [64,64] @ [64,64] + be2, SiLU -> msg_h ----
    tile_gemm64<64>(&sT[0][0], 68, We2, acc, t);
    {
        float4 bq = *(const float4*)(be2 + tx * 4);
        float bv[4] = {bq.x, bq.y, bq.z, bq.w};
#pragma unroll
        for (int i = 0; i < 4; ++i) {
            float4 o;
            o.x = silu_f(acc[i][0] + bv[0]);
            o.y = silu_f(acc[i][1] + bv[1]);
            o.z = silu_f(acc[i][2] + bv[2]);
            o.w = silu_f(acc[i][3] + bv[3]);
            *(float4*)&sM[ty * 4 + i][tx * 4] = o;
        }
    }
    __syncthreads();

    // ---- coord_mlp: SiLU(msg_h @ Wx1 + bx1) @ Wx2 -> coef per edge ----
    tile_gemm64<64>(&sM[0][0], 68, Wx1, acc, t);
    {
        float4 bq = *(const float4*)(bx1 + tx * 4);
        float bv[4] = {bq.x, bq.y, bq.z, bq.w};
        float4 wq = *(const float4*)(Wx2 + tx * 4);
        float wv[4] = {wq.x, wq.y, wq.z, wq.w};
        float p[4];
#pragma unroll
        for (int i = 0; i < 4; ++i) {
            float s = 0.0f;
#pragma unroll
            for (int j = 0; j < 4; ++j)
                s += silu_f(acc[i][j] + bv[j]) * wv[j];
            p[i] = s;
        }
        // reduce across the 16 tx lanes (lane bits 0..3)
#pragma unroll
        for (int off = 1; off < 16; off <<= 1) {
#pragma unroll
            for (int i = 0; i < 4; ++i)
                p[i] += __shfl_xor(p[i], off);
        }
        if (tx == 0) {
#pragma unroll
            for (int i = 0; i < 4; ++i) {
                const int e = ty * 4 + i;
                const int gd = sDst[e];
                const float coef = p[i];
                atomicAdd(&x_sum[(size_t)gd * 3 + 0], coef * sXd[e][0]);
                atomicAdd(&x_sum[(size_t)gd * 3 + 1], coef * sXd[e][1]);
                atomicAdd(&x_sum[(size_t)gd * 3 + 2], coef * sXd[e][2]);
                atomicAdd(&deg[gd], 1.0f);
            }
        }
    }

    // ---- scatter msg_h (coalesced: one wave covers one edge row) ----
    {
        const int j = t & 63;
        const int eoff = t >> 6;
        for (int eb = 0; eb < 64; eb += 4) {
            const int e = eb + eoff;
            atomicAdd(&h_neigh[(size_t)sDst[e] * 64 + j], sM[e][j]);
        }
    }
}

__global__ __launch_bounds__(256, 2)
void egnn_node_kernel(const float* __restrict__ node_feat,
                      const float* __restrict__ coord,
                      const float* __restrict__ Wn1, const float* __restrict__ bn1,
                      const float* __restrict__ Wn2, const float* __restrict__ bn2,
                      const float* __restrict__ h_neigh,
                      const float* __restrict__ x_sum,
                      const float* __restrict__ deg,
                      float* __restrict__ out_h,   // [N*64]
                      float* __restrict__ out_x)   // [N*3]
{
    __shared__ float sF[64][132];   // [node_feat(64) | h_neigh(64)]
    __shared__ float sT[64][68];

    const int t = threadIdx.x;
    const int n0 = blockIdx.x * 64;

    // ---- load [node_feat | h_neigh] rows (coalesced) ----
    {
        const int r = t >> 2;
        const int sub = t & 3;          // each sub loads 32 floats
        const int n = n0 + r;
        if (n < N_NODES) {
            const float* rowsrc = (sub < 2) ? (node_feat + (size_t)n * 64 + sub * 32)
                                            : (h_neigh  + (size_t)n * 64 + (sub - 2) * 32);
#pragma unroll
            for (int q = 0; q < 8; ++q)
                *(float4*)&sF[r][sub * 32 + 4 * q] = *(const float4*)(rowsrc + 4 * q);
        } else {
#pragma unroll
            for (int q = 0; q < 8; ++q)
                *(float4*)&sF[r][sub * 32 + 4 * q] = make_float4(0.f, 0.f, 0.f, 0.f);
        }
    }
    __syncthreads();

    const int tx = t & 15;
    const int ty = t >> 4;
    float acc[4][4];

    // ---- node_mlp layer 1 ----
    tile_gemm64<128>(&sF[0][0], 132, Wn1, acc, t);
    {
        float4 bq = *(const float4*)(bn1 + tx * 4);
        float bv[4] = {bq.x, bq.y, bq.z, bq.w};
#pragma unroll
        for (int i = 0; i < 4; ++i) {
            float4 o;
            o.x = silu_f(acc[i][0] + bv[0]);
            o.y = silu_f(acc[i][1] + bv[1]);
            o.z = silu_f(acc[i][2] + bv[2]);
            o.w = silu_f(acc[i][3] + bv[3]);
            *(float4*)&sT[ty * 4 + i][tx * 4] = o;
        }
    }
    __syncthreads();

    // ---- node_mlp layer 2 (no activation) + store h ----
    tile_gemm64<64>(&sT[0][0], 68, Wn2, acc, t);
    {
        float4 bq = *(const float4*)(bn2 + tx * 4);
        float bv[4] = {bq.x, bq.y, bq.z, bq.w};
#pragma unroll
        for (int i = 0; i < 4; ++i) {
            const int n = n0 + ty * 4 + i;
            if (n < N_NODES) {
                float4 o;
                o.x = acc[i][0] + bv[0];
                o.y = acc[i][1] + bv[1];
                o.z = acc[i][2] + bv[2];
                o.w = acc[i][3] + bv[3];
                *(float4*)&out_h[(size_t)n * 64 + tx * 4] = o;
            }
        }
    }

    // ---- coordinate update: x = coord + x_sum / max(deg,1) ----
    if (t < 64) {
        const int n = n0 + t;
        if (n < N_NODES) {
            const float d = deg[n];
            const float inv = 1.0f / fmaxf(d, 1.0f);
#pragma unroll
            for (int c = 0; c < 3; ++c)
                out_x[(size_t)n * 3 + c] = coord[(size_t)n * 3 + c]
                                         + x_sum[(size_t)n * 3 + c] * inv;
        }
    }
}

extern "C" void kernel_launch(void* const* d_in, const int* in_sizes, int n_in,
                              void* d_out, int out_size, void* d_ws, size_t ws_size,
                              hipStream_t stream) {
    const float* node_feat = (const float*)d_in[0];
    const float* coord     = (const float*)d_in[1];
    const int*   src       = (const int*)d_in[2];
    const int*   dst       = (const int*)d_in[3];
    const float* We1 = (const float*)d_in[4];
    const float* be1 = (const float*)d_in[5];
    const float* We2 = (const float*)d_in[6];
    const float* be2 = (const float*)d_in[7];
    const float* Wx1 = (const float*)d_in[8];
    const float* bx1 = (const float*)d_in[9];
    const float* Wx2 = (const float*)d_in[10];
    const float* Wn1 = (const float*)d_in[11];
    const float* bn1 = (const float*)d_in[12];
    const float* Wn2 = (const float*)d_in[13];
    const float* bn2 = (const float*)d_in[14];

    float* out_h = (float*)d_out;                       // [N,64]
    float* out_x = out_h + (size_t)N_NODES * 64;        // [N,3]

    float* h_neigh = (float*)d_ws;                      // [N,64]
    float* x_sum   = h_neigh + (size_t)N_NODES * 64;    // [N,3]
    float* deg     = x_sum + (size_t)N_NODES * 3;       // [N]

    const size_t zero_bytes = (size_t)N_NODES * 68 * sizeof(float);
    hipMemsetAsync(d_ws, 0, zero_bytes, stream);

    egnn_edge_kernel<<<N_EDGES / 64, 256, 0, stream>>>(
        node_feat, coord, src, dst,
        We1, be1, We2, be2, Wx1, bx1, Wx2,
        h_neigh, x_sum, deg);

    egnn_node_kernel<<<(N_NODES + 63) / 64, 256, 0, stream>>>(
        node_feat, coord, Wn1, bn1, Wn2, bn2,
        h_neigh, x_sum, deg, out_h, out_x);
}

// Round 2
// 505.862 us; speedup vs baseline: 1.3769x; 1.3769x over previous
//
#include <hip/hip_runtime.h>
#include <math.h>

#define N_NODES 50000
#define N_EDGES 800000
#define EPS_F 1e-30f

typedef __bf16 bf16x8 __attribute__((ext_vector_type(8)));
typedef __bf16 bf16x4 __attribute__((ext_vector_type(4)));
typedef float  f32x4  __attribute__((ext_vector_type(4)));

#define STR1 136   // sFb row stride in bf16 (272B, 16B-mult, banks spread)
#define STR2 72    // sT/sM row stride in bf16 (144B)

__device__ __forceinline__ float silu_f(float x) {
    return x / (1.0f + __expf(-x));
}

// ---------------- weight packing: W[k][n] f32 -> Wp[n][k] bf16 ----------------
__global__ void pack_weights(const float* __restrict__ We1,
                             const float* __restrict__ We2,
                             const float* __restrict__ Wx1,
                             __bf16* __restrict__ We1p,   // [64][128]
                             __bf16* __restrict__ We2p,   // [64][64]
                             __bf16* __restrict__ Wx1p)   // [64][64]
{
    const int t = blockIdx.x * 256 + threadIdx.x;
    for (int i = t; i < 64 * 128; i += gridDim.x * 256) {
        const int n = i >> 7, k = i & 127;
        We1p[i] = (__bf16)We1[k * 64 + n];
    }
    for (int i = t; i < 64 * 64; i += gridDim.x * 256) {
        const int n = i >> 6, k = i & 63;
        We2p[i] = (__bf16)We2[k * 64 + n];
        Wx1p[i] = (__bf16)Wx1[k * 64 + n];
    }
}

// ---------------- edge kernel: MFMA bf16 fused edge MLP + scatter ----------------
__global__ __launch_bounds__(256, 4)
void egnn_edge_mfma(const float* __restrict__ node_feat,
                    const float* __restrict__ coord,
                    const int* __restrict__ src,
                    const int* __restrict__ dst,
                    const float* __restrict__ We1,   // for row 128 (radial) f32
                    const float* __restrict__ be1,
                    const float* __restrict__ be2,
                    const float* __restrict__ bx1,
                    const float* __restrict__ Wx2,
                    const __bf16* __restrict__ We1p,
                    const __bf16* __restrict__ We2p,
                    const __bf16* __restrict__ Wx1p,
                    float* __restrict__ h_neigh,
                    float* __restrict__ x_sum,
                    float* __restrict__ deg)
{
    __shared__ __bf16 sFb[64 * STR1];   // [h_src(0:64) | h_dst(64:128)] bf16
    __shared__ __bf16 sT [64 * STR2];   // layer-1 activations
    __shared__ __bf16 sM [64 * STR2];   // msg_h (bf16 copy for layer-3 A)
    __shared__ float  sRad[64];
    __shared__ float  sXd[64][3];
    __shared__ int    sDst[64];

    const int t  = threadIdx.x;
    const int e0 = blockIdx.x * 64;     // E = 12500 * 64, no tail

    // ---- gather + f32->bf16 convert ----
    {
        const int e = t >> 2, sub = t & 3;
        const int gs = src[e0 + e];
        const int gd = dst[e0 + e];
        const float4* rs = (const float4*)(node_feat + (size_t)gs * 64) + sub * 4;
        const float4* rd = (const float4*)(node_feat + (size_t)gd * 64) + sub * 4;
#pragma unroll
        for (int q = 0; q < 4; ++q) {
            float4 a = rs[q];
            float4 b = rd[q];
            *(bf16x4*)&sFb[e * STR1 + sub * 16 + 4 * q] =
                (bf16x4){(__bf16)a.x, (__bf16)a.y, (__bf16)a.z, (__bf16)a.w};
            *(bf16x4*)&sFb[e * STR1 + 64 + sub * 16 + 4 * q] =
                (bf16x4){(__bf16)b.x, (__bf16)b.y, (__bf16)b.z, (__bf16)b.w};
        }
    }
    if (t < 64) {
        const int e  = t;
        const int gs = src[e0 + e];
        const int gd = dst[e0 + e];
        float dx = coord[(size_t)gs * 3 + 0] - coord[(size_t)gd * 3 + 0];
        float dy = coord[(size_t)gs * 3 + 1] - coord[(size_t)gd * 3 + 1];
        float dz = coord[(size_t)gs * 3 + 2] - coord[(size_t)gd * 3 + 2];
        float radial = dx * dx + dy * dy + dz * dz;
        sRad[e] = radial;
        float inv = 1.0f / (sqrtf(radial) + EPS_F);
        sXd[e][0] = dx * inv; sXd[e][1] = dy * inv; sXd[e][2] = dz * inv;
        sDst[e] = gd;
    }
    __syncthreads();

    const int lane = t & 63;
    const int w    = t >> 6;        // wave id: rows w*16 .. w*16+15
    const int lr   = lane & 15;     // A-row / B-col / C-col index
    const int lk   = lane >> 4;     // k-group / C-row group

    f32x4 acc[4];

    // ---- layer 1: [64,128]bf16 @ [128,64]bf16 + (be1 + radial*We1[128]) ----
    {
#pragma unroll
        for (int nt = 0; nt < 4; ++nt) {
            const int col = nt * 16 + lr;
            const float b0 = be1[col];
            const float wr = We1[128 * 64 + col];
#pragma unroll
            for (int r = 0; r < 4; ++r)
                acc[nt][r] = b0 + sRad[w * 16 + lk * 4 + r] * wr;
        }
        const int arow = w * 16 + lr;
#pragma unroll
        for (int ks = 0; ks < 4; ++ks) {
            bf16x8 a = *(const bf16x8*)&sFb[arow * STR1 + ks * 32 + lk * 8];
#pragma unroll
            for (int nt = 0; nt < 4; ++nt) {
                bf16x8 b = *(const bf16x8*)&We1p[(nt * 16 + lr) * 128 + ks * 32 + lk * 8];
                acc[nt] = __builtin_amdgcn_mfma_f32_16x16x32_bf16(a, b, acc[nt], 0, 0, 0);
            }
        }
        // SiLU -> sT (bf16)
#pragma unroll
        for (int nt = 0; nt < 4; ++nt) {
            const int col = nt * 16 + lr;
#pragma unroll
            for (int r = 0; r < 4; ++r) {
                const int row = w * 16 + lk * 4 + r;
                sT[row * STR2 + col] = (__bf16)silu_f(acc[nt][r]);
            }
        }
    }
    __syncthreads();

    // ---- layer 2: sT @ We2 + be2, SiLU -> msg_h; scatter h_neigh from regs ----
    {
#pragma unroll
        for (int nt = 0; nt < 4; ++nt) {
            const float b0 = be2[nt * 16 + lr];
            acc[nt] = (f32x4){b0, b0, b0, b0};
        }
        const int arow = w * 16 + lr;
#pragma unroll
        for (int ks = 0; ks < 2; ++ks) {
            bf16x8 a = *(const bf16x8*)&sT[arow * STR2 + ks * 32 + lk * 8];
#pragma unroll
            for (int nt = 0; nt < 4; ++nt) {
                bf16x8 b = *(const bf16x8*)&We2p[(nt * 16 + lr) * 64 + ks * 32 + lk * 8];
                acc[nt] = __builtin_amdgcn_mfma_f32_16x16x32_bf16(a, b, acc[nt], 0, 0, 0);
            }
        }
#pragma unroll
        for (int nt = 0; nt < 4; ++nt) {
            const int col = nt * 16 + lr;
#pragma unroll
            for (int r = 0; r < 4; ++r) {
                const int row = w * 16 + lk * 4 + r;
                const float v = silu_f(acc[nt][r]);
                sM[row * STR2 + col] = (__bf16)v;
                atomicAdd(&h_neigh[(size_t)sDst[row] * 64 + col], v);
            }
        }
    }
    __syncthreads();

    // ---- layer 3: sM @ Wx1 + bx1, SiLU, dot Wx2 -> coef; scatter x_sum/deg ----
    {
#pragma unroll
        for (int nt = 0; nt < 4; ++nt) {
            const float b0 = bx1[nt * 16 + lr];
            acc[nt] = (f32x4){b0, b0, b0, b0};
        }
        const int arow = w * 16 + lr;
#pragma unroll
        for (int ks = 0; ks < 2; ++ks) {
            bf16x8 a = *(const bf16x8*)&sM[arow * STR2 + ks * 32 + lk * 8];
#pragma unroll
            for (int nt = 0; nt < 4; ++nt) {
                bf16x8 b = *(const bf16x8*)&Wx1p[(nt * 16 + lr) * 64 + ks * 32 + lk * 8];
                acc[nt] = __builtin_amdgcn_mfma_f32_16x16x32_bf16(a, b, acc[nt], 0, 0, 0);
            }
        }
        float p[4] = {0.f, 0.f, 0.f, 0.f};
#pragma unroll
        for (int nt = 0; nt < 4; ++nt) {
            const float wv = Wx2[nt * 16 + lr];
#pragma unroll
            for (int r = 0; r < 4; ++r)
                p[r] += silu_f(acc[nt][r]) * wv;
        }
#pragma unroll
        for (int off = 1; off < 16; off <<= 1)
#pragma unroll
            for (int r = 0; r < 4; ++r)
                p[r] += __shfl_xor(p[r], off);
        if (lr == 0) {
#pragma unroll
            for (int r = 0; r < 4; ++r) {
                const int e  = w * 16 + lk * 4 + r;
                const int gd = sDst[e];
                const float coef = p[r];
                atomicAdd(&x_sum[(size_t)gd * 3 + 0], coef * sXd[e][0]);
                atomicAdd(&x_sum[(size_t)gd * 3 + 1], coef * sXd[e][1]);
                atomicAdd(&x_sum[(size_t)gd * 3 + 2], coef * sXd[e][2]);
                atomicAdd(&deg[gd], 1.0f);
            }
        }
    }
}

// ---------------- node kernel (f32 vector GEMM, unchanged) ----------------
template<int KDIM>
__device__ __forceinline__ void tile_gemm64(const float* __restrict__ A, int astride,
                                            const float* __restrict__ B,
                                            float acc[4][4], int t)
{
    const int tx = t & 15;
    const int ty = t >> 4;
#pragma unroll
    for (int i = 0; i < 4; ++i)
#pragma unroll
        for (int j = 0; j < 4; ++j) acc[i][j] = 0.0f;

    for (int k = 0; k < KDIM; k += 4) {
        float bv[4][4];
#pragma unroll
        for (int kk = 0; kk < 4; ++kk) {
            float4 bq = *(const float4*)(B + (size_t)(k + kk) * 64 + tx * 4);
            bv[kk][0] = bq.x; bv[kk][1] = bq.y; bv[kk][2] = bq.z; bv[kk][3] = bq.w;
        }
#pragma unroll
        for (int i = 0; i < 4; ++i) {
            float4 aq = *(const float4*)(A + (size_t)(ty * 4 + i) * astride + k);
            float av[4] = {aq.x, aq.y, aq.z, aq.w};
#pragma unroll
            for (int kk = 0; kk < 4; ++kk)
#pragma unroll
                for (int j = 0; j < 4; ++j)
                    acc[i][j] = fmaf(av[kk], bv[kk][j], acc[i][j]);
        }
    }
}

__global__ __launch_bounds__(256, 2)
void egnn_node_kernel(const float* __restrict__ node_feat,
                      const float* __restrict__ coord,
                      const float* __restrict__ Wn1, const float* __restrict__ bn1,
                      const float* __restrict__ Wn2, const float* __restrict__ bn2,
                      const float* __restrict__ h_neigh,
                      const float* __restrict__ x_sum,
                      const float* __restrict__ deg,
                      float* __restrict__ out_h,
                      float* __restrict__ out_x)
{
    __shared__ float sF[64][132];
    __shared__ float sT[64][68];

    const int t  = threadIdx.x;
    const int n0 = blockIdx.x * 64;

    {
        const int r = t >> 2;
        const int sub = t & 3;
        const int n = n0 + r;
        if (n < N_NODES) {
            const float* rowsrc = (sub < 2) ? (node_feat + (size_t)n * 64 + sub * 32)
                                            : (h_neigh  + (size_t)n * 64 + (sub - 2) * 32);
#pragma unroll
            for (int q = 0; q < 8; ++q)
                *(float4*)&sF[r][sub * 32 + 4 * q] = *(const float4*)(rowsrc + 4 * q);
        } else {
#pragma unroll
            for (int q = 0; q < 8; ++q)
                *(float4*)&sF[r][sub * 32 + 4 * q] = make_float4(0.f, 0.f, 0.f, 0.f);
        }
    }
    __syncthreads();

    const int tx = t & 15;
    const int ty = t >> 4;
    float acc[4][4];

    tile_gemm64<128>(&sF[0][0], 132, Wn1, acc, t);
    {
        float4 bq = *(const float4*)(bn1 + tx * 4);
        float bv[4] = {bq.x, bq.y, bq.z, bq.w};
#pragma unroll
        for (int i = 0; i < 4; ++i) {
            float4 o;
            o.x = silu_f(acc[i][0] + bv[0]);
            o.y = silu_f(acc[i][1] + bv[1]);
            o.z = silu_f(acc[i][2] + bv[2]);
            o.w = silu_f(acc[i][3] + bv[3]);
            *(float4*)&sT[ty * 4 + i][tx * 4] = o;
        }
    }
    __syncthreads();

    tile_gemm64<64>(&sT[0][0], 68, Wn2, acc, t);
    {
        float4 bq = *(const float4*)(bn2 + tx * 4);
        float bv[4] = {bq.x, bq.y, bq.z, bq.w};
#pragma unroll
        for (int i = 0; i < 4; ++i) {
            const int n = n0 + ty * 4 + i;
            if (n < N_NODES) {
                float4 o;
                o.x = acc[i][0] + bv[0];
                o.y = acc[i][1] + bv[1];
                o.z = acc[i][2] + bv[2];
                o.w = acc[i][3] + bv[3];
                *(float4*)&out_h[(size_t)n * 64 + tx * 4] = o;
            }
        }
    }

    if (t < 64) {
        const int n = n0 + t;
        if (n < N_NODES) {
            const float d = deg[n];
            const float inv = 1.0f / fmaxf(d, 1.0f);
#pragma unroll
            for (int c = 0; c < 3; ++c)
                out_x[(size_t)n * 3 + c] = coord[(size_t)n * 3 + c]
                                         + x_sum[(size_t)n * 3 + c] * inv;
        }
    }
}

extern "C" void kernel_launch(void* const* d_in, const int* in_sizes, int n_in,
                              void* d_out, int out_size, void* d_ws, size_t ws_size,
                              hipStream_t stream) {
    const float* node_feat = (const float*)d_in[0];
    const float* coord     = (const float*)d_in[1];
    const int*   src       = (const int*)d_in[2];
    const int*   dst       = (const int*)d_in[3];
    const float* We1 = (const float*)d_in[4];
    const float* be1 = (const float*)d_in[5];
    const float* We2 = (const float*)d_in[6];
    const float* be2 = (const float*)d_in[7];
    const float* Wx1 = (const float*)d_in[8];
    const float* bx1 = (const float*)d_in[9];
    const float* Wx2 = (const float*)d_in[10];
    const float* Wn1 = (const float*)d_in[11];
    const float* bn1 = (const float*)d_in[12];
    const float* Wn2 = (const float*)d_in[13];
    const float* bn2 = (const float*)d_in[14];

    float* out_h = (float*)d_out;
    float* out_x = out_h + (size_t)N_NODES * 64;

    float* h_neigh = (float*)d_ws;                       // [N,64]
    float* x_sum   = h_neigh + (size_t)N_NODES * 64;     // [N,3]
    float* deg     = x_sum + (size_t)N_NODES * 3;        // [N]
    __bf16* We1p   = (__bf16*)(deg + N_NODES);           // [64][128]
    __bf16* We2p   = We1p + 64 * 128;                    // [64][64]
    __bf16* Wx1p   = We2p + 64 * 64;                     // [64][64]

    const size_t zero_bytes = (size_t)N_NODES * 68 * sizeof(float);
    hipMemsetAsync(d_ws, 0, zero_bytes, stream);

    pack_weights<<<32, 256, 0, stream>>>(We1, We2, Wx1, We1p, We2p, Wx1p);

    egnn_edge_mfma<<<N_EDGES / 64, 256, 0, stream>>>(
        node_feat, coord, src, dst,
        We1, be1, be2, bx1, Wx2,
        We1p, We2p, Wx1p,
        h_neigh, x_sum, deg);

    egnn_node_kernel<<<(N_NODES + 63) / 64, 256, 0, stream>>>(
        node_feat, coord, Wn1, bn1, Wn2, bn2,
        h_neigh, x_sum, deg, out_h, out_x);
}

// Round 3
// 391.100 us; speedup vs baseline: 1.7809x; 1.2934x over previous
//
#include <hip/hip_runtime.h>
#include <math.h>

#define N_NODES 50000
#define N_EDGES 800000
#define EPS_F 1e-30f

typedef __bf16 bf16x8 __attribute__((ext_vector_type(8)));
typedef __bf16 bf16x4 __attribute__((ext_vector_type(4)));
typedef float  f32x4  __attribute__((ext_vector_type(4)));

#define STR1 136   // 128-wide bf16 tile row stride (272B)
#define STR2 72    // 64-wide bf16 tile row stride (144B)

__device__ __forceinline__ float silu_f(float x) {
    return x / (1.0f + __expf(-x));
}

// ---------------- weight packing: W[k][n] f32 -> Wp[n][k] bf16 ----------------
__global__ void pack_weights(const float* __restrict__ We1,
                             const float* __restrict__ We2,
                             const float* __restrict__ Wx1,
                             const float* __restrict__ Wn1,
                             const float* __restrict__ Wn2,
                             __bf16* __restrict__ We1p,   // [64][128]
                             __bf16* __restrict__ We2p,   // [64][64]
                             __bf16* __restrict__ Wx1p,   // [64][64]
                             __bf16* __restrict__ Wn1p,   // [64][128]
                             __bf16* __restrict__ Wn2p)   // [64][64]
{
    const int t = blockIdx.x * 256 + threadIdx.x;
    for (int i = t; i < 64 * 128; i += gridDim.x * 256) {
        const int n = i >> 7, k = i & 127;
        We1p[i] = (__bf16)We1[k * 64 + n];
        Wn1p[i] = (__bf16)Wn1[k * 64 + n];
    }
    for (int i = t; i < 64 * 64; i += gridDim.x * 256) {
        const int n = i >> 6, k = i & 63;
        We2p[i] = (__bf16)We2[k * 64 + n];
        Wx1p[i] = (__bf16)Wx1[k * 64 + n];
        Wn2p[i] = (__bf16)Wn2[k * 64 + n];
    }
}

// ---------------- CSR build ----------------
__global__ void hist_kernel(const int* __restrict__ dst, int* __restrict__ cnt) {
    const int e = blockIdx.x * 256 + threadIdx.x;
    if (e < N_EDGES) atomicAdd(&cnt[dst[e]], 1);
}

__global__ void scan1_kernel(const int* __restrict__ cnt,
                             int* __restrict__ excl, int* __restrict__ bsum) {
    __shared__ int s[256];
    const int tid = threadIdx.x;
    const int i = blockIdx.x * 256 + tid;
    const int v = (i < N_NODES) ? cnt[i] : 0;
    s[tid] = v; __syncthreads();
#pragma unroll
    for (int off = 1; off < 256; off <<= 1) {
        int t = (tid >= off) ? s[tid - off] : 0;
        __syncthreads();
        s[tid] += t;
        __syncthreads();
    }
    if (i < N_NODES) excl[i] = s[tid] - v;
    if (tid == 255) bsum[blockIdx.x] = s[255];
}

__global__ void scan2_kernel(int* __restrict__ bsum, int* __restrict__ bpre, int nb) {
    __shared__ int s[256];
    const int tid = threadIdx.x;
    const int v = (tid < nb) ? bsum[tid] : 0;
    s[tid] = v; __syncthreads();
#pragma unroll
    for (int off = 1; off < 256; off <<= 1) {
        int t = (tid >= off) ? s[tid - off] : 0;
        __syncthreads();
        s[tid] += t;
        __syncthreads();
    }
    if (tid < nb) bpre[tid] = s[tid] - v;
}

__global__ void scan3_kernel(const int* __restrict__ excl, const int* __restrict__ bpre,
                             int* __restrict__ offsets, int* __restrict__ cursor) {
    const int i = blockIdx.x * 256 + threadIdx.x;
    if (i < N_NODES) {
        const int o = bpre[blockIdx.x] + excl[i];
        offsets[i] = o;
        cursor[i] = o;
    }
    if (blockIdx.x == 0 && threadIdx.x == 0) offsets[N_NODES] = N_EDGES;
}

__global__ void fill_kernel(const int* __restrict__ dst,
                            int* __restrict__ cursor, int* __restrict__ perm) {
    const int e = blockIdx.x * 256 + threadIdx.x;
    if (e < N_EDGES) {
        const int p = atomicAdd(&cursor[dst[e]], 1);
        perm[p] = e;
    }
}

// ---------------- edge kernel (fast path): MFMA, stores msg buffers ----------------
__global__ __launch_bounds__(256, 4)
void egnn_edge_mfma_v2(const float* __restrict__ node_feat,
                       const float* __restrict__ coord,
                       const int* __restrict__ src,
                       const int* __restrict__ dst,
                       const float* __restrict__ We1,   // row 128 (radial) f32
                       const float* __restrict__ be1,
                       const float* __restrict__ be2,
                       const float* __restrict__ bx1,
                       const float* __restrict__ Wx2,
                       const __bf16* __restrict__ We1p,
                       const __bf16* __restrict__ We2p,
                       const __bf16* __restrict__ Wx1p,
                       __bf16* __restrict__ msg_h,      // [E*64] bf16
                       float4* __restrict__ msg_x)      // [E]
{
    __shared__ __bf16 sFb[64 * STR1];
    __shared__ __bf16 sT [64 * STR2];
    __shared__ __bf16 sM [64 * STR2];
    __shared__ float  sRad[64];
    __shared__ float  sXd[64][3];

    const int t  = threadIdx.x;
    const int e0 = blockIdx.x * 64;     // E = 12500 * 64

    {
        const int e = t >> 2, sub = t & 3;
        const int gs = src[e0 + e];
        const int gd = dst[e0 + e];
        const float4* rs = (const float4*)(node_feat + (size_t)gs * 64) + sub * 4;
        const float4* rd = (const float4*)(node_feat + (size_t)gd * 64) + sub * 4;
#pragma unroll
        for (int q = 0; q < 4; ++q) {
            float4 a = rs[q];
            float4 b = rd[q];
            *(bf16x4*)&sFb[e * STR1 + sub * 16 + 4 * q] =
                (bf16x4){(__bf16)a.x, (__bf16)a.y, (__bf16)a.z, (__bf16)a.w};
            *(bf16x4*)&sFb[e * STR1 + 64 + sub * 16 + 4 * q] =
                (bf16x4){(__bf16)b.x, (__bf16)b.y, (__bf16)b.z, (__bf16)b.w};
        }
    }
    if (t < 64) {
        const int e  = t;
        const int gs = src[e0 + e];
        const int gd = dst[e0 + e];
        float dx = coord[(size_t)gs * 3 + 0] - coord[(size_t)gd * 3 + 0];
        float dy = coord[(size_t)gs * 3 + 1] - coord[(size_t)gd * 3 + 1];
        float dz = coord[(size_t)gs * 3 + 2] - coord[(size_t)gd * 3 + 2];
        float radial = dx * dx + dy * dy + dz * dz;
        sRad[e] = radial;
        float inv = 1.0f / (sqrtf(radial) + EPS_F);
        sXd[e][0] = dx * inv; sXd[e][1] = dy * inv; sXd[e][2] = dz * inv;
    }
    __syncthreads();

    const int lane = t & 63;
    const int w    = t >> 6;
    const int lr   = lane & 15;
    const int lk   = lane >> 4;

    f32x4 acc[4];

    // ---- layer 1 ----
    {
#pragma unroll
        for (int nt = 0; nt < 4; ++nt) {
            const int col = nt * 16 + lr;
            const float b0 = be1[col];
            const float wr = We1[128 * 64 + col];
#pragma unroll
            for (int r = 0; r < 4; ++r)
                acc[nt][r] = b0 + sRad[w * 16 + lk * 4 + r] * wr;
        }
        const int arow = w * 16 + lr;
#pragma unroll
        for (int ks = 0; ks < 4; ++ks) {
            bf16x8 a = *(const bf16x8*)&sFb[arow * STR1 + ks * 32 + lk * 8];
#pragma unroll
            for (int nt = 0; nt < 4; ++nt) {
                bf16x8 b = *(const bf16x8*)&We1p[(nt * 16 + lr) * 128 + ks * 32 + lk * 8];
                acc[nt] = __builtin_amdgcn_mfma_f32_16x16x32_bf16(a, b, acc[nt], 0, 0, 0);
            }
        }
#pragma unroll
        for (int nt = 0; nt < 4; ++nt) {
            const int col = nt * 16 + lr;
#pragma unroll
            for (int r = 0; r < 4; ++r) {
                const int row = w * 16 + lk * 4 + r;
                sT[row * STR2 + col] = (__bf16)silu_f(acc[nt][r]);
            }
        }
    }
    __syncthreads();

    // ---- layer 2 -> msg_h ----
    {
#pragma unroll
        for (int nt = 0; nt < 4; ++nt) {
            const float b0 = be2[nt * 16 + lr];
            acc[nt] = (f32x4){b0, b0, b0, b0};
        }
        const int arow = w * 16 + lr;
#pragma unroll
        for (int ks = 0; ks < 2; ++ks) {
            bf16x8 a = *(const bf16x8*)&sT[arow * STR2 + ks * 32 + lk * 8];
#pragma unroll
            for (int nt = 0; nt < 4; ++nt) {
                bf16x8 b = *(const bf16x8*)&We2p[(nt * 16 + lr) * 64 + ks * 32 + lk * 8];
                acc[nt] = __builtin_amdgcn_mfma_f32_16x16x32_bf16(a, b, acc[nt], 0, 0, 0);
            }
        }
#pragma unroll
        for (int nt = 0; nt < 4; ++nt) {
            const int col = nt * 16 + lr;
#pragma unroll
            for (int r = 0; r < 4; ++r) {
                const int row = w * 16 + lk * 4 + r;
                sM[row * STR2 + col] = (__bf16)silu_f(acc[nt][r]);
            }
        }
    }
    __syncthreads();

    // ---- coalesced msg_h store (from sM) ----
    {
        const int r = t >> 2, q = t & 3;
        bf16x8 v0 = *(const bf16x8*)&sM[r * STR2 + q * 16];
        bf16x8 v1 = *(const bf16x8*)&sM[r * STR2 + q * 16 + 8];
        *(bf16x8*)&msg_h[(size_t)(e0 + r) * 64 + q * 16]     = v0;
        *(bf16x8*)&msg_h[(size_t)(e0 + r) * 64 + q * 16 + 8] = v1;
    }

    // ---- layer 3: coef -> msg_x ----
    {
#pragma unroll
        for (int nt = 0; nt < 4; ++nt) {
            const float b0 = bx1[nt * 16 + lr];
            acc[nt] = (f32x4){b0, b0, b0, b0};
        }
        const int arow = w * 16 + lr;
#pragma unroll
        for (int ks = 0; ks < 2; ++ks) {
            bf16x8 a = *(const bf16x8*)&sM[arow * STR2 + ks * 32 + lk * 8];
#pragma unroll
            for (int nt = 0; nt < 4; ++nt) {
                bf16x8 b = *(const bf16x8*)&Wx1p[(nt * 16 + lr) * 64 + ks * 32 + lk * 8];
                acc[nt] = __builtin_amdgcn_mfma_f32_16x16x32_bf16(a, b, acc[nt], 0, 0, 0);
            }
        }
        float p[4] = {0.f, 0.f, 0.f, 0.f};
#pragma unroll
        for (int nt = 0; nt < 4; ++nt) {
            const float wv = Wx2[nt * 16 + lr];
#pragma unroll
            for (int r = 0; r < 4; ++r)
                p[r] += silu_f(acc[nt][r]) * wv;
        }
#pragma unroll
        for (int off = 1; off < 16; off <<= 1)
#pragma unroll
            for (int r = 0; r < 4; ++r)
                p[r] += __shfl_xor(p[r], off);
        if (lr == 0) {
#pragma unroll
            for (int r = 0; r < 4; ++r) {
                const int e = w * 16 + lk * 4 + r;
                const float coef = p[r];
                msg_x[e0 + e] = make_float4(coef * sXd[e][0], coef * sXd[e][1],
                                            coef * sXd[e][2], 0.0f);
            }
        }
    }
}

// ---------------- node kernel (fast path): CSR gather + MFMA MLP ----------------
__global__ __launch_bounds__(256, 4)
void egnn_node_mfma(const float* __restrict__ node_feat,
                    const float* __restrict__ coord,
                    const int* __restrict__ offsets,
                    const int* __restrict__ perm,
                    const __bf16* __restrict__ msg_h,
                    const float4* __restrict__ msg_x,
                    const float* __restrict__ bn1,
                    const float* __restrict__ bn2,
                    const __bf16* __restrict__ Wn1p,
                    const __bf16* __restrict__ Wn2p,
                    float* __restrict__ out_h,
                    float* __restrict__ out_x)
{
    __shared__ __bf16 sFb[64 * STR1];   // [node_feat | h_neigh] bf16
    __shared__ __bf16 sT [64 * STR2];

    const int t  = threadIdx.x;
    const int n0 = blockIdx.x * 64;
    const int r  = t >> 2, q = t & 3;
    const int n  = n0 + r;
    const bool valid = (n < N_NODES);

    // node_feat -> sFb[r][q*16 .. +16]
    {
        if (valid) {
            const float4* rowsrc = (const float4*)(node_feat + (size_t)n * 64) + q * 4;
#pragma unroll
            for (int k = 0; k < 4; ++k) {
                float4 a = rowsrc[k];
                *(bf16x4*)&sFb[r * STR1 + q * 16 + 4 * k] =
                    (bf16x4){(__bf16)a.x, (__bf16)a.y, (__bf16)a.z, (__bf16)a.w};
            }
        } else {
#pragma unroll
            for (int k = 0; k < 4; ++k)
                *(bf16x4*)&sFb[r * STR1 + q * 16 + 4 * k] = (bf16x4){0, 0, 0, 0};
        }
    }

    // gather-reduce this node's CSR segment
    {
        const int beg = valid ? offsets[n] : 0;
        const int end = valid ? offsets[n + 1] : 0;
        float facc[16];
#pragma unroll
        for (int i = 0; i < 16; ++i) facc[i] = 0.0f;
        float xa = 0.f, xb = 0.f, xc = 0.f;

        for (int j = beg; j < end; ++j) {
            const int e = perm[j];
            bf16x8 v0 = *(const bf16x8*)&msg_h[(size_t)e * 64 + q * 16];
            bf16x8 v1 = *(const bf16x8*)&msg_h[(size_t)e * 64 + q * 16 + 8];
#pragma unroll
            for (int i = 0; i < 8; ++i) facc[i]     += (float)v0[i];
#pragma unroll
            for (int i = 0; i < 8; ++i) facc[8 + i] += (float)v1[i];
            if (q == 0) {
                float4 mx = msg_x[e];
                xa += mx.x; xb += mx.y; xc += mx.z;
            }
        }
#pragma unroll
        for (int i = 0; i < 16; ++i)
            sFb[r * STR1 + 64 + q * 16 + i] = (__bf16)facc[i];

        if (q == 0 && valid) {
            const float d = (float)(end - beg);
            const float inv = 1.0f / fmaxf(d, 1.0f);
            out_x[(size_t)n * 3 + 0] = coord[(size_t)n * 3 + 0] + xa * inv;
            out_x[(size_t)n * 3 + 1] = coord[(size_t)n * 3 + 1] + xb * inv;
            out_x[(size_t)n * 3 + 2] = coord[(size_t)n * 3 + 2] + xc * inv;
        }
    }
    __syncthreads();

    const int lane = t & 63;
    const int w    = t >> 6;
    const int lr   = lane & 15;
    const int lk   = lane >> 4;

    f32x4 acc[4];

    // ---- node layer 1 (K=128) ----
    {
#pragma unroll
        for (int nt = 0; nt < 4; ++nt) {
            const float b0 = bn1[nt * 16 + lr];
            acc[nt] = (f32x4){b0, b0, b0, b0};
        }
        const int arow = w * 16 + lr;
#pragma unroll
        for (int ks = 0; ks < 4; ++ks) {
            bf16x8 a = *(const bf16x8*)&sFb[arow * STR1 + ks * 32 + lk * 8];
#pragma unroll
            for (int nt = 0; nt < 4; ++nt) {
                bf16x8 b = *(const bf16x8*)&Wn1p[(nt * 16 + lr) * 128 + ks * 32 + lk * 8];
                acc[nt] = __builtin_amdgcn_mfma_f32_16x16x32_bf16(a, b, acc[nt], 0, 0, 0);
            }
        }
#pragma unroll
        for (int nt = 0; nt < 4; ++nt) {
            const int col = nt * 16 + lr;
#pragma unroll
            for (int rr = 0; rr < 4; ++rr) {
                const int row = w * 16 + lk * 4 + rr;
                sT[row * STR2 + col] = (__bf16)silu_f(acc[nt][rr]);
            }
        }
    }
    __syncthreads();

    // ---- node layer 2 (K=64) -> sOut (aliases sFb) ----
    float* sOut = (float*)sFb;   // 64 rows x 68 f32 (stride 68 f32 = 272B = STR1 bf16)
    {
#pragma unroll
        for (int nt = 0; nt < 4; ++nt) {
            const float b0 = bn2[nt * 16 + lr];
            acc[nt] = (f32x4){b0, b0, b0, b0};
        }
        const int arow = w * 16 + lr;
#pragma unroll
        for (int ks = 0; ks < 2; ++ks) {
            bf16x8 a = *(const bf16x8*)&sT[arow * STR2 + ks * 32 + lk * 8];
#pragma unroll
            for (int nt = 0; nt < 4; ++nt) {
                bf16x8 b = *(const bf16x8*)&Wn2p[(nt * 16 + lr) * 64 + ks * 32 + lk * 8];
                acc[nt] = __builtin_amdgcn_mfma_f32_16x16x32_bf16(a, b, acc[nt], 0, 0, 0);
            }
        }
        __syncthreads();   // all sFb reads (layer 1) done; safe to overwrite
#pragma unroll
        for (int nt = 0; nt < 4; ++nt) {
            const int col = nt * 16 + lr;
#pragma unroll
            for (int rr = 0; rr < 4; ++rr) {
                const int row = w * 16 + lk * 4 + rr;
                sOut[row * 68 + col] = acc[nt][rr];
            }
        }
    }
    __syncthreads();

    if (valid) {
#pragma unroll
        for (int k = 0; k < 4; ++k) {
            float4 v = *(const float4*)&sOut[r * 68 + q * 16 + 4 * k];
            *(float4*)&out_h[(size_t)n * 64 + q * 16 + 4 * k] = v;
        }
    }
}

// ================= fallback path (round-2, atomics) =================
__global__ __launch_bounds__(256, 4)
void egnn_edge_mfma_atomic(const float* __restrict__ node_feat,
                           const float* __restrict__ coord,
                           const int* __restrict__ src,
                           const int* __restrict__ dst,
                           const float* __restrict__ We1,
                           const float* __restrict__ be1,
                           const float* __restrict__ be2,
                           const float* __restrict__ bx1,
                           const float* __restrict__ Wx2,
                           const __bf16* __restrict__ We1p,
                           const __bf16* __restrict__ We2p,
                           const __bf16* __restrict__ Wx1p,
                           float* __restrict__ h_neigh,
                           float* __restrict__ x_sum,
                           float* __restrict__ deg)
{
    __shared__ __bf16 sFb[64 * STR1];
    __shared__ __bf16 sT [64 * STR2];
    __shared__ __bf16 sM [64 * STR2];
    __shared__ float  sRad[64];
    __shared__ float  sXd[64][3];
    __shared__ int    sDst[64];

    const int t  = threadIdx.x;
    const int e0 = blockIdx.x * 64;

    {
        const int e = t >> 2, sub = t & 3;
        const int gs = src[e0 + e];
        const int gd = dst[e0 + e];
        const float4* rs = (const float4*)(node_feat + (size_t)gs * 64) + sub * 4;
        const float4* rd = (const float4*)(node_feat + (size_t)gd * 64) + sub * 4;
#pragma unroll
        for (int q = 0; q < 4; ++q) {
            float4 a = rs[q];
            float4 b = rd[q];
            *(bf16x4*)&sFb[e * STR1 + sub * 16 + 4 * q] =
                (bf16x4){(__bf16)a.x, (__bf16)a.y, (__bf16)a.z, (__bf16)a.w};
            *(bf16x4*)&sFb[e * STR1 + 64 + sub * 16 + 4 * q] =
                (bf16x4){(__bf16)b.x, (__bf16)b.y, (__bf16)b.z, (__bf16)b.w};
        }
    }
    if (t < 64) {
        const int e  = t;
        const int gs = src[e0 + e];
        const int gd = dst[e0 + e];
        float dx = coord[(size_t)gs * 3 + 0] - coord[(size_t)gd * 3 + 0];
        float dy = coord[(size_t)gs * 3 + 1] - coord[(size_t)gd * 3 + 1];
        float dz = coord[(size_t)gs * 3 + 2] - coord[(size_t)gd * 3 + 2];
        float radial = dx * dx + dy * dy + dz * dz;
        sRad[e] = radial;
        float inv = 1.0f / (sqrtf(radial) + EPS_F);
        sXd[e][0] = dx * inv; sXd[e][1] = dy * inv; sXd[e][2] = dz * inv;
        sDst[e] = gd;
    }
    __syncthreads();

    const int lane = t & 63;
    const int w    = t >> 6;
    const int lr   = lane & 15;
    const int lk   = lane >> 4;

    f32x4 acc[4];
    {
#pragma unroll
        for (int nt = 0; nt < 4; ++nt) {
            const int col = nt * 16 + lr;
            const float b0 = be1[col];
            const float wr = We1[128 * 64 + col];
#pragma unroll
            for (int r = 0; r < 4; ++r)
                acc[nt][r] = b0 + sRad[w * 16 + lk * 4 + r] * wr;
        }
        const int arow = w * 16 + lr;
#pragma unroll
        for (int ks = 0; ks < 4; ++ks) {
            bf16x8 a = *(const bf16x8*)&sFb[arow * STR1 + ks * 32 + lk * 8];
#pragma unroll
            for (int nt = 0; nt < 4; ++nt) {
                bf16x8 b = *(const bf16x8*)&We1p[(nt * 16 + lr) * 128 + ks * 32 + lk * 8];
                acc[nt] = __builtin_amdgcn_mfma_f32_16x16x32_bf16(a, b, acc[nt], 0, 0, 0);
            }
        }
#pragma unroll
        for (int nt = 0; nt < 4; ++nt) {
            const int col = nt * 16 + lr;
#pragma unroll
            for (int r = 0; r < 4; ++r) {
                const int row = w * 16 + lk * 4 + r;
                sT[row * STR2 + col] = (__bf16)silu_f(acc[nt][r]);
            }
        }
    }
    __syncthreads();
    {
#pragma unroll
        for (int nt = 0; nt < 4; ++nt) {
            const float b0 = be2[nt * 16 + lr];
            acc[nt] = (f32x4){b0, b0, b0, b0};
        }
        const int arow = w * 16 + lr;
#pragma unroll
        for (int ks = 0; ks < 2; ++ks) {
            bf16x8 a = *(const bf16x8*)&sT[arow * STR2 + ks * 32 + lk * 8];
#pragma unroll
            for (int nt = 0; nt < 4; ++nt) {
                bf16x8 b = *(const bf16x8*)&We2p[(nt * 16 + lr) * 64 + ks * 32 + lk * 8];
                acc[nt] = __builtin_amdgcn_mfma_f32_16x16x32_bf16(a, b, acc[nt], 0, 0, 0);
            }
        }
#pragma unroll
        for (int nt = 0; nt < 4; ++nt) {
            const int col = nt * 16 + lr;
#pragma unroll
            for (int r = 0; r < 4; ++r) {
                const int row = w * 16 + lk * 4 + r;
                const float v = silu_f(acc[nt][r]);
                sM[row * STR2 + col] = (__bf16)v;
                atomicAdd(&h_neigh[(size_t)sDst[row] * 64 + col], v);
            }
        }
    }
    __syncthreads();
    {
#pragma unroll
        for (int nt = 0; nt < 4; ++nt) {
            const float b0 = bx1[nt * 16 + lr];
            acc[nt] = (f32x4){b0, b0, b0, b0};
        }
        const int arow = w * 16 + lr;
#pragma unroll
        for (int ks = 0; ks < 2; ++ks) {
            bf16x8 a = *(const bf16x8*)&sM[arow * STR2 + ks * 32 + lk * 8];
#pragma unroll
            for (int nt = 0; nt < 4; ++nt) {
                bf16x8 b = *(const bf16x8*)&Wx1p[(nt * 16 + lr) * 64 + ks * 32 + lk * 8];
                acc[nt] = __builtin_amdgcn_mfma_f32_16x16x32_bf16(a, b, acc[nt], 0, 0, 0);
            }
        }
        float p[4] = {0.f, 0.f, 0.f, 0.f};
#pragma unroll
        for (int nt = 0; nt < 4; ++nt) {
            const float wv = Wx2[nt * 16 + lr];
#pragma unroll
            for (int r = 0; r < 4; ++r)
                p[r] += silu_f(acc[nt][r]) * wv;
        }
#pragma unroll
        for (int off = 1; off < 16; off <<= 1)
#pragma unroll
            for (int r = 0; r < 4; ++r)
                p[r] += __shfl_xor(p[r], off);
        if (lr == 0) {
#pragma unroll
            for (int r = 0; r < 4; ++r) {
                const int e  = w * 16 + lk * 4 + r;
                const int gd = sDst[e];
                const float coef = p[r];
                atomicAdd(&x_sum[(size_t)gd * 3 + 0], coef * sXd[e][0]);
                atomicAdd(&x_sum[(size_t)gd * 3 + 1], coef * sXd[e][1]);
                atomicAdd(&x_sum[(size_t)gd * 3 + 2], coef * sXd[e][2]);
                atomicAdd(&deg[gd], 1.0f);
            }
        }
    }
}

template<int KDIM>
__device__ __forceinline__ void tile_gemm64(const float* __restrict__ A, int astride,
                                            const float* __restrict__ B,
                                            float acc[4][4], int t)
{
    const int tx = t & 15;
    const int ty = t >> 4;
#pragma unroll
    for (int i = 0; i < 4; ++i)
#pragma unroll
        for (int j = 0; j < 4; ++j) acc[i][j] = 0.0f;

    for (int k = 0; k < KDIM; k += 4) {
        float bv[4][4];
#pragma unroll
        for (int kk = 0; kk < 4; ++kk) {
            float4 bq = *(const float4*)(B + (size_t)(k + kk) * 64 + tx * 4);
            bv[kk][0] = bq.x; bv[kk][1] = bq.y; bv[kk][2] = bq.z; bv[kk][3] = bq.w;
        }
#pragma unroll
        for (int i = 0; i < 4; ++i) {
            float4 aq = *(const float4*)(A + (size_t)(ty * 4 + i) * astride + k);
            float av[4] = {aq.x, aq.y, aq.z, aq.w};
#pragma unroll
            for (int kk = 0; kk < 4; ++kk)
#pragma unroll
                for (int j = 0; j < 4; ++j)
                    acc[i][j] = fmaf(av[kk], bv[kk][j], acc[i][j]);
        }
    }
}

__global__ __launch_bounds__(256, 2)
void egnn_node_kernel(const float* __restrict__ node_feat,
                      const float* __restrict__ coord,
                      const float* __restrict__ Wn1, const float* __restrict__ bn1,
                      const float* __restrict__ Wn2, const float* __restrict__ bn2,
                      const float* __restrict__ h_neigh,
                      const float* __restrict__ x_sum,
                      const float* __restrict__ deg,
                      float* __restrict__ out_h,
                      float* __restrict__ out_x)
{
    __shared__ float sF[64][132];
    __shared__ float sT2[64][68];

    const int t  = threadIdx.x;
    const int n0 = blockIdx.x * 64;

    {
        const int r = t >> 2;
        const int sub = t & 3;
        const int n = n0 + r;
        if (n < N_NODES) {
            const float* rowsrc = (sub < 2) ? (node_feat + (size_t)n * 64 + sub * 32)
                                            : (h_neigh  + (size_t)n * 64 + (sub - 2) * 32);
#pragma unroll
            for (int q = 0; q < 8; ++q)
                *(float4*)&sF[r][sub * 32 + 4 * q] = *(const float4*)(rowsrc + 4 * q);
        } else {
#pragma unroll
            for (int q = 0; q < 8; ++q)
                *(float4*)&sF[r][sub * 32 + 4 * q] = make_float4(0.f, 0.f, 0.f, 0.f);
        }
    }
    __syncthreads();

    const int tx = t & 15;
    const int ty = t >> 4;
    float acc[4][4];

    tile_gemm64<128>(&sF[0][0], 132, Wn1, acc, t);
    {
        float4 bq = *(const float4*)(bn1 + tx * 4);
        float bv[4] = {bq.x, bq.y, bq.z, bq.w};
#pragma unroll
        for (int i = 0; i < 4; ++i) {
            float4 o;
            o.x = silu_f(acc[i][0] + bv[0]);
            o.y = silu_f(acc[i][1] + bv[1]);
            o.z = silu_f(acc[i][2] + bv[2]);
            o.w = silu_f(acc[i][3] + bv[3]);
            *(float4*)&sT2[ty * 4 + i][tx * 4] = o;
        }
    }
    __syncthreads();

    tile_gemm64<64>(&sT2[0][0], 68, Wn2, acc, t);
    {
        float4 bq = *(const float4*)(bn2 + tx * 4);
        float bv[4] = {bq.x, bq.y, bq.z, bq.w};
#pragma unroll
        for (int i = 0; i < 4; ++i) {
            const int n = n0 + ty * 4 + i;
            if (n < N_NODES) {
                float4 o;
                o.x = acc[i][0] + bv[0];
                o.y = acc[i][1] + bv[1];
                o.z = acc[i][2] + bv[2];
                o.w = acc[i][3] + bv[3];
                *(float4*)&out_h[(size_t)n * 64 + tx * 4] = o;
            }
        }
    }

    if (t < 64) {
        const int n = n0 + t;
        if (n < N_NODES) {
            const float d = deg[n];
            const float inv = 1.0f / fmaxf(d, 1.0f);
#pragma unroll
            for (int c = 0; c < 3; ++c)
                out_x[(size_t)n * 3 + c] = coord[(size_t)n * 3 + c]
                                         + x_sum[(size_t)n * 3 + c] * inv;
        }
    }
}

// ================= host =================
extern "C" void kernel_launch(void* const* d_in, const int* in_sizes, int n_in,
                              void* d_out, int out_size, void* d_ws, size_t ws_size,
                              hipStream_t stream) {
    const float* node_feat = (const float*)d_in[0];
    const float* coord     = (const float*)d_in[1];
    const int*   src       = (const int*)d_in[2];
    const int*   dst       = (const int*)d_in[3];
    const float* We1 = (const float*)d_in[4];
    const float* be1 = (const float*)d_in[5];
    const float* We2 = (const float*)d_in[6];
    const float* be2 = (const float*)d_in[7];
    const float* Wx1 = (const float*)d_in[8];
    const float* bx1 = (const float*)d_in[9];
    const float* Wx2 = (const float*)d_in[10];
    const float* Wn1 = (const float*)d_in[11];
    const float* bn1 = (const float*)d_in[12];
    const float* Wn2 = (const float*)d_in[13];
    const float* bn2 = (const float*)d_in[14];

    float* out_h = (float*)d_out;
    float* out_x = out_h + (size_t)N_NODES * 64;

    // ---- fast-path workspace layout ----
    char* ws = (char*)d_ws;
    size_t off = 0;
    auto take = [&](size_t bytes) { char* p = ws + off; off = (off + bytes + 255) & ~(size_t)255; return p; };

    __bf16* msg_h   = (__bf16*)take((size_t)N_EDGES * 64 * 2);
    float4* msg_x   = (float4*)take((size_t)N_EDGES * 16);
    int*    perm    = (int*)take((size_t)N_EDGES * 4);
    int*    offsets = (int*)take((size_t)(N_NODES + 1) * 4);
    int*    cursor  = (int*)take((size_t)N_NODES * 4);
    int*    cnt     = (int*)take((size_t)N_NODES * 4);
    int*    excl    = (int*)take((size_t)N_NODES * 4);
    int*    bsum    = (int*)take(1024);
    int*    bpre    = (int*)take(1024);
    __bf16* We1p    = (__bf16*)take(64 * 128 * 2);
    __bf16* We2p    = (__bf16*)take(64 * 64 * 2);
    __bf16* Wx1p    = (__bf16*)take(64 * 64 * 2);
    __bf16* Wn1p    = (__bf16*)take(64 * 128 * 2);
    __bf16* Wn2p    = (__bf16*)take(64 * 64 * 2);
    const size_t needed = off;

    if (ws_size >= needed) {
        // ======== fast path: CSR gather, no f32 atomics ========
        hipMemsetAsync(cnt, 0, (size_t)N_NODES * 4, stream);
        pack_weights<<<32, 256, 0, stream>>>(We1, We2, Wx1, Wn1, Wn2,
                                             We1p, We2p, Wx1p, Wn1p, Wn2p);
        const int nb = (N_NODES + 255) / 256;   // 196
        hist_kernel<<<(N_EDGES + 255) / 256, 256, 0, stream>>>(dst, cnt);
        scan1_kernel<<<nb, 256, 0, stream>>>(cnt, excl, bsum);
        scan2_kernel<<<1, 256, 0, stream>>>(bsum, bpre, nb);
        scan3_kernel<<<nb, 256, 0, stream>>>(excl, bpre, offsets, cursor);
        fill_kernel<<<(N_EDGES + 255) / 256, 256, 0, stream>>>(dst, cursor, perm);

        egnn_edge_mfma_v2<<<N_EDGES / 64, 256, 0, stream>>>(
            node_feat, coord, src, dst,
            We1, be1, be2, bx1, Wx2,
            We1p, We2p, Wx1p,
            msg_h, msg_x);

        egnn_node_mfma<<<(N_NODES + 63) / 64, 256, 0, stream>>>(
            node_feat, coord, offsets, perm, msg_h, msg_x,
            bn1, bn2, Wn1p, Wn2p, out_h, out_x);
    } else {
        // ======== fallback: round-2 atomic path ========
        float* h_neigh = (float*)d_ws;                       // [N,64]
        float* x_sum   = h_neigh + (size_t)N_NODES * 64;     // [N,3]
        float* deg     = x_sum + (size_t)N_NODES * 3;        // [N]
        __bf16* fWe1p  = (__bf16*)(deg + N_NODES);
        __bf16* fWe2p  = fWe1p + 64 * 128;
        __bf16* fWx1p  = fWe2p + 64 * 64;
        __bf16* fWn1p  = fWx1p + 64 * 64;
        __bf16* fWn2p  = fWn1p + 64 * 128;

        hipMemsetAsync(d_ws, 0, (size_t)N_NODES * 68 * sizeof(float), stream);
        pack_weights<<<32, 256, 0, stream>>>(We1, We2, Wx1, Wn1, Wn2,
                                             fWe1p, fWe2p, fWx1p, fWn1p, fWn2p);
        egnn_edge_mfma_atomic<<<N_EDGES / 64, 256, 0, stream>>>(
            node_feat, coord, src, dst,
            We1, be1, be2, bx1, Wx2,
            fWe1p, fWe2p, fWx1p,
            h_neigh, x_sum, deg);
        egnn_node_kernel<<<(N_NODES + 63) / 64, 256, 0, stream>>>(
            node_feat, coord, Wn1, bn1, Wn2, bn2,
            h_neigh, x_sum, deg, out_h, out_x);
    }
}

// Round 4
// 376.493 us; speedup vs baseline: 1.8500x; 1.0388x over previous
//
#include <hip/hip_runtime.h>
#include <math.h>

#define N_NODES 50000
#define N_EDGES 800000
#define EPS_F 1e-30f

typedef __bf16 bf16x8 __attribute__((ext_vector_type(8)));
typedef __bf16 bf16x4 __attribute__((ext_vector_type(4)));
typedef float  f32x4  __attribute__((ext_vector_type(4)));

#define STR1 136   // 128-wide bf16 tile row stride (272B)
#define STR2 72    // 64-wide bf16 tile row stride (144B)

__device__ __forceinline__ float silu_f(float x) {
    return x / (1.0f + __expf(-x));
}

// ---------------- weight packing: W[k][n] f32 -> Wp[n][k] bf16 ----------------
__global__ void pack_weights(const float* __restrict__ We1,
                             const float* __restrict__ We2,
                             const float* __restrict__ Wx1,
                             const float* __restrict__ Wn1,
                             const float* __restrict__ Wn2,
                             __bf16* __restrict__ We1p,   // [64][128]
                             __bf16* __restrict__ We2p,   // [64][64]
                             __bf16* __restrict__ Wx1p,   // [64][64]
                             __bf16* __restrict__ Wn1p,   // [64][128]
                             __bf16* __restrict__ Wn2p)   // [64][64]
{
    const int t = blockIdx.x * 256 + threadIdx.x;
    for (int i = t; i < 64 * 128; i += gridDim.x * 256) {
        const int n = i >> 7, k = i & 127;
        We1p[i] = (__bf16)We1[k * 64 + n];
        Wn1p[i] = (__bf16)Wn1[k * 64 + n];
    }
    for (int i = t; i < 64 * 64; i += gridDim.x * 256) {
        const int n = i >> 6, k = i & 63;
        We2p[i] = (__bf16)We2[k * 64 + n];
        Wx1p[i] = (__bf16)Wx1[k * 64 + n];
        Wn2p[i] = (__bf16)Wn2[k * 64 + n];
    }
}

// ---------------- CSR build ----------------
__global__ void hist_kernel(const int* __restrict__ dst, int* __restrict__ cnt) {
    const int e = blockIdx.x * 256 + threadIdx.x;
    if (e < N_EDGES) atomicAdd(&cnt[dst[e]], 1);
}

__global__ void scan1_kernel(const int* __restrict__ cnt,
                             int* __restrict__ excl, int* __restrict__ bsum) {
    __shared__ int s[256];
    const int tid = threadIdx.x;
    const int i = blockIdx.x * 256 + tid;
    const int v = (i < N_NODES) ? cnt[i] : 0;
    s[tid] = v; __syncthreads();
#pragma unroll
    for (int off = 1; off < 256; off <<= 1) {
        int t = (tid >= off) ? s[tid - off] : 0;
        __syncthreads();
        s[tid] += t;
        __syncthreads();
    }
    if (i < N_NODES) excl[i] = s[tid] - v;
    if (tid == 255) bsum[blockIdx.x] = s[255];
}

__global__ void scan2_kernel(int* __restrict__ bsum, int* __restrict__ bpre, int nb) {
    __shared__ int s[256];
    const int tid = threadIdx.x;
    const int v = (tid < nb) ? bsum[tid] : 0;
    s[tid] = v; __syncthreads();
#pragma unroll
    for (int off = 1; off < 256; off <<= 1) {
        int t = (tid >= off) ? s[tid - off] : 0;
        __syncthreads();
        s[tid] += t;
        __syncthreads();
    }
    if (tid < nb) bpre[tid] = s[tid] - v;
}

__global__ void scan3_kernel(const int* __restrict__ excl, const int* __restrict__ bpre,
                             int* __restrict__ offsets, int* __restrict__ cursor) {
    const int i = blockIdx.x * 256 + threadIdx.x;
    if (i < N_NODES) {
        const int o = bpre[blockIdx.x] + excl[i];
        offsets[i] = o;
        cursor[i] = o;
    }
    if (blockIdx.x == 0 && threadIdx.x == 0) offsets[N_NODES] = N_EDGES;
}

__global__ void fill_kernel(const int* __restrict__ dst,
                            int* __restrict__ cursor, int* __restrict__ perm) {
    const int e = blockIdx.x * 256 + threadIdx.x;
    if (e < N_EDGES) {
        const int p = atomicAdd(&cursor[dst[e]], 1);
        perm[p] = e;
    }
}

// ---------------- edge kernel (fast path): perm-ordered, MFMA ----------------
__global__ __launch_bounds__(256, 5)
void egnn_edge_mfma_v3(const float* __restrict__ node_feat,
                       const float* __restrict__ coord,
                       const int* __restrict__ src,
                       const int* __restrict__ dst,
                       const int* __restrict__ perm,
                       const float* __restrict__ We1,   // row 128 (radial) f32
                       const float* __restrict__ be1,
                       const float* __restrict__ be2,
                       const float* __restrict__ bx1,
                       const float* __restrict__ Wx2,
                       const __bf16* __restrict__ We1p,
                       const __bf16* __restrict__ We2p,
                       const __bf16* __restrict__ Wx1p,
                       __bf16* __restrict__ msg_h,      // [E*64] bf16, perm order
                       float4* __restrict__ msg_x)      // [E], perm order
{
    __shared__ __bf16 sFb[64 * STR1];
    __shared__ __bf16 sT [64 * STR2];
    __shared__ float  sRad[64];
    __shared__ float  sXd[64][3];
    __bf16* const sM = sFb;   // sFb dead after layer-1 barrier; reuse as msg tile

    const int t  = threadIdx.x;
    const int j0 = blockIdx.x * 64;     // E = 12500 * 64

    // ---- gather (dst-sorted: dst rows ~16x reused, L1-hot) ----
    {
        const int e = t >> 2, sub = t & 3;
        const int ge = perm[j0 + e];
        const int gs = src[ge];
        const int gd = dst[ge];
        const float4* rs = (const float4*)(node_feat + (size_t)gs * 64) + sub * 4;
        const float4* rd = (const float4*)(node_feat + (size_t)gd * 64) + sub * 4;
#pragma unroll
        for (int q = 0; q < 4; ++q) {
            float4 a = rs[q];
            float4 b = rd[q];
            *(bf16x4*)&sFb[e * STR1 + sub * 16 + 4 * q] =
                (bf16x4){(__bf16)a.x, (__bf16)a.y, (__bf16)a.z, (__bf16)a.w};
            *(bf16x4*)&sFb[e * STR1 + 64 + sub * 16 + 4 * q] =
                (bf16x4){(__bf16)b.x, (__bf16)b.y, (__bf16)b.z, (__bf16)b.w};
        }
    }
    if (t < 64) {
        const int e  = t;
        const int ge = perm[j0 + e];
        const int gs = src[ge];
        const int gd = dst[ge];
        float dx = coord[(size_t)gs * 3 + 0] - coord[(size_t)gd * 3 + 0];
        float dy = coord[(size_t)gs * 3 + 1] - coord[(size_t)gd * 3 + 1];
        float dz = coord[(size_t)gs * 3 + 2] - coord[(size_t)gd * 3 + 2];
        float radial = dx * dx + dy * dy + dz * dz;
        sRad[e] = radial;
        float inv = 1.0f / (sqrtf(radial) + EPS_F);
        sXd[e][0] = dx * inv; sXd[e][1] = dy * inv; sXd[e][2] = dz * inv;
    }
    __syncthreads();

    const int lane = t & 63;
    const int w    = t >> 6;
    const int lr   = lane & 15;
    const int lk   = lane >> 4;

    f32x4 acc[4];

    // ---- layer 1 ----
    {
#pragma unroll
        for (int nt = 0; nt < 4; ++nt) {
            const int col = nt * 16 + lr;
            const float b0 = be1[col];
            const float wr = We1[128 * 64 + col];
#pragma unroll
            for (int r = 0; r < 4; ++r)
                acc[nt][r] = b0 + sRad[w * 16 + lk * 4 + r] * wr;
        }
        const int arow = w * 16 + lr;
#pragma unroll
        for (int ks = 0; ks < 4; ++ks) {
            bf16x8 a = *(const bf16x8*)&sFb[arow * STR1 + ks * 32 + lk * 8];
#pragma unroll
            for (int nt = 0; nt < 4; ++nt) {
                bf16x8 b = *(const bf16x8*)&We1p[(nt * 16 + lr) * 128 + ks * 32 + lk * 8];
                acc[nt] = __builtin_amdgcn_mfma_f32_16x16x32_bf16(a, b, acc[nt], 0, 0, 0);
            }
        }
#pragma unroll
        for (int nt = 0; nt < 4; ++nt) {
            const int col = nt * 16 + lr;
#pragma unroll
            for (int r = 0; r < 4; ++r) {
                const int row = w * 16 + lk * 4 + r;
                sT[row * STR2 + col] = (__bf16)silu_f(acc[nt][r]);
            }
        }
    }
    __syncthreads();   // sT ready; sFb reads done -> sM (alias) may be written

    // ---- layer 2 -> msg_h tile (sM aliases sFb) ----
    {
#pragma unroll
        for (int nt = 0; nt < 4; ++nt) {
            const float b0 = be2[nt * 16 + lr];
            acc[nt] = (f32x4){b0, b0, b0, b0};
        }
        const int arow = w * 16 + lr;
#pragma unroll
        for (int ks = 0; ks < 2; ++ks) {
            bf16x8 a = *(const bf16x8*)&sT[arow * STR2 + ks * 32 + lk * 8];
#pragma unroll
            for (int nt = 0; nt < 4; ++nt) {
                bf16x8 b = *(const bf16x8*)&We2p[(nt * 16 + lr) * 64 + ks * 32 + lk * 8];
                acc[nt] = __builtin_amdgcn_mfma_f32_16x16x32_bf16(a, b, acc[nt], 0, 0, 0);
            }
        }
#pragma unroll
        for (int nt = 0; nt < 4; ++nt) {
            const int col = nt * 16 + lr;
#pragma unroll
            for (int r = 0; r < 4; ++r) {
                const int row = w * 16 + lk * 4 + r;
                sM[row * STR2 + col] = (__bf16)silu_f(acc[nt][r]);
            }
        }
    }
    __syncthreads();

    // ---- coalesced msg_h store (contiguous at j) ----
    {
        const int r = t >> 2, q = t & 3;
        bf16x8 v0 = *(const bf16x8*)&sM[r * STR2 + q * 16];
        bf16x8 v1 = *(const bf16x8*)&sM[r * STR2 + q * 16 + 8];
        *(bf16x8*)&msg_h[(size_t)(j0 + r) * 64 + q * 16]     = v0;
        *(bf16x8*)&msg_h[(size_t)(j0 + r) * 64 + q * 16 + 8] = v1;
    }

    // ---- layer 3: coef -> msg_x (contiguous at j) ----
    {
#pragma unroll
        for (int nt = 0; nt < 4; ++nt) {
            const float b0 = bx1[nt * 16 + lr];
            acc[nt] = (f32x4){b0, b0, b0, b0};
        }
        const int arow = w * 16 + lr;
#pragma unroll
        for (int ks = 0; ks < 2; ++ks) {
            bf16x8 a = *(const bf16x8*)&sM[arow * STR2 + ks * 32 + lk * 8];
#pragma unroll
            for (int nt = 0; nt < 4; ++nt) {
                bf16x8 b = *(const bf16x8*)&Wx1p[(nt * 16 + lr) * 64 + ks * 32 + lk * 8];
                acc[nt] = __builtin_amdgcn_mfma_f32_16x16x32_bf16(a, b, acc[nt], 0, 0, 0);
            }
        }
        float p[4] = {0.f, 0.f, 0.f, 0.f};
#pragma unroll
        for (int nt = 0; nt < 4; ++nt) {
            const float wv = Wx2[nt * 16 + lr];
#pragma unroll
            for (int r = 0; r < 4; ++r)
                p[r] += silu_f(acc[nt][r]) * wv;
        }
#pragma unroll
        for (int off = 1; off < 16; off <<= 1)
#pragma unroll
            for (int r = 0; r < 4; ++r)
                p[r] += __shfl_xor(p[r], off);
        if (lr == 0) {
#pragma unroll
            for (int r = 0; r < 4; ++r) {
                const int e = w * 16 + lk * 4 + r;
                const float coef = p[r];
                msg_x[j0 + e] = make_float4(coef * sXd[e][0], coef * sXd[e][1],
                                            coef * sXd[e][2], 0.0f);
            }
        }
    }
}

// ---------------- node kernel (fast path): streaming CSR + MFMA MLP ----------------
__global__ __launch_bounds__(256, 5)
void egnn_node_mfma_v3(const float* __restrict__ node_feat,
                       const float* __restrict__ coord,
                       const int* __restrict__ offsets,
                       const __bf16* __restrict__ msg_h,   // perm order: contiguous per node
                       const float4* __restrict__ msg_x,
                       const float* __restrict__ bn1,
                       const float* __restrict__ bn2,
                       const __bf16* __restrict__ Wn1p,
                       const __bf16* __restrict__ Wn2p,
                       float* __restrict__ out_h,
                       float* __restrict__ out_x)
{
    __shared__ __bf16 sFb[64 * STR1];   // [node_feat | h_neigh] bf16
    __shared__ __bf16 sT [64 * STR2];

    const int t  = threadIdx.x;
    const int n0 = blockIdx.x * 64;
    const int r  = t >> 2, q = t & 3;
    const int n  = n0 + r;
    const bool valid = (n < N_NODES);

    // node_feat -> sFb[r][q*16 .. +16]
    {
        if (valid) {
            const float4* rowsrc = (const float4*)(node_feat + (size_t)n * 64) + q * 4;
#pragma unroll
            for (int k = 0; k < 4; ++k) {
                float4 a = rowsrc[k];
                *(bf16x4*)&sFb[r * STR1 + q * 16 + 4 * k] =
                    (bf16x4){(__bf16)a.x, (__bf16)a.y, (__bf16)a.z, (__bf16)a.w};
            }
        } else {
#pragma unroll
            for (int k = 0; k < 4; ++k)
                *(bf16x4*)&sFb[r * STR1 + q * 16 + 4 * k] = (bf16x4){0, 0, 0, 0};
        }
    }

    // streaming gather-reduce of this node's contiguous segment
    {
        const int beg = valid ? offsets[n] : 0;
        const int end = valid ? offsets[n + 1] : 0;
        float facc[16];
#pragma unroll
        for (int i = 0; i < 16; ++i) facc[i] = 0.0f;
        float xa = 0.f, xb = 0.f, xc = 0.f;

        for (int j = beg; j < end; ++j) {
            bf16x8 v0 = *(const bf16x8*)&msg_h[(size_t)j * 64 + q * 16];
            bf16x8 v1 = *(const bf16x8*)&msg_h[(size_t)j * 64 + q * 16 + 8];
#pragma unroll
            for (int i = 0; i < 8; ++i) facc[i]     += (float)v0[i];
#pragma unroll
            for (int i = 0; i < 8; ++i) facc[8 + i] += (float)v1[i];
            if (q == 0) {
                float4 mx = msg_x[j];
                xa += mx.x; xb += mx.y; xc += mx.z;
            }
        }
#pragma unroll
        for (int i = 0; i < 16; ++i)
            sFb[r * STR1 + 64 + q * 16 + i] = (__bf16)facc[i];

        if (q == 0 && valid) {
            const float d = (float)(end - beg);
            const float inv = 1.0f / fmaxf(d, 1.0f);
            out_x[(size_t)n * 3 + 0] = coord[(size_t)n * 3 + 0] + xa * inv;
            out_x[(size_t)n * 3 + 1] = coord[(size_t)n * 3 + 1] + xb * inv;
            out_x[(size_t)n * 3 + 2] = coord[(size_t)n * 3 + 2] + xc * inv;
        }
    }
    __syncthreads();

    const int lane = t & 63;
    const int w    = t >> 6;
    const int lr   = lane & 15;
    const int lk   = lane >> 4;

    f32x4 acc[4];

    // ---- node layer 1 (K=128) ----
    {
#pragma unroll
        for (int nt = 0; nt < 4; ++nt) {
            const float b0 = bn1[nt * 16 + lr];
            acc[nt] = (f32x4){b0, b0, b0, b0};
        }
        const int arow = w * 16 + lr;
#pragma unroll
        for (int ks = 0; ks < 4; ++ks) {
            bf16x8 a = *(const bf16x8*)&sFb[arow * STR1 + ks * 32 + lk * 8];
#pragma unroll
            for (int nt = 0; nt < 4; ++nt) {
                bf16x8 b = *(const bf16x8*)&Wn1p[(nt * 16 + lr) * 128 + ks * 32 + lk * 8];
                acc[nt] = __builtin_amdgcn_mfma_f32_16x16x32_bf16(a, b, acc[nt], 0, 0, 0);
            }
        }
#pragma unroll
        for (int nt = 0; nt < 4; ++nt) {
            const int col = nt * 16 + lr;
#pragma unroll
            for (int rr = 0; rr < 4; ++rr) {
                const int row = w * 16 + lk * 4 + rr;
                sT[row * STR2 + col] = (__bf16)silu_f(acc[nt][rr]);
            }
        }
    }
    __syncthreads();

    // ---- node layer 2 (K=64) -> sOut (aliases sFb) ----
    float* sOut = (float*)sFb;   // 64 rows x 68 f32 (stride 272B)
    {
#pragma unroll
        for (int nt = 0; nt < 4; ++nt) {
            const float b0 = bn2[nt * 16 + lr];
            acc[nt] = (f32x4){b0, b0, b0, b0};
        }
        const int arow = w * 16 + lr;
#pragma unroll
        for (int ks = 0; ks < 2; ++ks) {
            bf16x8 a = *(const bf16x8*)&sT[arow * STR2 + ks * 32 + lk * 8];
#pragma unroll
            for (int nt = 0; nt < 4; ++nt) {
                bf16x8 b = *(const bf16x8*)&Wn2p[(nt * 16 + lr) * 64 + ks * 32 + lk * 8];
                acc[nt] = __builtin_amdgcn_mfma_f32_16x16x32_bf16(a, b, acc[nt], 0, 0, 0);
            }
        }
        __syncthreads();   // all sFb reads (layer 1) done; safe to overwrite
#pragma unroll
        for (int nt = 0; nt < 4; ++nt) {
            const int col = nt * 16 + lr;
#pragma unroll
            for (int rr = 0; rr < 4; ++rr) {
                const int row = w * 16 + lk * 4 + rr;
                sOut[row * 68 + col] = acc[nt][rr];
            }
        }
    }
    __syncthreads();

    if (valid) {
#pragma unroll
        for (int k = 0; k < 4; ++k) {
            float4 v = *(const float4*)&sOut[r * 68 + q * 16 + 4 * k];
            *(float4*)&out_h[(size_t)n * 64 + q * 16 + 4 * k] = v;
        }
    }
}

// ================= fallback path (atomics, round-2 proven) =================
__global__ __launch_bounds__(256, 4)
void egnn_edge_mfma_atomic(const float* __restrict__ node_feat,
                           const float* __restrict__ coord,
                           const int* __restrict__ src,
                           const int* __restrict__ dst,
                           const float* __restrict__ We1,
                           const float* __restrict__ be1,
                           const float* __restrict__ be2,
                           const float* __restrict__ bx1,
                           const float* __restrict__ Wx2,
                           const __bf16* __restrict__ We1p,
                           const __bf16* __restrict__ We2p,
                           const __bf16* __restrict__ Wx1p,
                           float* __restrict__ h_neigh,
                           float* __restrict__ x_sum,
                           float* __restrict__ deg)
{
    __shared__ __bf16 sFb[64 * STR1];
    __shared__ __bf16 sT [64 * STR2];
    __shared__ __bf16 sM [64 * STR2];
    __shared__ float  sRad[64];
    __shared__ float  sXd[64][3];
    __shared__ int    sDst[64];

    const int t  = threadIdx.x;
    const int e0 = blockIdx.x * 64;

    {
        const int e = t >> 2, sub = t & 3;
        const int gs = src[e0 + e];
        const int gd = dst[e0 + e];
        const float4* rs = (const float4*)(node_feat + (size_t)gs * 64) + sub * 4;
        const float4* rd = (const float4*)(node_feat + (size_t)gd * 64) + sub * 4;
#pragma unroll
        for (int q = 0; q < 4; ++q) {
            float4 a = rs[q];
            float4 b = rd[q];
            *(bf16x4*)&sFb[e * STR1 + sub * 16 + 4 * q] =
                (bf16x4){(__bf16)a.x, (__bf16)a.y, (__bf16)a.z, (__bf16)a.w};
            *(bf16x4*)&sFb[e * STR1 + 64 + sub * 16 + 4 * q] =
                (bf16x4){(__bf16)b.x, (__bf16)b.y, (__bf16)b.z, (__bf16)b.w};
        }
    }
    if (t < 64) {
        const int e  = t;
        const int gs = src[e0 + e];
        const int gd = dst[e0 + e];
        float dx = coord[(size_t)gs * 3 + 0] - coord[(size_t)gd * 3 + 0];
        float dy = coord[(size_t)gs * 3 + 1] - coord[(size_t)gd * 3 + 1];
        float dz = coord[(size_t)gs * 3 + 2] - coord[(size_t)gd * 3 + 2];
        float radial = dx * dx + dy * dy + dz * dz;
        sRad[e] = radial;
        float inv = 1.0f / (sqrtf(radial) + EPS_F);
        sXd[e][0] = dx * inv; sXd[e][1] = dy * inv; sXd[e][2] = dz * inv;
        sDst[e] = gd;
    }
    __syncthreads();

    const int lane = t & 63;
    const int w    = t >> 6;
    const int lr   = lane & 15;
    const int lk   = lane >> 4;

    f32x4 acc[4];
    {
#pragma unroll
        for (int nt = 0; nt < 4; ++nt) {
            const int col = nt * 16 + lr;
            const float b0 = be1[col];
            const float wr = We1[128 * 64 + col];
#pragma unroll
            for (int r = 0; r < 4; ++r)
                acc[nt][r] = b0 + sRad[w * 16 + lk * 4 + r] * wr;
        }
        const int arow = w * 16 + lr;
#pragma unroll
        for (int ks = 0; ks < 4; ++ks) {
            bf16x8 a = *(const bf16x8*)&sFb[arow * STR1 + ks * 32 + lk * 8];
#pragma unroll
            for (int nt = 0; nt < 4; ++nt) {
                bf16x8 b = *(const bf16x8*)&We1p[(nt * 16 + lr) * 128 + ks * 32 + lk * 8];
                acc[nt] = __builtin_amdgcn_mfma_f32_16x16x32_bf16(a, b, acc[nt], 0, 0, 0);
            }
        }
#pragma unroll
        for (int nt = 0; nt < 4; ++nt) {
            const int col = nt * 16 + lr;
#pragma unroll
            for (int r = 0; r < 4; ++r) {
                const int row = w * 16 + lk * 4 + r;
                sT[row * STR2 + col] = (__bf16)silu_f(acc[nt][r]);
            }
        }
    }
    __syncthreads();
    {
#pragma unroll
        for (int nt = 0; nt < 4; ++nt) {
            const float b0 = be2[nt * 16 + lr];
            acc[nt] = (f32x4){b0, b0, b0, b0};
        }
        const int arow = w * 16 + lr;
#pragma unroll
        for (int ks = 0; ks < 2; ++ks) {
            bf16x8 a = *(const bf16x8*)&sT[arow * STR2 + ks * 32 + lk * 8];
#pragma unroll
            for (int nt = 0; nt < 4; ++nt) {
                bf16x8 b = *(const bf16x8*)&We2p[(nt * 16 + lr) * 64 + ks * 32 + lk * 8];
                acc[nt] = __builtin_amdgcn_mfma_f32_16x16x32_bf16(a, b, acc[nt], 0, 0, 0);
            }
        }
#pragma unroll
        for (int nt = 0; nt < 4; ++nt) {
            const int col = nt * 16 + lr;
#pragma unroll
            for (int r = 0; r < 4; ++r) {
                const int row = w * 16 + lk * 4 + r;
                const float v = silu_f(acc[nt][r]);
                sM[row * STR2 + col] = (__bf16)v;
                atomicAdd(&h_neigh[(size_t)sDst[row] * 64 + col], v);
            }
        }
    }
    __syncthreads();
    {
#pragma unroll
        for (int nt = 0; nt < 4; ++nt) {
            const float b0 = bx1[nt * 16 + lr];
            acc[nt] = (f32x4){b0, b0, b0, b0};
        }
        const int arow = w * 16 + lr;
#pragma unroll
        for (int ks = 0; ks < 2; ++ks) {
            bf16x8 a = *(const bf16x8*)&sM[arow * STR2 + ks * 32 + lk * 8];
#pragma unroll
            for (int nt = 0; nt < 4; ++nt) {
                bf16x8 b = *(const bf16x8*)&Wx1p[(nt * 16 + lr) * 64 + ks * 32 + lk * 8];
                acc[nt] = __builtin_amdgcn_mfma_f32_16x16x32_bf16(a, b, acc[nt], 0, 0, 0);
            }
        }
        float p[4] = {0.f, 0.f, 0.f, 0.f};
#pragma unroll
        for (int nt = 0; nt < 4; ++nt) {
            const float wv = Wx2[nt * 16 + lr];
#pragma unroll
            for (int r = 0; r < 4; ++r)
                p[r] += silu_f(acc[nt][r]) * wv;
        }
#pragma unroll
        for (int off = 1; off < 16; off <<= 1)
#pragma unroll
            for (int r = 0; r < 4; ++r)
                p[r] += __shfl_xor(p[r], off);
        if (lr == 0) {
#pragma unroll
            for (int r = 0; r < 4; ++r) {
                const int e  = w * 16 + lk * 4 + r;
                const int gd = sDst[e];
                const float coef = p[r];
                atomicAdd(&x_sum[(size_t)gd * 3 + 0], coef * sXd[e][0]);
                atomicAdd(&x_sum[(size_t)gd * 3 + 1], coef * sXd[e][1]);
                atomicAdd(&x_sum[(size_t)gd * 3 + 2], coef * sXd[e][2]);
                atomicAdd(&deg[gd], 1.0f);
            }
        }
    }
}

template<int KDIM>
__device__ __forceinline__ void tile_gemm64(const float* __restrict__ A, int astride,
                                            const float* __restrict__ B,
                                            float acc[4][4], int t)
{
    const int tx = t & 15;
    const int ty = t >> 4;
#pragma unroll
    for (int i = 0; i < 4; ++i)
#pragma unroll
        for (int j = 0; j < 4; ++j) acc[i][j] = 0.0f;

    for (int k = 0; k < KDIM; k += 4) {
        float bv[4][4];
#pragma unroll
        for (int kk = 0; kk < 4; ++kk) {
            float4 bq = *(const float4*)(B + (size_t)(k + kk) * 64 + tx * 4);
            bv[kk][0] = bq.x; bv[kk][1] = bq.y; bv[kk][2] = bq.z; bv[kk][3] = bq.w;
        }
#pragma unroll
        for (int i = 0; i < 4; ++i) {
            float4 aq = *(const float4*)(A + (size_t)(ty * 4 + i) * astride + k);
            float av[4] = {aq.x, aq.y, aq.z, aq.w};
#pragma unroll
            for (int kk = 0; kk < 4; ++kk)
#pragma unroll
                for (int j = 0; j < 4; ++j)
                    acc[i][j] = fmaf(av[kk], bv[kk][j], acc[i][j]);
        }
    }
}

__global__ __launch_bounds__(256, 2)
void egnn_node_kernel(const float* __restrict__ node_feat,
                      const float* __restrict__ coord,
                      const float* __restrict__ Wn1, const float* __restrict__ bn1,
                      const float* __restrict__ Wn2, const float* __restrict__ bn2,
                      const float* __restrict__ h_neigh,
                      const float* __restrict__ x_sum,
                      const float* __restrict__ deg,
                      float* __restrict__ out_h,
                      float* __restrict__ out_x)
{
    __shared__ float sF[64][132];
    __shared__ float sT2[64][68];

    const int t  = threadIdx.x;
    const int n0 = blockIdx.x * 64;

    {
        const int r = t >> 2;
        const int sub = t & 3;
        const int n = n0 + r;
        if (n < N_NODES) {
            const float* rowsrc = (sub < 2) ? (node_feat + (size_t)n * 64 + sub * 32)
                                            : (h_neigh  + (size_t)n * 64 + (sub - 2) * 32);
#pragma unroll
            for (int q = 0; q < 8; ++q)
                *(float4*)&sF[r][sub * 32 + 4 * q] = *(const float4*)(rowsrc + 4 * q);
        } else {
#pragma unroll
            for (int q = 0; q < 8; ++q)
                *(float4*)&sF[r][sub * 32 + 4 * q] = make_float4(0.f, 0.f, 0.f, 0.f);
        }
    }
    __syncthreads();

    const int tx = t & 15;
    const int ty = t >> 4;
    float acc[4][4];

    tile_gemm64<128>(&sF[0][0], 132, Wn1, acc, t);
    {
        float4 bq = *(const float4*)(bn1 + tx * 4);
        float bv[4] = {bq.x, bq.y, bq.z, bq.w};
#pragma unroll
        for (int i = 0; i < 4; ++i) {
            float4 o;
            o.x = silu_f(acc[i][0] + bv[0]);
            o.y = silu_f(acc[i][1] + bv[1]);
            o.z = silu_f(acc[i][2] + bv[2]);
            o.w = silu_f(acc[i][3] + bv[3]);
            *(float4*)&sT2[ty * 4 + i][tx * 4] = o;
        }
    }
    __syncthreads();

    tile_gemm64<64>(&sT2[0][0], 68, Wn2, acc, t);
    {
        float4 bq = *(const float4*)(bn2 + tx * 4);
        float bv[4] = {bq.x, bq.y, bq.z, bq.w};
#pragma unroll
        for (int i = 0; i < 4; ++i) {
            const int n = n0 + ty * 4 + i;
            if (n < N_NODES) {
                float4 o;
                o.x = acc[i][0] + bv[0];
                o.y = acc[i][1] + bv[1];
                o.z = acc[i][2] + bv[2];
                o.w = acc[i][3] + bv[3];
                *(float4*)&out_h[(size_t)n * 64 + tx * 4] = o;
            }
        }
    }

    if (t < 64) {
        const int n = n0 + t;
        if (n < N_NODES) {
            const float d = deg[n];
            const float inv = 1.0f / fmaxf(d, 1.0f);
#pragma unroll
            for (int c = 0; c < 3; ++c)
                out_x[(size_t)n * 3 + c] = coord[(size_t)n * 3 + c]
                                         + x_sum[(size_t)n * 3 + c] * inv;
        }
    }
}

// ================= host =================
extern "C" void kernel_launch(void* const* d_in, const int* in_sizes, int n_in,
                              void* d_out, int out_size, void* d_ws, size_t ws_size,
                              hipStream_t stream) {
    const float* node_feat = (const float*)d_in[0];
    const float* coord     = (const float*)d_in[1];
    const int*   src       = (const int*)d_in[2];
    const int*   dst       = (const int*)d_in[3];
    const float* We1 = (const float*)d_in[4];
    const float* be1 = (const float*)d_in[5];
    const float* We2 = (const float*)d_in[6];
    const float* be2 = (const float*)d_in[7];
    const float* Wx1 = (const float*)d_in[8];
    const float* bx1 = (const float*)d_in[9];
    const float* Wx2 = (const float*)d_in[10];
    const float* Wn1 = (const float*)d_in[11];
    const float* bn1 = (const float*)d_in[12];
    const float* Wn2 = (const float*)d_in[13];
    const float* bn2 = (const float*)d_in[14];

    float* out_h = (float*)d_out;
    float* out_x = out_h + (size_t)N_NODES * 64;

    // ---- fast-path workspace layout ----
    char* ws = (char*)d_ws;
    size_t off = 0;
    auto take = [&](size_t bytes) { char* p = ws + off; off = (off + bytes + 255) & ~(size_t)255; return p; };

    __bf16* msg_h   = (__bf16*)take((size_t)N_EDGES * 64 * 2);
    float4* msg_x   = (float4*)take((size_t)N_EDGES * 16);
    int*    perm    = (int*)take((size_t)N_EDGES * 4);
    int*    offsets = (int*)take((size_t)(N_NODES + 1) * 4);
    int*    cursor  = (int*)take((size_t)N_NODES * 4);
    int*    cnt     = (int*)take((size_t)N_NODES * 4);
    int*    excl    = (int*)take((size_t)N_NODES * 4);
    int*    bsum    = (int*)take(1024);
    int*    bpre    = (int*)take(1024);
    __bf16* We1p    = (__bf16*)take(64 * 128 * 2);
    __bf16* We2p    = (__bf16*)take(64 * 64 * 2);
    __bf16* Wx1p    = (__bf16*)take(64 * 64 * 2);
    __bf16* Wn1p    = (__bf16*)take(64 * 128 * 2);
    __bf16* Wn2p    = (__bf16*)take(64 * 64 * 2);
    const size_t needed = off;

    if (ws_size >= needed) {
        // ======== fast path: perm-ordered edge pass, streaming node pass ========
        hipMemsetAsync(cnt, 0, (size_t)N_NODES * 4, stream);
        pack_weights<<<32, 256, 0, stream>>>(We1, We2, Wx1, Wn1, Wn2,
                                             We1p, We2p, Wx1p, Wn1p, Wn2p);
        const int nb = (N_NODES + 255) / 256;   // 196
        hist_kernel<<<(N_EDGES + 255) / 256, 256, 0, stream>>>(dst, cnt);
        scan1_kernel<<<nb, 256, 0, stream>>>(cnt, excl, bsum);
        scan2_kernel<<<1, 256, 0, stream>>>(bsum, bpre, nb);
        scan3_kernel<<<nb, 256, 0, stream>>>(excl, bpre, offsets, cursor);
        fill_kernel<<<(N_EDGES + 255) / 256, 256, 0, stream>>>(dst, cursor, perm);

        egnn_edge_mfma_v3<<<N_EDGES / 64, 256, 0, stream>>>(
            node_feat, coord, src, dst, perm,
            We1, be1, be2, bx1, Wx2,
            We1p, We2p, Wx1p,
            msg_h, msg_x);

        egnn_node_mfma_v3<<<(N_NODES + 63) / 64, 256, 0, stream>>>(
            node_feat, coord, offsets, msg_h, msg_x,
            bn1, bn2, Wn1p, Wn2p, out_h, out_x);
    } else {
        // ======== fallback: atomic path ========
        float* h_neigh = (float*)d_ws;                       // [N,64]
        float* x_sum   = h_neigh + (size_t)N_NODES * 64;     // [N,3]
        float* deg     = x_sum + (size_t)N_NODES * 3;        // [N]
        __bf16* fWe1p  = (__bf16*)(deg + N_NODES);
        __bf16* fWe2p  = fWe1p + 64 * 128;
        __bf16* fWx1p  = fWe2p + 64 * 64;
        __bf16* fWn1p  = fWx1p + 64 * 64;
        __bf16* fWn2p  = fWn1p + 64 * 128;

        hipMemsetAsync(d_ws, 0, (size_t)N_NODES * 68 * sizeof(float), stream);
        pack_weights<<<32, 256, 0, stream>>>(We1, We2, Wx1, Wn1, Wn2,
                                             fWe1p, fWe2p, fWx1p, fWn1p, fWn2p);
        egnn_edge_mfma_atomic<<<N_EDGES / 64, 256, 0, stream>>>(
            node_feat, coord, src, dst,
            We1, be1, be2, bx1, Wx2,
            fWe1p, fWe2p, fWx1p,
            h_neigh, x_sum, deg);
        egnn_node_kernel<<<(N_NODES + 63) / 64, 256, 0, stream>>>(
            node_feat, coord, Wn1, bn1, Wn2, bn2,
            h_neigh, x_sum, deg, out_h, out_x);
    }
}

// Round 5
// 334.094 us; speedup vs baseline: 2.0847x; 1.1269x over previous
//
#include <hip/hip_runtime.h>
#include <math.h>

#define N_NODES 50000
#define N_EDGES 800000
#define EPS_F 1e-30f

typedef __bf16 bf16x8 __attribute__((ext_vector_type(8)));
typedef __bf16 bf16x4 __attribute__((ext_vector_type(4)));
typedef float  f32x4  __attribute__((ext_vector_type(4)));

#define STR1 136   // 128-wide bf16 tile row stride (272B)
#define STR2 72    // 64-wide bf16 tile row stride (144B)

__device__ __forceinline__ float silu_f(float x) {
    return x / (1.0f + __expf(-x));
}

// ---------------- prologue: pack weights bf16-T + convert node_feat ----------------
__global__ void prep_kernel(const float* __restrict__ node_feat,
                            const float* __restrict__ We1,
                            const float* __restrict__ We2,
                            const float* __restrict__ Wx1,
                            const float* __restrict__ Wn1,
                            const float* __restrict__ Wn2,
                            __bf16* __restrict__ nfb,    // [N*64]
                            __bf16* __restrict__ We1p,   // [64][128]
                            __bf16* __restrict__ We2p,   // [64][64]
                            __bf16* __restrict__ Wx1p,   // [64][64]
                            __bf16* __restrict__ Wn1p,   // [64][128]
                            __bf16* __restrict__ Wn2p)   // [64][64]
{
    const int t = blockIdx.x * 256 + threadIdx.x;
    const int stride = gridDim.x * 256;
    for (int i = t; i < N_NODES * 64; i += stride)
        nfb[i] = (__bf16)node_feat[i];
    for (int i = t; i < 64 * 128; i += stride) {
        const int n = i >> 7, k = i & 127;
        We1p[i] = (__bf16)We1[k * 64 + n];
        Wn1p[i] = (__bf16)Wn1[k * 64 + n];
    }
    for (int i = t; i < 64 * 64; i += stride) {
        const int n = i >> 6, k = i & 63;
        We2p[i] = (__bf16)We2[k * 64 + n];
        Wx1p[i] = (__bf16)Wx1[k * 64 + n];
        Wn2p[i] = (__bf16)Wn2[k * 64 + n];
    }
}

// ---------------- CSR build ----------------
__global__ void hist_kernel(const int* __restrict__ dst, int* __restrict__ cnt) {
    const int e = blockIdx.x * 256 + threadIdx.x;
    if (e < N_EDGES) atomicAdd(&cnt[dst[e]], 1);
}

__global__ void scan1_kernel(const int* __restrict__ cnt,
                             int* __restrict__ excl, int* __restrict__ bsum) {
    __shared__ int s[256];
    const int tid = threadIdx.x;
    const int i = blockIdx.x * 256 + tid;
    const int v = (i < N_NODES) ? cnt[i] : 0;
    s[tid] = v; __syncthreads();
#pragma unroll
    for (int off = 1; off < 256; off <<= 1) {
        int t = (tid >= off) ? s[tid - off] : 0;
        __syncthreads();
        s[tid] += t;
        __syncthreads();
    }
    if (i < N_NODES) excl[i] = s[tid] - v;
    if (tid == 255) bsum[blockIdx.x] = s[255];
}

__global__ void scan2_kernel(int* __restrict__ bsum, int* __restrict__ bpre, int nb) {
    __shared__ int s[256];
    const int tid = threadIdx.x;
    const int v = (tid < nb) ? bsum[tid] : 0;
    s[tid] = v; __syncthreads();
#pragma unroll
    for (int off = 1; off < 256; off <<= 1) {
        int t = (tid >= off) ? s[tid - off] : 0;
        __syncthreads();
        s[tid] += t;
        __syncthreads();
    }
    if (tid < nb) bpre[tid] = s[tid] - v;
}

__global__ void scan3_kernel(const int* __restrict__ excl, const int* __restrict__ bpre,
                             int* __restrict__ offsets, int* __restrict__ cursor) {
    const int i = blockIdx.x * 256 + threadIdx.x;
    if (i < N_NODES) {
        const int o = bpre[blockIdx.x] + excl[i];
        offsets[i] = o;
        cursor[i] = o;
    }
    if (blockIdx.x == 0 && threadIdx.x == 0) offsets[N_NODES] = N_EDGES;
}

// fill: scatter-materialize src ids, dst ids and edge geometry in dst-sorted order
__global__ void fill_v2(const int* __restrict__ src, const int* __restrict__ dst,
                        const float* __restrict__ coord,
                        int* __restrict__ cursor,
                        int* __restrict__ src_p, int* __restrict__ dst_p,
                        float4* __restrict__ geom) {
    const int e = blockIdx.x * 256 + threadIdx.x;
    if (e < N_EDGES) {
        const int gs = src[e];
        const int gd = dst[e];
        const int p = atomicAdd(&cursor[gd], 1);
        src_p[p] = gs;
        dst_p[p] = gd;
        const float dx = coord[(size_t)gs * 3 + 0] - coord[(size_t)gd * 3 + 0];
        const float dy = coord[(size_t)gs * 3 + 1] - coord[(size_t)gd * 3 + 1];
        const float dz = coord[(size_t)gs * 3 + 2] - coord[(size_t)gd * 3 + 2];
        const float radial = dx * dx + dy * dy + dz * dz;
        const float inv = 1.0f / (sqrtf(radial) + EPS_F);
        geom[p] = make_float4(dx * inv, dy * inv, dz * inv, radial);
    }
}

// ---------------- edge kernel: MFMA MLP + in-block segment-reduce scatter ----------------
__global__ __launch_bounds__(256, 5)
void egnn_edge_mfma_v4(const __bf16* __restrict__ nfb,
                       const int* __restrict__ src_p,
                       const int* __restrict__ dst_p,
                       const float4* __restrict__ geom,
                       const float* __restrict__ We1,   // row 128 (radial) f32
                       const float* __restrict__ be1,
                       const float* __restrict__ be2,
                       const float* __restrict__ bx1,
                       const float* __restrict__ Wx2,
                       const __bf16* __restrict__ We1p,
                       const __bf16* __restrict__ We2p,
                       const __bf16* __restrict__ Wx1p,
                       float* __restrict__ h_neigh,     // [N*64] f32 accum
                       float* __restrict__ xs)          // [N*4]  f32 accum
{
    __shared__ __bf16 sFb[64 * STR1];
    __shared__ __bf16 sT [64 * STR2];
    __shared__ float  sRad[64];
    __shared__ float  sXd[64][3];
    __shared__ float  sCoef[64];
    __shared__ int    sDst[64];
    __bf16* const sM = sFb;   // sFb dead after layer-1 reads; reuse for msg tile

    const int t  = threadIdx.x;
    const int j0 = blockIdx.x * 64;     // E = 12500 * 64

    // ---- gather bf16 rows (all reads coalesced / L1-hot) ----
    {
        const int e = t >> 2, sub = t & 3;
        const int gs = src_p[j0 + e];
        const int gd = dst_p[j0 + e];
        const bf16x8* rs = (const bf16x8*)(nfb + (size_t)gs * 64) + sub * 2;
        const bf16x8* rd = (const bf16x8*)(nfb + (size_t)gd * 64) + sub * 2;
        *(bf16x8*)&sFb[e * STR1 + sub * 16]          = rs[0];
        *(bf16x8*)&sFb[e * STR1 + sub * 16 + 8]      = rs[1];
        *(bf16x8*)&sFb[e * STR1 + 64 + sub * 16]     = rd[0];
        *(bf16x8*)&sFb[e * STR1 + 64 + sub * 16 + 8] = rd[1];
    }
    if (t < 64) {
        const float4 g = geom[j0 + t];
        sXd[t][0] = g.x; sXd[t][1] = g.y; sXd[t][2] = g.z;
        sRad[t] = g.w;
        sDst[t] = dst_p[j0 + t];
    }
    __syncthreads();

    const int lane = t & 63;
    const int w    = t >> 6;
    const int lr   = lane & 15;
    const int lk   = lane >> 4;

    f32x4 acc[4];

    // ---- layer 1: [64,128]bf16 @ [128,64]bf16 + (be1 + radial*We1[128]) ----
    {
#pragma unroll
        for (int nt = 0; nt < 4; ++nt) {
            const int col = nt * 16 + lr;
            const float b0 = be1[col];
            const float wr = We1[128 * 64 + col];
#pragma unroll
            for (int r = 0; r < 4; ++r)
                acc[nt][r] = b0 + sRad[w * 16 + lk * 4 + r] * wr;
        }
        const int arow = w * 16 + lr;
#pragma unroll
        for (int ks = 0; ks < 4; ++ks) {
            bf16x8 a = *(const bf16x8*)&sFb[arow * STR1 + ks * 32 + lk * 8];
#pragma unroll
            for (int nt = 0; nt < 4; ++nt) {
                bf16x8 b = *(const bf16x8*)&We1p[(nt * 16 + lr) * 128 + ks * 32 + lk * 8];
                acc[nt] = __builtin_amdgcn_mfma_f32_16x16x32_bf16(a, b, acc[nt], 0, 0, 0);
            }
        }
#pragma unroll
        for (int nt = 0; nt < 4; ++nt) {
            const int col = nt * 16 + lr;
#pragma unroll
            for (int r = 0; r < 4; ++r) {
                const int row = w * 16 + lk * 4 + r;
                sT[row * STR2 + col] = (__bf16)silu_f(acc[nt][r]);
            }
        }
    }
    __syncthreads();   // sT ready; sFb reads done -> sM (alias) writable

    // ---- layer 2 -> msg tile sM (aliases sFb) ----
    {
#pragma unroll
        for (int nt = 0; nt < 4; ++nt) {
            const float b0 = be2[nt * 16 + lr];
            acc[nt] = (f32x4){b0, b0, b0, b0};
        }
        const int arow = w * 16 + lr;
#pragma unroll
        for (int ks = 0; ks < 2; ++ks) {
            bf16x8 a = *(const bf16x8*)&sT[arow * STR2 + ks * 32 + lk * 8];
#pragma unroll
            for (int nt = 0; nt < 4; ++nt) {
                bf16x8 b = *(const bf16x8*)&We2p[(nt * 16 + lr) * 64 + ks * 32 + lk * 8];
                acc[nt] = __builtin_amdgcn_mfma_f32_16x16x32_bf16(a, b, acc[nt], 0, 0, 0);
            }
        }
#pragma unroll
        for (int nt = 0; nt < 4; ++nt) {
            const int col = nt * 16 + lr;
#pragma unroll
            for (int r = 0; r < 4; ++r) {
                const int row = w * 16 + lk * 4 + r;
                sM[row * STR2 + col] = (__bf16)silu_f(acc[nt][r]);
            }
        }
    }
    __syncthreads();   // sM ready (read-only below)

    // ---- layer 3: coef per edge -> sCoef ----
    {
#pragma unroll
        for (int nt = 0; nt < 4; ++nt) {
            const float b0 = bx1[nt * 16 + lr];
            acc[nt] = (f32x4){b0, b0, b0, b0};
        }
        const int arow = w * 16 + lr;
#pragma unroll
        for (int ks = 0; ks < 2; ++ks) {
            bf16x8 a = *(const bf16x8*)&sM[arow * STR2 + ks * 32 + lk * 8];
#pragma unroll
            for (int nt = 0; nt < 4; ++nt) {
                bf16x8 b = *(const bf16x8*)&Wx1p[(nt * 16 + lr) * 64 + ks * 32 + lk * 8];
                acc[nt] = __builtin_amdgcn_mfma_f32_16x16x32_bf16(a, b, acc[nt], 0, 0, 0);
            }
        }
        float p[4] = {0.f, 0.f, 0.f, 0.f};
#pragma unroll
        for (int nt = 0; nt < 4; ++nt) {
            const float wv = Wx2[nt * 16 + lr];
#pragma unroll
            for (int r = 0; r < 4; ++r)
                p[r] += silu_f(acc[nt][r]) * wv;
        }
#pragma unroll
        for (int off = 1; off < 16; off <<= 1)
#pragma unroll
            for (int r = 0; r < 4; ++r)
                p[r] += __shfl_xor(p[r], off);
        if (lr == 0) {
#pragma unroll
            for (int r = 0; r < 4; ++r)
                sCoef[w * 16 + lk * 4 + r] = p[r];
        }
    }

    // ---- segment-reduce msg columns onto h_neigh (runs of equal dst) ----
    {
        const int j = t & 63, g = t >> 6;
        float accum = 0.0f;
        int cur = sDst[g * 16];
#pragma unroll
        for (int rr = 0; rr < 16; ++rr) {
            const int row = g * 16 + rr;
            const float v = (float)sM[row * STR2 + j];
            const int d = sDst[row];
            if (d != cur) {   // wave-uniform branch (depends only on row)
                atomicAdd(&h_neigh[(size_t)cur * 64 + j], accum);
                accum = 0.0f; cur = d;
            }
            accum += v;
        }
        atomicAdd(&h_neigh[(size_t)cur * 64 + j], accum);
    }
    __syncthreads();   // sCoef ready

    // ---- per-run head-walk: coef * x_hat -> xs ----
    if (t < 64) {
        const int e = t;
        const bool head = (e == 0) || (sDst[e] != sDst[e - 1]);
        if (head) {
            const int d = sDst[e];
            float sx = 0.f, sy = 0.f, sz = 0.f;
            int k = e;
            while (k < 64 && sDst[k] == d) {
                const float c = sCoef[k];
                sx += c * sXd[k][0];
                sy += c * sXd[k][1];
                sz += c * sXd[k][2];
                ++k;
            }
            atomicAdd(&xs[(size_t)d * 4 + 0], sx);
            atomicAdd(&xs[(size_t)d * 4 + 1], sy);
            atomicAdd(&xs[(size_t)d * 4 + 2], sz);
        }
    }
}

// ---------------- node kernel: streamed inputs + MFMA MLP ----------------
__global__ __launch_bounds__(256, 5)
void egnn_node_mfma_v4(const float* __restrict__ node_feat,
                       const float* __restrict__ coord,
                       const int* __restrict__ offsets,
                       const float* __restrict__ h_neigh,   // [N*64] f32
                       const float4* __restrict__ xs,       // [N]
                       const float* __restrict__ bn1,
                       const float* __restrict__ bn2,
                       const __bf16* __restrict__ Wn1p,
                       const __bf16* __restrict__ Wn2p,
                       float* __restrict__ out_h,
                       float* __restrict__ out_x)
{
    __shared__ __bf16 sFb[64 * STR1];   // [node_feat | h_neigh] bf16
    __shared__ __bf16 sT [64 * STR2];

    const int t  = threadIdx.x;
    const int n0 = blockIdx.x * 64;
    const int r  = t >> 2, q = t & 3;
    const int n  = n0 + r;
    const bool valid = (n < N_NODES);

    // [node_feat | h_neigh] rows -> bf16 tile (coalesced streams)
    {
        if (valid) {
            const float4* rf = (const float4*)(node_feat + (size_t)n * 64) + q * 4;
            const float4* rh = (const float4*)(h_neigh  + (size_t)n * 64) + q * 4;
#pragma unroll
            for (int k = 0; k < 4; ++k) {
                float4 a = rf[k];
                float4 b = rh[k];
                *(bf16x4*)&sFb[r * STR1 + q * 16 + 4 * k] =
                    (bf16x4){(__bf16)a.x, (__bf16)a.y, (__bf16)a.z, (__bf16)a.w};
                *(bf16x4*)&sFb[r * STR1 + 64 + q * 16 + 4 * k] =
                    (bf16x4){(__bf16)b.x, (__bf16)b.y, (__bf16)b.z, (__bf16)b.w};
            }
        } else {
#pragma unroll
            for (int k = 0; k < 4; ++k) {
                *(bf16x4*)&sFb[r * STR1 + q * 16 + 4 * k]      = (bf16x4){0, 0, 0, 0};
                *(bf16x4*)&sFb[r * STR1 + 64 + q * 16 + 4 * k] = (bf16x4){0, 0, 0, 0};
            }
        }
    }

    // coordinate update (deg free from CSR offsets)
    if (q == 0 && valid) {
        const int deg = offsets[n + 1] - offsets[n];
        const float inv = 1.0f / fmaxf((float)deg, 1.0f);
        const float4 xv = xs[n];
        out_x[(size_t)n * 3 + 0] = coord[(size_t)n * 3 + 0] + xv.x * inv;
        out_x[(size_t)n * 3 + 1] = coord[(size_t)n * 3 + 1] + xv.y * inv;
        out_x[(size_t)n * 3 + 2] = coord[(size_t)n * 3 + 2] + xv.z * inv;
    }
    __syncthreads();

    const int lane = t & 63;
    const int w    = t >> 6;
    const int lr   = lane & 15;
    const int lk   = lane >> 4;

    f32x4 acc[4];

    // ---- node layer 1 (K=128) ----
    {
#pragma unroll
        for (int nt = 0; nt < 4; ++nt) {
            const float b0 = bn1[nt * 16 + lr];
            acc[nt] = (f32x4){b0, b0, b0, b0};
        }
        const int arow = w * 16 + lr;
#pragma unroll
        for (int ks = 0; ks < 4; ++ks) {
            bf16x8 a = *(const bf16x8*)&sFb[arow * STR1 + ks * 32 + lk * 8];
#pragma unroll
            for (int nt = 0; nt < 4; ++nt) {
                bf16x8 b = *(const bf16x8*)&Wn1p[(nt * 16 + lr) * 128 + ks * 32 + lk * 8];
                acc[nt] = __builtin_amdgcn_mfma_f32_16x16x32_bf16(a, b, acc[nt], 0, 0, 0);
            }
        }
#pragma unroll
        for (int nt = 0; nt < 4; ++nt) {
            const int col = nt * 16 + lr;
#pragma unroll
            for (int rr = 0; rr < 4; ++rr) {
                const int row = w * 16 + lk * 4 + rr;
                sT[row * STR2 + col] = (__bf16)silu_f(acc[nt][rr]);
            }
        }
    }
    __syncthreads();

    // ---- node layer 2 (K=64) -> sOut (aliases sFb) ----
    float* sOut = (float*)sFb;   // 64 rows x 68 f32 (row stride 272B)
    {
#pragma unroll
        for (int nt = 0; nt < 4; ++nt) {
            const float b0 = bn2[nt * 16 + lr];
            acc[nt] = (f32x4){b0, b0, b0, b0};
        }
        const int arow = w * 16 + lr;
#pragma unroll
        for (int ks = 0; ks < 2; ++ks) {
            bf16x8 a = *(const bf16x8*)&sT[arow * STR2 + ks * 32 + lk * 8];
#pragma unroll
            for (int nt = 0; nt < 4; ++nt) {
                bf16x8 b = *(const bf16x8*)&Wn2p[(nt * 16 + lr) * 64 + ks * 32 + lk * 8];
                acc[nt] = __builtin_amdgcn_mfma_f32_16x16x32_bf16(a, b, acc[nt], 0, 0, 0);
            }
        }
        __syncthreads();   // all sFb reads done; safe to overwrite
#pragma unroll
        for (int nt = 0; nt < 4; ++nt) {
            const int col = nt * 16 + lr;
#pragma unroll
            for (int rr = 0; rr < 4; ++rr) {
                const int row = w * 16 + lk * 4 + rr;
                sOut[row * 68 + col] = acc[nt][rr];
            }
        }
    }
    __syncthreads();

    if (valid) {
#pragma unroll
        for (int k = 0; k < 4; ++k) {
            float4 v = *(const float4*)&sOut[r * 68 + q * 16 + 4 * k];
            *(float4*)&out_h[(size_t)n * 64 + q * 16 + 4 * k] = v;
        }
    }
}

// ================= fallback path (atomics, round-2 proven) =================
__global__ __launch_bounds__(256, 4)
void egnn_edge_mfma_atomic(const float* __restrict__ node_feat,
                           const float* __restrict__ coord,
                           const int* __restrict__ src,
                           const int* __restrict__ dst,
                           const float* __restrict__ We1,
                           const float* __restrict__ be1,
                           const float* __restrict__ be2,
                           const float* __restrict__ bx1,
                           const float* __restrict__ Wx2,
                           const __bf16* __restrict__ We1p,
                           const __bf16* __restrict__ We2p,
                           const __bf16* __restrict__ Wx1p,
                           float* __restrict__ h_neigh,
                           float* __restrict__ x_sum,
                           float* __restrict__ deg)
{
    __shared__ __bf16 sFb[64 * STR1];
    __shared__ __bf16 sT [64 * STR2];
    __shared__ __bf16 sM [64 * STR2];
    __shared__ float  sRad[64];
    __shared__ float  sXd[64][3];
    __shared__ int    sDst[64];

    const int t  = threadIdx.x;
    const int e0 = blockIdx.x * 64;

    {
        const int e = t >> 2, sub = t & 3;
        const int gs = src[e0 + e];
        const int gd = dst[e0 + e];
        const float4* rs = (const float4*)(node_feat + (size_t)gs * 64) + sub * 4;
        const float4* rd = (const float4*)(node_feat + (size_t)gd * 64) + sub * 4;
#pragma unroll
        for (int q = 0; q < 4; ++q) {
            float4 a = rs[q];
            float4 b = rd[q];
            *(bf16x4*)&sFb[e * STR1 + sub * 16 + 4 * q] =
                (bf16x4){(__bf16)a.x, (__bf16)a.y, (__bf16)a.z, (__bf16)a.w};
            *(bf16x4*)&sFb[e * STR1 + 64 + sub * 16 + 4 * q] =
                (bf16x4){(__bf16)b.x, (__bf16)b.y, (__bf16)b.z, (__bf16)b.w};
        }
    }
    if (t < 64) {
        const int e  = t;
        const int gs = src[e0 + e];
        const int gd = dst[e0 + e];
        float dx = coord[(size_t)gs * 3 + 0] - coord[(size_t)gd * 3 + 0];
        float dy = coord[(size_t)gs * 3 + 1] - coord[(size_t)gd * 3 + 1];
        float dz = coord[(size_t)gs * 3 + 2] - coord[(size_t)gd * 3 + 2];
        float radial = dx * dx + dy * dy + dz * dz;
        sRad[e] = radial;
        float inv = 1.0f / (sqrtf(radial) + EPS_F);
        sXd[e][0] = dx * inv; sXd[e][1] = dy * inv; sXd[e][2] = dz * inv;
        sDst[e] = gd;
    }
    __syncthreads();

    const int lane = t & 63;
    const int w    = t >> 6;
    const int lr   = lane & 15;
    const int lk   = lane >> 4;

    f32x4 acc[4];
    {
#pragma unroll
        for (int nt = 0; nt < 4; ++nt) {
            const int col = nt * 16 + lr;
            const float b0 = be1[col];
            const float wr = We1[128 * 64 + col];
#pragma unroll
            for (int r = 0; r < 4; ++r)
                acc[nt][r] = b0 + sRad[w * 16 + lk * 4 + r] * wr;
        }
        const int arow = w * 16 + lr;
#pragma unroll
        for (int ks = 0; ks < 4; ++ks) {
            bf16x8 a = *(const bf16x8*)&sFb[arow * STR1 + ks * 32 + lk * 8];
#pragma unroll
            for (int nt = 0; nt < 4; ++nt) {
                bf16x8 b = *(const bf16x8*)&We1p[(nt * 16 + lr) * 128 + ks * 32 + lk * 8];
                acc[nt] = __builtin_amdgcn_mfma_f32_16x16x32_bf16(a, b, acc[nt], 0, 0, 0);
            }
        }
#pragma unroll
        for (int nt = 0; nt < 4; ++nt) {
            const int col = nt * 16 + lr;
#pragma unroll
            for (int r = 0; r < 4; ++r) {
                const int row = w * 16 + lk * 4 + r;
                sT[row * STR2 + col] = (__bf16)silu_f(acc[nt][r]);
            }
        }
    }
    __syncthreads();
    {
#pragma unroll
        for (int nt = 0; nt < 4; ++nt) {
            const float b0 = be2[nt * 16 + lr];
            acc[nt] = (f32x4){b0, b0, b0, b0};
        }
        const int arow = w * 16 + lr;
#pragma unroll
        for (int ks = 0; ks < 2; ++ks) {
            bf16x8 a = *(const bf16x8*)&sT[arow * STR2 + ks * 32 + lk * 8];
#pragma unroll
            for (int nt = 0; nt < 4; ++nt) {
                bf16x8 b = *(const bf16x8*)&We2p[(nt * 16 + lr) * 64 + ks * 32 + lk * 8];
                acc[nt] = __builtin_amdgcn_mfma_f32_16x16x32_bf16(a, b, acc[nt], 0, 0, 0);
            }
        }
#pragma unroll
        for (int nt = 0; nt < 4; ++nt) {
            const int col = nt * 16 + lr;
#pragma unroll
            for (int r = 0; r < 4; ++r) {
                const int row = w * 16 + lk * 4 + r;
                const float v = silu_f(acc[nt][r]);
                sM[row * STR2 + col] = (__bf16)v;
                atomicAdd(&h_neigh[(size_t)sDst[row] * 64 + col], v);
            }
        }
    }
    __syncthreads();
    {
#pragma unroll
        for (int nt = 0; nt < 4; ++nt) {
            const float b0 = bx1[nt * 16 + lr];
            acc[nt] = (f32x4){b0, b0, b0, b0};
        }
        const int arow = w * 16 + lr;
#pragma unroll
        for (int ks = 0; ks < 2; ++ks) {
            bf16x8 a = *(const bf16x8*)&sM[arow * STR2 + ks * 32 + lk * 8];
#pragma unroll
            for (int nt = 0; nt < 4; ++nt) {
                bf16x8 b = *(const bf16x8*)&Wx1p[(nt * 16 + lr) * 64 + ks * 32 + lk * 8];
                acc[nt] = __builtin_amdgcn_mfma_f32_16x16x32_bf16(a, b, acc[nt], 0, 0, 0);
            }
        }
        float p[4] = {0.f, 0.f, 0.f, 0.f};
#pragma unroll
        for (int nt = 0; nt < 4; ++nt) {
            const float wv = Wx2[nt * 16 + lr];
#pragma unroll
            for (int r = 0; r < 4; ++r)
                p[r] += silu_f(acc[nt][r]) * wv;
        }
#pragma unroll
        for (int off = 1; off < 16; off <<= 1)
#pragma unroll
            for (int r = 0; r < 4; ++r)
                p[r] += __shfl_xor(p[r], off);
        if (lr == 0) {
#pragma unroll
            for (int r = 0; r < 4; ++r) {
                const int e  = w * 16 + lk * 4 + r;
                const int gd = sDst[e];
                const float coef = p[r];
                atomicAdd(&x_sum[(size_t)gd * 3 + 0], coef * sXd[e][0]);
                atomicAdd(&x_sum[(size_t)gd * 3 + 1], coef * sXd[e][1]);
                atomicAdd(&x_sum[(size_t)gd * 3 + 2], coef * sXd[e][2]);
                atomicAdd(&deg[gd], 1.0f);
            }
        }
    }
}

template<int KDIM>
__device__ __forceinline__ void tile_gemm64(const float* __restrict__ A, int astride,
                                            const float* __restrict__ B,
                                            float acc[4][4], int t)
{
    const int tx = t & 15;
    const int ty = t >> 4;
#pragma unroll
    for (int i = 0; i < 4; ++i)
#pragma unroll
        for (int j = 0; j < 4; ++j) acc[i][j] = 0.0f;

    for (int k = 0; k < KDIM; k += 4) {
        float bv[4][4];
#pragma unroll
        for (int kk = 0; kk < 4; ++kk) {
            float4 bq = *(const float4*)(B + (size_t)(k + kk) * 64 + tx * 4);
            bv[kk][0] = bq.x; bv[kk][1] = bq.y; bv[kk][2] = bq.z; bv[kk][3] = bq.w;
        }
#pragma unroll
        for (int i = 0; i < 4; ++i) {
            float4 aq = *(const float4*)(A + (size_t)(ty * 4 + i) * astride + k);
            float av[4] = {aq.x, aq.y, aq.z, aq.w};
#pragma unroll
            for (int kk = 0; kk < 4; ++kk)
#pragma unroll
                for (int j = 0; j < 4; ++j)
                    acc[i][j] = fmaf(av[kk], bv[kk][j], acc[i][j]);
        }
    }
}

__global__ __launch_bounds__(256, 2)
void egnn_node_kernel(const float* __restrict__ node_feat,
                      const float* __restrict__ coord,
                      const float* __restrict__ Wn1, const float* __restrict__ bn1,
                      const float* __restrict__ Wn2, const float* __restrict__ bn2,
                      const float* __restrict__ h_neigh,
                      const float* __restrict__ x_sum,
                      const float* __restrict__ deg,
                      float* __restrict__ out_h,
                      float* __restrict__ out_x)
{
    __shared__ float sF[64][132];
    __shared__ float sT2[64][68];

    const int t  = threadIdx.x;
    const int n0 = blockIdx.x * 64;

    {
        const int r = t >> 2;
        const int sub = t & 3;
        const int n = n0 + r;
        if (n < N_NODES) {
            const float* rowsrc = (sub < 2) ? (node_feat + (size_t)n * 64 + sub * 32)
                                            : (h_neigh  + (size_t)n * 64 + (sub - 2) * 32);
#pragma unroll
            for (int q = 0; q < 8; ++q)
                *(float4*)&sF[r][sub * 32 + 4 * q] = *(const float4*)(rowsrc + 4 * q);
        } else {
#pragma unroll
            for (int q = 0; q < 8; ++q)
                *(float4*)&sF[r][sub * 32 + 4 * q] = make_float4(0.f, 0.f, 0.f, 0.f);
        }
    }
    __syncthreads();

    const int tx = t & 15;
    const int ty = t >> 4;
    float acc[4][4];

    tile_gemm64<128>(&sF[0][0], 132, Wn1, acc, t);
    {
        float4 bq = *(const float4*)(bn1 + tx * 4);
        float bv[4] = {bq.x, bq.y, bq.z, bq.w};
#pragma unroll
        for (int i = 0; i < 4; ++i) {
            float4 o;
            o.x = silu_f(acc[i][0] + bv[0]);
            o.y = silu_f(acc[i][1] + bv[1]);
            o.z = silu_f(acc[i][2] + bv[2]);
            o.w = silu_f(acc[i][3] + bv[3]);
            *(float4*)&sT2[ty * 4 + i][tx * 4] = o;
        }
    }
    __syncthreads();

    tile_gemm64<64>(&sT2[0][0], 68, Wn2, acc, t);
    {
        float4 bq = *(const float4*)(bn2 + tx * 4);
        float bv[4] = {bq.x, bq.y, bq.z, bq.w};
#pragma unroll
        for (int i = 0; i < 4; ++i) {
            const int n = n0 + ty * 4 + i;
            if (n < N_NODES) {
                float4 o;
                o.x = acc[i][0] + bv[0];
                o.y = acc[i][1] + bv[1];
                o.z = acc[i][2] + bv[2];
                o.w = acc[i][3] + bv[3];
                *(float4*)&out_h[(size_t)n * 64 + tx * 4] = o;
            }
        }
    }

    if (t < 64) {
        const int n = n0 + t;
        if (n < N_NODES) {
            const float d = deg[n];
            const float inv = 1.0f / fmaxf(d, 1.0f);
#pragma unroll
            for (int c = 0; c < 3; ++c)
                out_x[(size_t)n * 3 + c] = coord[(size_t)n * 3 + c]
                                         + x_sum[(size_t)n * 3 + c] * inv;
        }
    }
}

// ================= host =================
extern "C" void kernel_launch(void* const* d_in, const int* in_sizes, int n_in,
                              void* d_out, int out_size, void* d_ws, size_t ws_size,
                              hipStream_t stream) {
    const float* node_feat = (const float*)d_in[0];
    const float* coord     = (const float*)d_in[1];
    const int*   src       = (const int*)d_in[2];
    const int*   dst       = (const int*)d_in[3];
    const float* We1 = (const float*)d_in[4];
    const float* be1 = (const float*)d_in[5];
    const float* We2 = (const float*)d_in[6];
    const float* be2 = (const float*)d_in[7];
    const float* Wx1 = (const float*)d_in[8];
    const float* bx1 = (const float*)d_in[9];
    const float* Wx2 = (const float*)d_in[10];
    const float* Wn1 = (const float*)d_in[11];
    const float* bn1 = (const float*)d_in[12];
    const float* Wn2 = (const float*)d_in[13];
    const float* bn2 = (const float*)d_in[14];

    float* out_h = (float*)d_out;
    float* out_x = out_h + (size_t)N_NODES * 64;

    // ---- workspace layout (fast path) ----
    char* ws = (char*)d_ws;
    size_t off = 0;
    auto take = [&](size_t bytes) { char* p = ws + off; off = (off + bytes + 255) & ~(size_t)255; return p; };

    float*  h_neigh = (float*)take((size_t)N_NODES * 64 * 4);   // 12.8MB (zeroed)
    float*  xs      = (float*)take((size_t)N_NODES * 16);       // 800KB  (zeroed, contiguous w/ h_neigh)
    int*    src_p   = (int*)take((size_t)N_EDGES * 4);
    int*    dst_p   = (int*)take((size_t)N_EDGES * 4);
    float4* geom    = (float4*)take((size_t)N_EDGES * 16);
    __bf16* nfb     = (__bf16*)take((size_t)N_NODES * 64 * 2);
    int*    offsets = (int*)take((size_t)(N_NODES + 1) * 4);
    int*    cursor  = (int*)take((size_t)N_NODES * 4);
    int*    cnt     = (int*)take((size_t)N_NODES * 4);
    int*    excl    = (int*)take((size_t)N_NODES * 4);
    int*    bsum    = (int*)take(1024);
    int*    bpre    = (int*)take(1024);
    __bf16* We1p    = (__bf16*)take(64 * 128 * 2);
    __bf16* We2p    = (__bf16*)take(64 * 64 * 2);
    __bf16* Wx1p    = (__bf16*)take(64 * 64 * 2);
    __bf16* Wn1p    = (__bf16*)take(64 * 128 * 2);
    __bf16* Wn2p    = (__bf16*)take(64 * 64 * 2);
    const size_t needed = off;

    if (ws_size >= needed) {
        // zero accumulators (h_neigh + xs are contiguous) and histogram
        hipMemsetAsync(h_neigh, 0, (size_t)N_NODES * 64 * 4 + (size_t)N_NODES * 16, stream);
        hipMemsetAsync(cnt, 0, (size_t)N_NODES * 4, stream);

        prep_kernel<<<2048, 256, 0, stream>>>(node_feat, We1, We2, Wx1, Wn1, Wn2,
                                              nfb, We1p, We2p, Wx1p, Wn1p, Wn2p);
        const int nb = (N_NODES + 255) / 256;   // 196
        hist_kernel<<<(N_EDGES + 255) / 256, 256, 0, stream>>>(dst, cnt);
        scan1_kernel<<<nb, 256, 0, stream>>>(cnt, excl, bsum);
        scan2_kernel<<<1, 256, 0, stream>>>(bsum, bpre, nb);
        scan3_kernel<<<nb, 256, 0, stream>>>(excl, bpre, offsets, cursor);
        fill_v2<<<(N_EDGES + 255) / 256, 256, 0, stream>>>(src, dst, coord, cursor,
                                                           src_p, dst_p, geom);

        egnn_edge_mfma_v4<<<N_EDGES / 64, 256, 0, stream>>>(
            nfb, src_p, dst_p, geom,
            We1, be1, be2, bx1, Wx2,
            We1p, We2p, Wx1p,
            h_neigh, xs);

        egnn_node_mfma_v4<<<(N_NODES + 63) / 64, 256, 0, stream>>>(
            node_feat, coord, offsets, h_neigh, (const float4*)xs,
            bn1, bn2, Wn1p, Wn2p, out_h, out_x);
    } else {
        // ======== fallback: atomic path ========
        float* fh_neigh = (float*)d_ws;                        // [N,64]
        float* fx_sum   = fh_neigh + (size_t)N_NODES * 64;     // [N,3]
        float* fdeg     = fx_sum + (size_t)N_NODES * 3;        // [N]
        __bf16* fnfb    = (__bf16*)(fdeg + N_NODES);
        __bf16* fWe1p   = fnfb + (size_t)N_NODES * 64;
        __bf16* fWe2p   = fWe1p + 64 * 128;
        __bf16* fWx1p   = fWe2p + 64 * 64;
        __bf16* fWn1p   = fWx1p + 64 * 64;
        __bf16* fWn2p   = fWn1p + 64 * 128;

        hipMemsetAsync(d_ws, 0, (size_t)N_NODES * 68 * sizeof(float), stream);
        prep_kernel<<<2048, 256, 0, stream>>>(node_feat, We1, We2, Wx1, Wn1, Wn2,
                                              fnfb, fWe1p, fWe2p, fWx1p, fWn1p, fWn2p);
        egnn_edge_mfma_atomic<<<N_EDGES / 64, 256, 0, stream>>>(
            node_feat, coord, src, dst,
            We1, be1, be2, bx1, Wx2,
            fWe1p, fWe2p, fWx1p,
            fh_neigh, fx_sum, fdeg);
        egnn_node_kernel<<<(N_NODES + 63) / 64, 256, 0, stream>>>(
            node_feat, coord, Wn1, bn1, Wn2, bn2,
            fh_neigh, fx_sum, fdeg, out_h, out_x);
    }
}

// Round 6
// 331.782 us; speedup vs baseline: 2.0993x; 1.0070x over previous
//
#include <hip/hip_runtime.h>
#include <math.h>

#define N_NODES 50000
#define N_EDGES 800000
#define EPS_F 1e-30f

typedef __bf16 bf16x8 __attribute__((ext_vector_type(8)));
typedef __bf16 bf16x4 __attribute__((ext_vector_type(4)));
typedef float  f32x4  __attribute__((ext_vector_type(4)));

#define STR1 136   // 128-wide bf16 tile row stride (fallback kernels)
#define STR2 72    // 64-wide bf16 tile row stride (144B)

__device__ __forceinline__ float silu_f(float x) {
    return x / (1.0f + __expf(-x));
}

__device__ __forceinline__ bf16x8 cvt8(float4 u0, float4 u1) {
    return (bf16x8){(__bf16)u0.x, (__bf16)u0.y, (__bf16)u0.z, (__bf16)u0.w,
                    (__bf16)u1.x, (__bf16)u1.y, (__bf16)u1.z, (__bf16)u1.w};
}

// ---------------- prologue: pack weights bf16-T + convert node_feat ----------------
__global__ void prep_kernel(const float* __restrict__ node_feat,
                            const float* __restrict__ We1,
                            const float* __restrict__ We2,
                            const float* __restrict__ Wx1,
                            const float* __restrict__ Wn1,
                            const float* __restrict__ Wn2,
                            __bf16* __restrict__ nfb,    // [N*64]
                            __bf16* __restrict__ We1p,   // [64][128]
                            __bf16* __restrict__ We2p,   // [64][64]
                            __bf16* __restrict__ Wx1p,   // [64][64]
                            __bf16* __restrict__ Wn1p,   // [64][128]
                            __bf16* __restrict__ Wn2p)   // [64][64]
{
    const int t = blockIdx.x * 256 + threadIdx.x;
    const int stride = gridDim.x * 256;
    for (int i = t; i < N_NODES * 64; i += stride)
        nfb[i] = (__bf16)node_feat[i];
    for (int i = t; i < 64 * 128; i += stride) {
        const int n = i >> 7, k = i & 127;
        We1p[i] = (__bf16)We1[k * 64 + n];
        Wn1p[i] = (__bf16)Wn1[k * 64 + n];
    }
    for (int i = t; i < 64 * 64; i += stride) {
        const int n = i >> 6, k = i & 63;
        We2p[i] = (__bf16)We2[k * 64 + n];
        Wx1p[i] = (__bf16)Wx1[k * 64 + n];
        Wn2p[i] = (__bf16)Wn2[k * 64 + n];
    }
}

// ---------------- CSR build ----------------
__global__ void hist_kernel(const int* __restrict__ dst, int* __restrict__ cnt) {
    const int e = blockIdx.x * 256 + threadIdx.x;
    if (e < N_EDGES) atomicAdd(&cnt[dst[e]], 1);
}

__global__ void scan1_kernel(const int* __restrict__ cnt,
                             int* __restrict__ excl, int* __restrict__ bsum) {
    __shared__ int s[256];
    const int tid = threadIdx.x;
    const int i = blockIdx.x * 256 + tid;
    const int v = (i < N_NODES) ? cnt[i] : 0;
    s[tid] = v; __syncthreads();
#pragma unroll
    for (int off = 1; off < 256; off <<= 1) {
        int t = (tid >= off) ? s[tid - off] : 0;
        __syncthreads();
        s[tid] += t;
        __syncthreads();
    }
    if (i < N_NODES) excl[i] = s[tid] - v;
    if (tid == 255) bsum[blockIdx.x] = s[255];
}

__global__ void scan2_kernel(int* __restrict__ bsum, int* __restrict__ bpre, int nb) {
    __shared__ int s[256];
    const int tid = threadIdx.x;
    const int v = (tid < nb) ? bsum[tid] : 0;
    s[tid] = v; __syncthreads();
#pragma unroll
    for (int off = 1; off < 256; off <<= 1) {
        int t = (tid >= off) ? s[tid - off] : 0;
        __syncthreads();
        s[tid] += t;
        __syncthreads();
    }
    if (tid < nb) bpre[tid] = s[tid] - v;
}

__global__ void scan3_kernel(const int* __restrict__ excl, const int* __restrict__ bpre,
                             int* __restrict__ offsets, int* __restrict__ cursor) {
    const int i = blockIdx.x * 256 + threadIdx.x;
    if (i < N_NODES) {
        const int o = bpre[blockIdx.x] + excl[i];
        offsets[i] = o;
        cursor[i] = o;
    }
    if (blockIdx.x == 0 && threadIdx.x == 0) offsets[N_NODES] = N_EDGES;
}

__global__ void fill_v2(const int* __restrict__ src, const int* __restrict__ dst,
                        const float* __restrict__ coord,
                        int* __restrict__ cursor,
                        int* __restrict__ src_p, int* __restrict__ dst_p,
                        float4* __restrict__ geom) {
    const int e = blockIdx.x * 256 + threadIdx.x;
    if (e < N_EDGES) {
        const int gs = src[e];
        const int gd = dst[e];
        const int p = atomicAdd(&cursor[gd], 1);
        src_p[p] = gs;
        dst_p[p] = gd;
        const float dx = coord[(size_t)gs * 3 + 0] - coord[(size_t)gd * 3 + 0];
        const float dy = coord[(size_t)gs * 3 + 1] - coord[(size_t)gd * 3 + 1];
        const float dz = coord[(size_t)gs * 3 + 2] - coord[(size_t)gd * 3 + 2];
        const float radial = dx * dx + dy * dy + dz * dz;
        const float inv = 1.0f / (sqrtf(radial) + EPS_F);
        geom[p] = make_float4(dx * inv, dy * inv, dz * inv, radial);
    }
}

// ---------------- edge kernel v5: barrier-free, reg A-fragments ----------------
__global__ __launch_bounds__(256, 8)
void egnn_edge_mfma_v5(const __bf16* __restrict__ nfb,
                       const int* __restrict__ src_p,
                       const int* __restrict__ dst_p,
                       const float4* __restrict__ geom,
                       const float* __restrict__ We1,   // row 128 (radial) f32
                       const float* __restrict__ be1,
                       const float* __restrict__ be2,
                       const float* __restrict__ bx1,
                       const float* __restrict__ Wx2,
                       const __bf16* __restrict__ We1p,
                       const __bf16* __restrict__ We2p,
                       const __bf16* __restrict__ Wx1p,
                       float* __restrict__ h_neigh,     // [N*64] f32 accum
                       float* __restrict__ xs)          // [N*4]  f32 accum
{
    // all LDS below is WAVE-PRIVATE (each wave touches only rows w*16..w*16+15)
    __shared__ __bf16 sT[64 * STR2];
    __shared__ __bf16 sM[64 * STR2];
    __shared__ float  sCoef[64];

    const int t    = threadIdx.x;
    const int lane = t & 63;
    const int w    = t >> 6;
    const int lr   = lane & 15;
    const int lk   = lane >> 4;
    const int j0   = blockIdx.x * 64;     // E = 12500*64, no tail
    const int myrow = w * 16 + lr;

    const int gs = src_p[j0 + myrow];
    const int gd = dst_p[j0 + myrow];

    // A-fragments straight to registers (exact MFMA layout)
    const bf16x8 aS0 = *(const bf16x8*)(nfb + (size_t)gs * 64 + lk * 8);
    const bf16x8 aS1 = *(const bf16x8*)(nfb + (size_t)gs * 64 + 32 + lk * 8);
    const bf16x8 aD0 = *(const bf16x8*)(nfb + (size_t)gd * 64 + lk * 8);
    const bf16x8 aD1 = *(const bf16x8*)(nfb + (size_t)gd * 64 + 32 + lk * 8);

    float rad[4];
#pragma unroll
    for (int r = 0; r < 4; ++r)
        rad[r] = ((const float*)geom)[(size_t)(j0 + w * 16 + lk * 4 + r) * 4 + 3];

    f32x4 acc[4];

    // ---- layer 1: bias + radial column, then K=128 MFMA ----
#pragma unroll
    for (int nt = 0; nt < 4; ++nt) {
        const int col = nt * 16 + lr;
        const float b0 = be1[col];
        const float wr = We1[128 * 64 + col];
#pragma unroll
        for (int r = 0; r < 4; ++r)
            acc[nt][r] = b0 + rad[r] * wr;
    }
#pragma unroll
    for (int nt = 0; nt < 4; ++nt) {
        const __bf16* bp = We1p + (size_t)(nt * 16 + lr) * 128 + lk * 8;
        acc[nt] = __builtin_amdgcn_mfma_f32_16x16x32_bf16(aS0, *(const bf16x8*)(bp),      acc[nt], 0, 0, 0);
        acc[nt] = __builtin_amdgcn_mfma_f32_16x16x32_bf16(aS1, *(const bf16x8*)(bp + 32), acc[nt], 0, 0, 0);
        acc[nt] = __builtin_amdgcn_mfma_f32_16x16x32_bf16(aD0, *(const bf16x8*)(bp + 64), acc[nt], 0, 0, 0);
        acc[nt] = __builtin_amdgcn_mfma_f32_16x16x32_bf16(aD1, *(const bf16x8*)(bp + 96), acc[nt], 0, 0, 0);
    }
#pragma unroll
    for (int nt = 0; nt < 4; ++nt) {
        const int col = nt * 16 + lr;
#pragma unroll
        for (int r = 0; r < 4; ++r)
            sT[(w * 16 + lk * 4 + r) * STR2 + col] = (__bf16)silu_f(acc[nt][r]);
    }
    // no barrier: sT rows w*16.. are wave-private; per-wave LDS is in-order

    // ---- layer 2: K=64 -> msg tile sM ----
    {
        const bf16x8 a0 = *(const bf16x8*)&sT[myrow * STR2 + lk * 8];
        const bf16x8 a1 = *(const bf16x8*)&sT[myrow * STR2 + 32 + lk * 8];
#pragma unroll
        for (int nt = 0; nt < 4; ++nt) {
            const float b0 = be2[nt * 16 + lr];
            acc[nt] = (f32x4){b0, b0, b0, b0};
            const __bf16* bp = We2p + (size_t)(nt * 16 + lr) * 64 + lk * 8;
            acc[nt] = __builtin_amdgcn_mfma_f32_16x16x32_bf16(a0, *(const bf16x8*)(bp),      acc[nt], 0, 0, 0);
            acc[nt] = __builtin_amdgcn_mfma_f32_16x16x32_bf16(a1, *(const bf16x8*)(bp + 32), acc[nt], 0, 0, 0);
        }
#pragma unroll
        for (int nt = 0; nt < 4; ++nt) {
            const int col = nt * 16 + lr;
#pragma unroll
            for (int r = 0; r < 4; ++r)
                sM[(w * 16 + lk * 4 + r) * STR2 + col] = (__bf16)silu_f(acc[nt][r]);
        }
    }

    // ---- layer 3: coef per edge -> sCoef (wave-private) ----
    {
        const bf16x8 a0 = *(const bf16x8*)&sM[myrow * STR2 + lk * 8];
        const bf16x8 a1 = *(const bf16x8*)&sM[myrow * STR2 + 32 + lk * 8];
#pragma unroll
        for (int nt = 0; nt < 4; ++nt) {
            const float b0 = bx1[nt * 16 + lr];
            acc[nt] = (f32x4){b0, b0, b0, b0};
            const __bf16* bp = Wx1p + (size_t)(nt * 16 + lr) * 64 + lk * 8;
            acc[nt] = __builtin_amdgcn_mfma_f32_16x16x32_bf16(a0, *(const bf16x8*)(bp),      acc[nt], 0, 0, 0);
            acc[nt] = __builtin_amdgcn_mfma_f32_16x16x32_bf16(a1, *(const bf16x8*)(bp + 32), acc[nt], 0, 0, 0);
        }
        float p[4] = {0.f, 0.f, 0.f, 0.f};
#pragma unroll
        for (int nt = 0; nt < 4; ++nt) {
            const float wv = Wx2[nt * 16 + lr];
#pragma unroll
            for (int r = 0; r < 4; ++r)
                p[r] += silu_f(acc[nt][r]) * wv;
        }
#pragma unroll
        for (int off = 1; off < 16; off <<= 1)
#pragma unroll
            for (int r = 0; r < 4; ++r)
                p[r] += __shfl_xor(p[r], off);
        if (lr == 0) {
#pragma unroll
            for (int r = 0; r < 4; ++r)
                sCoef[w * 16 + lk * 4 + r] = p[r];
        }
    }

    // ---- column segment-reduce of msg onto h_neigh (wave-private) ----
    {
        float accum = 0.0f;
        int cur = __shfl(gd, 0);
#pragma unroll
        for (int rr = 0; rr < 16; ++rr) {
            const int d = __shfl(gd, rr);     // dst of row w*16+rr (lane rr holds it)
            const float v = (float)sM[(w * 16 + rr) * STR2 + lane];
            if (d != cur) {                   // wave-uniform branch
                atomicAdd(&h_neigh[(size_t)cur * 64 + lane], accum);
                accum = 0.0f; cur = d;
            }
            accum += v;
        }
        atomicAdd(&h_neigh[(size_t)cur * 64 + lane], accum);
    }

    // ---- xs: in-wave segmented shuffle-reduce over the 16-row group ----
    {
        const float c = sCoef[w * 16 + lr];       // wave-private, in-order LDS
        const float4 g = geom[j0 + w * 16 + lr];
        float vx = c * g.x, vy = c * g.y, vz = c * g.z;
        const int d = gd;                          // dst of row w*16+lr
#pragma unroll
        for (int off = 1; off < 16; off <<= 1) {
            const int   od = __shfl(d,  lane + off);
            const float ox = __shfl(vx, lane + off);
            const float oy = __shfl(vy, lane + off);
            const float oz = __shfl(vz, lane + off);
            if ((lr + off < 16) && (od == d)) { vx += ox; vy += oy; vz += oz; }
        }
        const int pd = __shfl(d, lane - 1);
        const bool head = (lr == 0) || (pd != d);
        if (head && lk == 0) {
            atomicAdd(&xs[(size_t)d * 4 + 0], vx);
            atomicAdd(&xs[(size_t)d * 4 + 1], vy);
            atomicAdd(&xs[(size_t)d * 4 + 2], vz);
        }
    }
}

// ---------------- node kernel v5: reg A-fragments, direct stores ----------------
__global__ __launch_bounds__(256, 8)
void egnn_node_mfma_v5(const __bf16* __restrict__ nfb,
                       const float* __restrict__ coord,
                       const int* __restrict__ offsets,
                       const float* __restrict__ h_neigh,   // [N*64] f32
                       const float4* __restrict__ xs,       // [N]
                       const float* __restrict__ bn1,
                       const float* __restrict__ bn2,
                       const __bf16* __restrict__ Wn1p,
                       const __bf16* __restrict__ Wn2p,
                       float* __restrict__ out_h,
                       float* __restrict__ out_x)
{
    __shared__ __bf16 sT[64 * STR2];   // wave-private slices

    const int t    = threadIdx.x;
    const int lane = t & 63;
    const int w    = t >> 6;
    const int lr   = lane & 15;
    const int lk   = lane >> 4;
    const int n0   = blockIdx.x * 64;
    const int myrow = n0 + w * 16 + lr;
    const bool valid = (myrow < N_NODES);

    const bf16x8 zf = {(__bf16)0.f, (__bf16)0.f, (__bf16)0.f, (__bf16)0.f,
                       (__bf16)0.f, (__bf16)0.f, (__bf16)0.f, (__bf16)0.f};

    bf16x8 a0 = zf, a1 = zf, a2 = zf, a3 = zf;
    if (valid) {
        a0 = *(const bf16x8*)(nfb + (size_t)myrow * 64 + lk * 8);
        a1 = *(const bf16x8*)(nfb + (size_t)myrow * 64 + 32 + lk * 8);
        const float* hp = h_neigh + (size_t)myrow * 64;
        a2 = cvt8(*(const float4*)(hp + lk * 8),      *(const float4*)(hp + lk * 8 + 4));
        a3 = cvt8(*(const float4*)(hp + 32 + lk * 8), *(const float4*)(hp + 32 + lk * 8 + 4));
    }

    // coordinate update (first wave, one thread per node)
    if (t < 64) {
        const int n = n0 + t;
        if (n < N_NODES) {
            const int deg = offsets[n + 1] - offsets[n];
            const float inv = 1.0f / fmaxf((float)deg, 1.0f);
            const float4 xv = xs[n];
            out_x[(size_t)n * 3 + 0] = coord[(size_t)n * 3 + 0] + xv.x * inv;
            out_x[(size_t)n * 3 + 1] = coord[(size_t)n * 3 + 1] + xv.y * inv;
            out_x[(size_t)n * 3 + 2] = coord[(size_t)n * 3 + 2] + xv.z * inv;
        }
    }

    f32x4 acc[4];

    // ---- node layer 1 (K=128) ----
#pragma unroll
    for (int nt = 0; nt < 4; ++nt) {
        const float b0 = bn1[nt * 16 + lr];
        acc[nt] = (f32x4){b0, b0, b0, b0};
        const __bf16* bp = Wn1p + (size_t)(nt * 16 + lr) * 128 + lk * 8;
        acc[nt] = __builtin_amdgcn_mfma_f32_16x16x32_bf16(a0, *(const bf16x8*)(bp),      acc[nt], 0, 0, 0);
        acc[nt] = __builtin_amdgcn_mfma_f32_16x16x32_bf16(a1, *(const bf16x8*)(bp + 32), acc[nt], 0, 0, 0);
        acc[nt] = __builtin_amdgcn_mfma_f32_16x16x32_bf16(a2, *(const bf16x8*)(bp + 64), acc[nt], 0, 0, 0);
        acc[nt] = __builtin_amdgcn_mfma_f32_16x16x32_bf16(a3, *(const bf16x8*)(bp + 96), acc[nt], 0, 0, 0);
    }
#pragma unroll
    for (int nt = 0; nt < 4; ++nt) {
        const int col = nt * 16 + lr;
#pragma unroll
        for (int rr = 0; rr < 4; ++rr)
            sT[(w * 16 + lk * 4 + rr) * STR2 + col] = (__bf16)silu_f(acc[nt][rr]);
    }

    // ---- node layer 2 (K=64), direct stores ----
    {
        const bf16x8 b0f = *(const bf16x8*)&sT[(w * 16 + lr) * STR2 + lk * 8];
        const bf16x8 b1f = *(const bf16x8*)&sT[(w * 16 + lr) * STR2 + 32 + lk * 8];
#pragma unroll
        for (int nt = 0; nt < 4; ++nt) {
            const float b0 = bn2[nt * 16 + lr];
            acc[nt] = (f32x4){b0, b0, b0, b0};
            const __bf16* bp = Wn2p + (size_t)(nt * 16 + lr) * 64 + lk * 8;
            acc[nt] = __builtin_amdgcn_mfma_f32_16x16x32_bf16(b0f, *(const bf16x8*)(bp),      acc[nt], 0, 0, 0);
            acc[nt] = __builtin_amdgcn_mfma_f32_16x16x32_bf16(b1f, *(const bf16x8*)(bp + 32), acc[nt], 0, 0, 0);
        }
#pragma unroll
        for (int nt = 0; nt < 4; ++nt) {
            const int col = nt * 16 + lr;
#pragma unroll
            for (int rr = 0; rr < 4; ++rr) {
                const int row = n0 + w * 16 + lk * 4 + rr;
                if (row < N_NODES)
                    out_h[(size_t)row * 64 + col] = acc[nt][rr];
            }
        }
    }
}

// ================= fallback path (atomics, round-2 proven) =================
__global__ __launch_bounds__(256, 4)
void egnn_edge_mfma_atomic(const float* __restrict__ node_feat,
                           const float* __restrict__ coord,
                           const int* __restrict__ src,
                           const int* __restrict__ dst,
                           const float* __restrict__ We1,
                           const float* __restrict__ be1,
                           const float* __restrict__ be2,
                           const float* __restrict__ bx1,
                           const float* __restrict__ Wx2,
                           const __bf16* __restrict__ We1p,
                           const __bf16* __restrict__ We2p,
                           const __bf16* __restrict__ Wx1p,
                           float* __restrict__ h_neigh,
                           float* __restrict__ x_sum,
                           float* __restrict__ deg)
{
    __shared__ __bf16 sFb[64 * STR1];
    __shared__ __bf16 sT [64 * STR2];
    __shared__ __bf16 sM [64 * STR2];
    __shared__ float  sRad[64];
    __shared__ float  sXd[64][3];
    __shared__ int    sDst[64];

    const int t  = threadIdx.x;
    const int e0 = blockIdx.x * 64;

    {
        const int e = t >> 2, sub = t & 3;
        const int gs = src[e0 + e];
        const int gd = dst[e0 + e];
        const float4* rs = (const float4*)(node_feat + (size_t)gs * 64) + sub * 4;
        const float4* rd = (const float4*)(node_feat + (size_t)gd * 64) + sub * 4;
#pragma unroll
        for (int q = 0; q < 4; ++q) {
            float4 a = rs[q];
            float4 b = rd[q];
            *(bf16x4*)&sFb[e * STR1 + sub * 16 + 4 * q] =
                (bf16x4){(__bf16)a.x, (__bf16)a.y, (__bf16)a.z, (__bf16)a.w};
            *(bf16x4*)&sFb[e * STR1 + 64 + sub * 16 + 4 * q] =
                (bf16x4){(__bf16)b.x, (__bf16)b.y, (__bf16)b.z, (__bf16)b.w};
        }
    }
    if (t < 64) {
        const int e  = t;
        const int gs = src[e0 + e];
        const int gd = dst[e0 + e];
        float dx = coord[(size_t)gs * 3 + 0] - coord[(size_t)gd * 3 + 0];
        float dy = coord[(size_t)gs * 3 + 1] - coord[(size_t)gd * 3 + 1];
        float dz = coord[(size_t)gs * 3 + 2] - coord[(size_t)gd * 3 + 2];
        float radial = dx * dx + dy * dy + dz * dz;
        sRad[e] = radial;
        float inv = 1.0f / (sqrtf(radial) + EPS_F);
        sXd[e][0] = dx * inv; sXd[e][1] = dy * inv; sXd[e][2] = dz * inv;
        sDst[e] = gd;
    }
    __syncthreads();

    const int lane = t & 63;
    const int w    = t >> 6;
    const int lr   = lane & 15;
    const int lk   = lane >> 4;

    f32x4 acc[4];
    {
#pragma unroll
        for (int nt = 0; nt < 4; ++nt) {
            const int col = nt * 16 + lr;
            const float b0 = be1[col];
            const float wr = We1[128 * 64 + col];
#pragma unroll
            for (int r = 0; r < 4; ++r)
                acc[nt][r] = b0 + sRad[w * 16 + lk * 4 + r] * wr;
        }
        const int arow = w * 16 + lr;
#pragma unroll
        for (int ks = 0; ks < 4; ++ks) {
            bf16x8 a = *(const bf16x8*)&sFb[arow * STR1 + ks * 32 + lk * 8];
#pragma unroll
            for (int nt = 0; nt < 4; ++nt) {
                bf16x8 b = *(const bf16x8*)&We1p[(nt * 16 + lr) * 128 + ks * 32 + lk * 8];
                acc[nt] = __builtin_amdgcn_mfma_f32_16x16x32_bf16(a, b, acc[nt], 0, 0, 0);
            }
        }
#pragma unroll
        for (int nt = 0; nt < 4; ++nt) {
            const int col = nt * 16 + lr;
#pragma unroll
            for (int r = 0; r < 4; ++r) {
                const int row = w * 16 + lk * 4 + r;
                sT[row * STR2 + col] = (__bf16)silu_f(acc[nt][r]);
            }
        }
    }
    __syncthreads();
    {
#pragma unroll
        for (int nt = 0; nt < 4; ++nt) {
            const float b0 = be2[nt * 16 + lr];
            acc[nt] = (f32x4){b0, b0, b0, b0};
        }
        const int arow = w * 16 + lr;
#pragma unroll
        for (int ks = 0; ks < 2; ++ks) {
            bf16x8 a = *(const bf16x8*)&sT[arow * STR2 + ks * 32 + lk * 8];
#pragma unroll
            for (int nt = 0; nt < 4; ++nt) {
                bf16x8 b = *(const bf16x8*)&We2p[(nt * 16 + lr) * 64 + ks * 32 + lk * 8];
                acc[nt] = __builtin_amdgcn_mfma_f32_16x16x32_bf16(a, b, acc[nt], 0, 0, 0);
            }
        }
#pragma unroll
        for (int nt = 0; nt < 4; ++nt) {
            const int col = nt * 16 + lr;
#pragma unroll
            for (int r = 0; r < 4; ++r) {
                const int row = w * 16 + lk * 4 + r;
                const float v = silu_f(acc[nt][r]);
                sM[row * STR2 + col] = (__bf16)v;
                atomicAdd(&h_neigh[(size_t)sDst[row] * 64 + col], v);
            }
        }
    }
    __syncthreads();
    {
#pragma unroll
        for (int nt = 0; nt < 4; ++nt) {
            const float b0 = bx1[nt * 16 + lr];
            acc[nt] = (f32x4){b0, b0, b0, b0};
        }
        const int arow = w * 16 + lr;
#pragma unroll
        for (int ks = 0; ks < 2; ++ks) {
            bf16x8 a = *(const bf16x8*)&sM[arow * STR2 + ks * 32 + lk * 8];
#pragma unroll
            for (int nt = 0; nt < 4; ++nt) {
                bf16x8 b = *(const bf16x8*)&Wx1p[(nt * 16 + lr) * 64 + ks * 32 + lk * 8];
                acc[nt] = __builtin_amdgcn_mfma_f32_16x16x32_bf16(a, b, acc[nt], 0, 0, 0);
            }
        }
        float p[4] = {0.f, 0.f, 0.f, 0.f};
#pragma unroll
        for (int nt = 0; nt < 4; ++nt) {
            const float wv = Wx2[nt * 16 + lr];
#pragma unroll
            for (int r = 0; r < 4; ++r)
                p[r] += silu_f(acc[nt][r]) * wv;
        }
#pragma unroll
        for (int off = 1; off < 16; off <<= 1)
#pragma unroll
            for (int r = 0; r < 4; ++r)
                p[r] += __shfl_xor(p[r], off);
        if (lr == 0) {
#pragma unroll
            for (int r = 0; r < 4; ++r) {
                const int e  = w * 16 + lk * 4 + r;
                const int gd = sDst[e];
                const float coef = p[r];
                atomicAdd(&x_sum[(size_t)gd * 3 + 0], coef * sXd[e][0]);
                atomicAdd(&x_sum[(size_t)gd * 3 + 1], coef * sXd[e][1]);
                atomicAdd(&x_sum[(size_t)gd * 3 + 2], coef * sXd[e][2]);
                atomicAdd(&deg[gd], 1.0f);
            }
        }
    }
}

template<int KDIM>
__device__ __forceinline__ void tile_gemm64(const float* __restrict__ A, int astride,
                                            const float* __restrict__ B,
                                            float acc[4][4], int t)
{
    const int tx = t & 15;
    const int ty = t >> 4;
#pragma unroll
    for (int i = 0; i < 4; ++i)
#pragma unroll
        for (int j = 0; j < 4; ++j) acc[i][j] = 0.0f;

    for (int k = 0; k < KDIM; k += 4) {
        float bv[4][4];
#pragma unroll
        for (int kk = 0; kk < 4; ++kk) {
            float4 bq = *(const float4*)(B + (size_t)(k + kk) * 64 + tx * 4);
            bv[kk][0] = bq.x; bv[kk][1] = bq.y; bv[kk][2] = bq.z; bv[kk][3] = bq.w;
        }
#pragma unroll
        for (int i = 0; i < 4; ++i) {
            float4 aq = *(const float4*)(A + (size_t)(ty * 4 + i) * astride + k);
            float av[4] = {aq.x, aq.y, aq.z, aq.w};
#pragma unroll
            for (int kk = 0; kk < 4; ++kk)
#pragma unroll
                for (int j = 0; j < 4; ++j)
                    acc[i][j] = fmaf(av[kk], bv[kk][j], acc[i][j]);
        }
    }
}

__global__ __launch_bounds__(256, 2)
void egnn_node_kernel(const float* __restrict__ node_feat,
                      const float* __restrict__ coord,
                      const float* __restrict__ Wn1, const float* __restrict__ bn1,
                      const float* __restrict__ Wn2, const float* __restrict__ bn2,
                      const float* __restrict__ h_neigh,
                      const float* __restrict__ x_sum,
                      const float* __restrict__ deg,
                      float* __restrict__ out_h,
                      float* __restrict__ out_x)
{
    __shared__ float sF[64][132];
    __shared__ float sT2[64][68];

    const int t  = threadIdx.x;
    const int n0 = blockIdx.x * 64;

    {
        const int r = t >> 2;
        const int sub = t & 3;
        const int n = n0 + r;
        if (n < N_NODES) {
            const float* rowsrc = (sub < 2) ? (node_feat + (size_t)n * 64 + sub * 32)
                                            : (h_neigh  + (size_t)n * 64 + (sub - 2) * 32);
#pragma unroll
            for (int q = 0; q < 8; ++q)
                *(float4*)&sF[r][sub * 32 + 4 * q] = *(const float4*)(rowsrc + 4 * q);
        } else {
#pragma unroll
            for (int q = 0; q < 8; ++q)
                *(float4*)&sF[r][sub * 32 + 4 * q] = make_float4(0.f, 0.f, 0.f, 0.f);
        }
    }
    __syncthreads();

    const int tx = t & 15;
    const int ty = t >> 4;
    float acc[4][4];

    tile_gemm64<128>(&sF[0][0], 132, Wn1, acc, t);
    {
        float4 bq = *(const float4*)(bn1 + tx * 4);
        float bv[4] = {bq.x, bq.y, bq.z, bq.w};
#pragma unroll
        for (int i = 0; i < 4; ++i) {
            float4 o;
            o.x = silu_f(acc[i][0] + bv[0]);
            o.y = silu_f(acc[i][1] + bv[1]);
            o.z = silu_f(acc[i][2] + bv[2]);
            o.w = silu_f(acc[i][3] + bv[3]);
            *(float4*)&sT2[ty * 4 + i][tx * 4] = o;
        }
    }
    __syncthreads();

    tile_gemm64<64>(&sT2[0][0], 68, Wn2, acc, t);
    {
        float4 bq = *(const float4*)(bn2 + tx * 4);
        float bv[4] = {bq.x, bq.y, bq.z, bq.w};
#pragma unroll
        for (int i = 0; i < 4; ++i) {
            const int n = n0 + ty * 4 + i;
            if (n < N_NODES) {
                float4 o;
                o.x = acc[i][0] + bv[0];
                o.y = acc[i][1] + bv[1];
                o.z = acc[i][2] + bv[2];
                o.w = acc[i][3] + bv[3];
                *(float4*)&out_h[(size_t)n * 64 + tx * 4] = o;
            }
        }
    }

    if (t < 64) {
        const int n = n0 + t;
        if (n < N_NODES) {
            const float d = deg[n];
            const float inv = 1.0f / fmaxf(d, 1.0f);
#pragma unroll
            for (int c = 0; c < 3; ++c)
                out_x[(size_t)n * 3 + c] = coord[(size_t)n * 3 + c]
                                         + x_sum[(size_t)n * 3 + c] * inv;
        }
    }
}

// ================= host =================
extern "C" void kernel_launch(void* const* d_in, const int* in_sizes, int n_in,
                              void* d_out, int out_size, void* d_ws, size_t ws_size,
                              hipStream_t stream) {
    const float* node_feat = (const float*)d_in[0];
    const float* coord     = (const float*)d_in[1];
    const int*   src       = (const int*)d_in[2];
    const int*   dst       = (const int*)d_in[3];
    const float* We1 = (const float*)d_in[4];
    const float* be1 = (const float*)d_in[5];
    const float* We2 = (const float*)d_in[6];
    const float* be2 = (const float*)d_in[7];
    const float* Wx1 = (const float*)d_in[8];
    const float* bx1 = (const float*)d_in[9];
    const float* Wx2 = (const float*)d_in[10];
    const float* Wn1 = (const float*)d_in[11];
    const float* bn1 = (const float*)d_in[12];
    const float* Wn2 = (const float*)d_in[13];
    const float* bn2 = (const float*)d_in[14];

    float* out_h = (float*)d_out;
    float* out_x = out_h + (size_t)N_NODES * 64;

    // ---- workspace layout (fast path) ----
    char* ws = (char*)d_ws;
    size_t off = 0;
    auto take = [&](size_t bytes) { char* p = ws + off; off = (off + bytes + 255) & ~(size_t)255; return p; };

    float*  h_neigh = (float*)take((size_t)N_NODES * 64 * 4);   // zeroed
    float*  xs      = (float*)take((size_t)N_NODES * 16);       // zeroed (contiguous)
    int*    src_p   = (int*)take((size_t)N_EDGES * 4);
    int*    dst_p   = (int*)take((size_t)N_EDGES * 4);
    float4* geom    = (float4*)take((size_t)N_EDGES * 16);
    __bf16* nfb     = (__bf16*)take((size_t)N_NODES * 64 * 2);
    int*    offsets = (int*)take((size_t)(N_NODES + 1) * 4);
    int*    cursor  = (int*)take((size_t)N_NODES * 4);
    int*    cnt     = (int*)take((size_t)N_NODES * 4);
    int*    excl    = (int*)take((size_t)N_NODES * 4);
    int*    bsum    = (int*)take(1024);
    int*    bpre    = (int*)take(1024);
    __bf16* We1p    = (__bf16*)take(64 * 128 * 2);
    __bf16* We2p    = (__bf16*)take(64 * 64 * 2);
    __bf16* Wx1p    = (__bf16*)take(64 * 64 * 2);
    __bf16* Wn1p    = (__bf16*)take(64 * 128 * 2);
    __bf16* Wn2p    = (__bf16*)take(64 * 64 * 2);
    const size_t needed = off;

    if (ws_size >= needed) {
        hipMemsetAsync(h_neigh, 0, (size_t)N_NODES * 64 * 4 + (size_t)N_NODES * 16, stream);
        hipMemsetAsync(cnt, 0, (size_t)N_NODES * 4, stream);

        prep_kernel<<<2048, 256, 0, stream>>>(node_feat, We1, We2, Wx1, Wn1, Wn2,
                                              nfb, We1p, We2p, Wx1p, Wn1p, Wn2p);
        const int nb = (N_NODES + 255) / 256;   // 196
        hist_kernel<<<(N_EDGES + 255) / 256, 256, 0, stream>>>(dst, cnt);
        scan1_kernel<<<nb, 256, 0, stream>>>(cnt, excl, bsum);
        scan2_kernel<<<1, 256, 0, stream>>>(bsum, bpre, nb);
        scan3_kernel<<<nb, 256, 0, stream>>>(excl, bpre, offsets, cursor);
        fill_v2<<<(N_EDGES + 255) / 256, 256, 0, stream>>>(src, dst, coord, cursor,
                                                           src_p, dst_p, geom);

        egnn_edge_mfma_v5<<<N_EDGES / 64, 256, 0, stream>>>(
            nfb, src_p, dst_p, geom,
            We1, be1, be2, bx1, Wx2,
            We1p, We2p, Wx1p,
            h_neigh, xs);

        egnn_node_mfma_v5<<<(N_NODES + 63) / 64, 256, 0, stream>>>(
            nfb, coord, offsets, h_neigh, (const float4*)xs,
            bn1, bn2, Wn1p, Wn2p, out_h, out_x);
    } else {
        // ======== fallback: atomic path ========
        float* fh_neigh = (float*)d_ws;
        float* fx_sum   = fh_neigh + (size_t)N_NODES * 64;
        float* fdeg     = fx_sum + (size_t)N_NODES * 3;
        __bf16* fnfb    = (__bf16*)(fdeg + N_NODES);
        __bf16* fWe1p   = fnfb + (size_t)N_NODES * 64;
        __bf16* fWe2p   = fWe1p + 64 * 128;
        __bf16* fWx1p   = fWe2p + 64 * 64;
        __bf16* fWn1p   = fWx1p + 64 * 64;
        __bf16* fWn2p   = fWn1p + 64 * 128;

        hipMemsetAsync(d_ws, 0, (size_t)N_NODES * 68 * sizeof(float), stream);
        prep_kernel<<<2048, 256, 0, stream>>>(node_feat, We1, We2, Wx1, Wn1, Wn2,
                                              fnfb, fWe1p, fWe2p, fWx1p, fWn1p, fWn2p);
        egnn_edge_mfma_atomic<<<N_EDGES / 64, 256, 0, stream>>>(
            node_feat, coord, src, dst,
            We1, be1, be2, bx1, Wx2,
            fWe1p, fWe2p, fWx1p,
            fh_neigh, fx_sum, fdeg);
        egnn_node_kernel<<<(N_NODES + 63) / 64, 256, 0, stream>>>(
            node_feat, coord, Wn1, bn1, Wn2, bn2,
            fh_neigh, fx_sum, fdeg, out_h, out_x);
    }
}

// Round 7
// 284.401 us; speedup vs baseline: 2.4490x; 1.1666x over previous
//
#include <hip/hip_runtime.h>
#include <math.h>

#define N_NODES 50000
#define N_EDGES 800000
#define EPS_F 1e-30f

typedef __bf16 bf16x8 __attribute__((ext_vector_type(8)));
typedef __bf16 bf16x4 __attribute__((ext_vector_type(4)));
typedef float  f32x4  __attribute__((ext_vector_type(4)));

#define STR1 136   // 128-wide bf16 tile row stride (fallback kernel)
#define STR2 72    // 64-wide bf16 tile row stride (144B)

__device__ __forceinline__ float silu_f(float x) {
    return x / (1.0f + __expf(-x));
}

__device__ __forceinline__ bf16x8 cvt8(float4 u0, float4 u1) {
    return (bf16x8){(__bf16)u0.x, (__bf16)u0.y, (__bf16)u0.z, (__bf16)u0.w,
                    (__bf16)u1.x, (__bf16)u1.y, (__bf16)u1.z, (__bf16)u1.w};
}

// ---------------- prologue: pack weights bf16-T + convert node_feat ----------------
__global__ void prep_kernel(const float* __restrict__ node_feat,
                            const float* __restrict__ We1,
                            const float* __restrict__ We2,
                            const float* __restrict__ Wx1,
                            const float* __restrict__ Wn1,
                            const float* __restrict__ Wn2,
                            __bf16* __restrict__ nfb,    // [N*64]
                            __bf16* __restrict__ We1p,   // [64][128]
                            __bf16* __restrict__ We2p,   // [64][64]
                            __bf16* __restrict__ Wx1p,   // [64][64]
                            __bf16* __restrict__ Wn1p,   // [64][128]
                            __bf16* __restrict__ Wn2p)   // [64][64]
{
    const int t = blockIdx.x * 256 + threadIdx.x;
    const int stride = gridDim.x * 256;
    for (int i = t; i < N_NODES * 64; i += stride)
        nfb[i] = (__bf16)node_feat[i];
    for (int i = t; i < 64 * 128; i += stride) {
        const int n = i >> 7, k = i & 127;
        We1p[i] = (__bf16)We1[k * 64 + n];
        Wn1p[i] = (__bf16)Wn1[k * 64 + n];
    }
    for (int i = t; i < 64 * 64; i += stride) {
        const int n = i >> 6, k = i & 63;
        We2p[i] = (__bf16)We2[k * 64 + n];
        Wx1p[i] = (__bf16)Wx1[k * 64 + n];
        Wn2p[i] = (__bf16)Wn2[k * 64 + n];
    }
}

// ---------------- P1/P2 precompute: P1 = nf@We1[0:64]+be1, P2 = nf@We1[64:128] ----------------
__global__ __launch_bounds__(256, 8)
void pgemm_kernel(const __bf16* __restrict__ nfb,
                  const __bf16* __restrict__ We1p,   // [64][128] (n-major, k = src|dst)
                  const float* __restrict__ be1,
                  __bf16* __restrict__ P1b,          // [N*64]
                  __bf16* __restrict__ P2b)          // [N*64]
{
    __shared__ __bf16 sC[64 * STR2];   // wave-private slices

    const int t    = threadIdx.x;
    const int lane = t & 63;
    const int w    = t >> 6;
    const int lr   = lane & 15;
    const int lk   = lane >> 4;
    const int n0   = blockIdx.x * 64;
    const int myrow = n0 + w * 16 + lr;
    const bool valid = (myrow < N_NODES);

    const bf16x8 zf = {(__bf16)0.f, (__bf16)0.f, (__bf16)0.f, (__bf16)0.f,
                       (__bf16)0.f, (__bf16)0.f, (__bf16)0.f, (__bf16)0.f};
    bf16x8 a0 = zf, a1 = zf;
    if (valid) {
        a0 = *(const bf16x8*)(nfb + (size_t)myrow * 64 + lk * 8);
        a1 = *(const bf16x8*)(nfb + (size_t)myrow * 64 + 32 + lk * 8);
    }

    f32x4 acc[4];
#pragma unroll
    for (int pass = 0; pass < 2; ++pass) {
#pragma unroll
        for (int nt = 0; nt < 4; ++nt) {
            const int col = nt * 16 + lr;
            const float b0 = (pass == 0) ? be1[col] : 0.0f;
            acc[nt] = (f32x4){b0, b0, b0, b0};
            const __bf16* bp = We1p + (size_t)col * 128 + pass * 64 + lk * 8;
            acc[nt] = __builtin_amdgcn_mfma_f32_16x16x32_bf16(a0, *(const bf16x8*)(bp),      acc[nt], 0, 0, 0);
            acc[nt] = __builtin_amdgcn_mfma_f32_16x16x32_bf16(a1, *(const bf16x8*)(bp + 32), acc[nt], 0, 0, 0);
        }
#pragma unroll
        for (int nt = 0; nt < 4; ++nt) {
            const int col = nt * 16 + lr;
#pragma unroll
            for (int r = 0; r < 4; ++r)
                sC[(w * 16 + lk * 4 + r) * STR2 + col] = (__bf16)acc[nt][r];
        }
        // wave-private redistribution -> coalesced row store
        if (valid) {
            __bf16* out = (pass == 0) ? P1b : P2b;
            bf16x8 v0 = *(const bf16x8*)&sC[(w * 16 + lr) * STR2 + lk * 8];
            bf16x8 v1 = *(const bf16x8*)&sC[(w * 16 + lr) * STR2 + 32 + lk * 8];
            *(bf16x8*)(out + (size_t)myrow * 64 + lk * 8)      = v0;
            *(bf16x8*)(out + (size_t)myrow * 64 + 32 + lk * 8) = v1;
        }
    }
}

// ---------------- CSR build ----------------
__global__ void hist_kernel(const int* __restrict__ dst, int* __restrict__ cnt) {
    const int e = blockIdx.x * 256 + threadIdx.x;
    if (e < N_EDGES) atomicAdd(&cnt[dst[e]], 1);
}

__global__ void scan1_kernel(const int* __restrict__ cnt,
                             int* __restrict__ excl, int* __restrict__ bsum) {
    __shared__ int s[256];
    const int tid = threadIdx.x;
    const int i = blockIdx.x * 256 + tid;
    const int v = (i < N_NODES) ? cnt[i] : 0;
    s[tid] = v; __syncthreads();
#pragma unroll
    for (int off = 1; off < 256; off <<= 1) {
        int t = (tid >= off) ? s[tid - off] : 0;
        __syncthreads();
        s[tid] += t;
        __syncthreads();
    }
    if (i < N_NODES) excl[i] = s[tid] - v;
    if (tid == 255) bsum[blockIdx.x] = s[255];
}

__global__ void scan2_kernel(int* __restrict__ bsum, int* __restrict__ bpre, int nb) {
    __shared__ int s[256];
    const int tid = threadIdx.x;
    const int v = (tid < nb) ? bsum[tid] : 0;
    s[tid] = v; __syncthreads();
#pragma unroll
    for (int off = 1; off < 256; off <<= 1) {
        int t = (tid >= off) ? s[tid - off] : 0;
        __syncthreads();
        s[tid] += t;
        __syncthreads();
    }
    if (tid < nb) bpre[tid] = s[tid] - v;
}

__global__ void scan3_kernel(const int* __restrict__ excl, const int* __restrict__ bpre,
                             int* __restrict__ offsets, int* __restrict__ cursor) {
    const int i = blockIdx.x * 256 + threadIdx.x;
    if (i < N_NODES) {
        const int o = bpre[blockIdx.x] + excl[i];
        offsets[i] = o;
        cursor[i] = o;
    }
    if (blockIdx.x == 0 && threadIdx.x == 0) offsets[N_NODES] = N_EDGES;
}

__global__ void fill_v3(const int* __restrict__ src, const int* __restrict__ dst,
                        const float* __restrict__ coord,
                        int* __restrict__ cursor,
                        int2* __restrict__ edge_p,
                        float4* __restrict__ geom) {
    const int e = blockIdx.x * 256 + threadIdx.x;
    if (e < N_EDGES) {
        const int gs = src[e];
        const int gd = dst[e];
        const int p = atomicAdd(&cursor[gd], 1);
        edge_p[p] = make_int2(gs, gd);
        const float dx = coord[(size_t)gs * 3 + 0] - coord[(size_t)gd * 3 + 0];
        const float dy = coord[(size_t)gs * 3 + 1] - coord[(size_t)gd * 3 + 1];
        const float dz = coord[(size_t)gs * 3 + 2] - coord[(size_t)gd * 3 + 2];
        const float radial = dx * dx + dy * dy + dz * dz;
        const float inv = 1.0f / (sqrtf(radial) + EPS_F);
        geom[p] = make_float4(dx * inv, dy * inv, dz * inv, radial);
    }
}

// ---------------- edge kernel v6: layer1 factored out, reg-resident ----------------
__global__ __launch_bounds__(256, 8)
void egnn_edge_mfma_v6(const __bf16* __restrict__ P1b,
                       const __bf16* __restrict__ P2b,
                       const int2* __restrict__ edge_p,
                       const float4* __restrict__ geom,
                       const float* __restrict__ We1,   // row 128 (radial) f32
                       const float* __restrict__ be2,
                       const float* __restrict__ bx1,
                       const float* __restrict__ Wx2,
                       const __bf16* __restrict__ We2p,
                       const __bf16* __restrict__ Wx1p,
                       float* __restrict__ h_neigh,     // [N*64] f32 accum
                       float* __restrict__ xs)          // [N*4]  f32 accum
{
    // wave-private LDS only
    __shared__ __bf16 sM[64 * STR2];
    __shared__ float  sCoef[64];

    const int t    = threadIdx.x;
    const int lane = t & 63;
    const int w    = t >> 6;
    const int lr   = lane & 15;
    const int lk   = lane >> 4;
    const int j0   = blockIdx.x * 64;     // E = 12500*64, no tail
    const int myrow = w * 16 + lr;

    const int2  ed = edge_p[j0 + myrow];
    const int   gs = ed.x;
    const int   gd = ed.y;
    const float4 g = geom[j0 + myrow];

    // gather precomputed layer-1 partials (bf16 rows, same fragment slots)
    const bf16x8 p1a = *(const bf16x8*)(P1b + (size_t)gs * 64 + lk * 8);
    const bf16x8 p1c = *(const bf16x8*)(P1b + (size_t)gs * 64 + 32 + lk * 8);
    const bf16x8 p2a = *(const bf16x8*)(P2b + (size_t)gd * 64 + lk * 8);
    const bf16x8 p2c = *(const bf16x8*)(P2b + (size_t)gd * 64 + 32 + lk * 8);

    // radial weight row (f32), this lane's column chunks
    const float4 w00 = *(const float4*)(We1 + 128 * 64 + lk * 8);
    const float4 w01 = *(const float4*)(We1 + 128 * 64 + lk * 8 + 4);
    const float4 w10 = *(const float4*)(We1 + 128 * 64 + 32 + lk * 8);
    const float4 w11 = *(const float4*)(We1 + 128 * 64 + 32 + lk * 8 + 4);

    // ---- layer 1 in registers: silu(P1[src] + P2[dst] + radial*We1r) ----
    bf16x8 a0, a1;
    {
        const float wv0[8] = {w00.x, w00.y, w00.z, w00.w, w01.x, w01.y, w01.z, w01.w};
        const float wv1[8] = {w10.x, w10.y, w10.z, w10.w, w11.x, w11.y, w11.z, w11.w};
#pragma unroll
        for (int u = 0; u < 8; ++u) {
            a0[u] = (__bf16)silu_f((float)p1a[u] + (float)p2a[u] + g.w * wv0[u]);
            a1[u] = (__bf16)silu_f((float)p1c[u] + (float)p2c[u] + g.w * wv1[u]);
        }
    }

    f32x4 acc[4];

    // ---- layer 2: K=64 MFMA from registers -> msg tile sM ----
#pragma unroll
    for (int nt = 0; nt < 4; ++nt) {
        const float b0 = be2[nt * 16 + lr];
        acc[nt] = (f32x4){b0, b0, b0, b0};
        const __bf16* bp = We2p + (size_t)(nt * 16 + lr) * 64 + lk * 8;
        acc[nt] = __builtin_amdgcn_mfma_f32_16x16x32_bf16(a0, *(const bf16x8*)(bp),      acc[nt], 0, 0, 0);
        acc[nt] = __builtin_amdgcn_mfma_f32_16x16x32_bf16(a1, *(const bf16x8*)(bp + 32), acc[nt], 0, 0, 0);
    }
#pragma unroll
    for (int nt = 0; nt < 4; ++nt) {
        const int col = nt * 16 + lr;
#pragma unroll
        for (int r = 0; r < 4; ++r)
            sM[(w * 16 + lk * 4 + r) * STR2 + col] = (__bf16)silu_f(acc[nt][r]);
    }
    // no barrier: wave-private rows, in-order per-wave LDS

    // ---- layer 3: coef per edge -> sCoef ----
    {
        const bf16x8 m0 = *(const bf16x8*)&sM[myrow * STR2 + lk * 8];
        const bf16x8 m1 = *(const bf16x8*)&sM[myrow * STR2 + 32 + lk * 8];
#pragma unroll
        for (int nt = 0; nt < 4; ++nt) {
            const float b0 = bx1[nt * 16 + lr];
            acc[nt] = (f32x4){b0, b0, b0, b0};
            const __bf16* bp = Wx1p + (size_t)(nt * 16 + lr) * 64 + lk * 8;
            acc[nt] = __builtin_amdgcn_mfma_f32_16x16x32_bf16(m0, *(const bf16x8*)(bp),      acc[nt], 0, 0, 0);
            acc[nt] = __builtin_amdgcn_mfma_f32_16x16x32_bf16(m1, *(const bf16x8*)(bp + 32), acc[nt], 0, 0, 0);
        }
        float p[4] = {0.f, 0.f, 0.f, 0.f};
#pragma unroll
        for (int nt = 0; nt < 4; ++nt) {
            const float wv = Wx2[nt * 16 + lr];
#pragma unroll
            for (int r = 0; r < 4; ++r)
                p[r] += silu_f(acc[nt][r]) * wv;
        }
#pragma unroll
        for (int off = 1; off < 16; off <<= 1)
#pragma unroll
            for (int r = 0; r < 4; ++r)
                p[r] += __shfl_xor(p[r], off);
        if (lr == 0) {
#pragma unroll
            for (int r = 0; r < 4; ++r)
                sCoef[w * 16 + lk * 4 + r] = p[r];
        }
    }

    // ---- column segment-reduce of msg onto h_neigh (runs of equal dst) ----
    {
        float accum = 0.0f;
        int cur = __shfl(gd, 0);
#pragma unroll
        for (int rr = 0; rr < 16; ++rr) {
            const int d = __shfl(gd, rr);     // dst of row w*16+rr
            const float v = (float)sM[(w * 16 + rr) * STR2 + lane];
            if (d != cur) {                   // wave-uniform branch
                atomicAdd(&h_neigh[(size_t)cur * 64 + lane], accum);
                accum = 0.0f; cur = d;
            }
            accum += v;
        }
        atomicAdd(&h_neigh[(size_t)cur * 64 + lane], accum);
    }

    // ---- xs: in-wave segmented shuffle-reduce over the 16-row group ----
    {
        const float c = sCoef[w * 16 + lr];
        float vx = c * g.x, vy = c * g.y, vz = c * g.z;
        const int d = gd;
#pragma unroll
        for (int off = 1; off < 16; off <<= 1) {
            const int   od = __shfl(d,  lane + off);
            const float ox = __shfl(vx, lane + off);
            const float oy = __shfl(vy, lane + off);
            const float oz = __shfl(vz, lane + off);
            if ((lr + off < 16) && (od == d)) { vx += ox; vy += oy; vz += oz; }
        }
        const int pd = __shfl(d, lane - 1);
        const bool head = (lr == 0) || (pd != d);
        if (head && lk == 0) {
            atomicAdd(&xs[(size_t)d * 4 + 0], vx);
            atomicAdd(&xs[(size_t)d * 4 + 1], vy);
            atomicAdd(&xs[(size_t)d * 4 + 2], vz);
        }
    }
}

// ---------------- node kernel v5: reg A-fragments, direct stores ----------------
__global__ __launch_bounds__(256, 8)
void egnn_node_mfma_v5(const __bf16* __restrict__ nfb,
                       const float* __restrict__ coord,
                       const int* __restrict__ offsets,
                       const float* __restrict__ h_neigh,   // [N*64] f32
                       const float4* __restrict__ xs,       // [N]
                       const float* __restrict__ bn1,
                       const float* __restrict__ bn2,
                       const __bf16* __restrict__ Wn1p,
                       const __bf16* __restrict__ Wn2p,
                       float* __restrict__ out_h,
                       float* __restrict__ out_x)
{
    __shared__ __bf16 sT[64 * STR2];   // wave-private slices

    const int t    = threadIdx.x;
    const int lane = t & 63;
    const int w    = t >> 6;
    const int lr   = lane & 15;
    const int lk   = lane >> 4;
    const int n0   = blockIdx.x * 64;
    const int myrow = n0 + w * 16 + lr;
    const bool valid = (myrow < N_NODES);

    const bf16x8 zf = {(__bf16)0.f, (__bf16)0.f, (__bf16)0.f, (__bf16)0.f,
                       (__bf16)0.f, (__bf16)0.f, (__bf16)0.f, (__bf16)0.f};

    bf16x8 a0 = zf, a1 = zf, a2 = zf, a3 = zf;
    if (valid) {
        a0 = *(const bf16x8*)(nfb + (size_t)myrow * 64 + lk * 8);
        a1 = *(const bf16x8*)(nfb + (size_t)myrow * 64 + 32 + lk * 8);
        const float* hp = h_neigh + (size_t)myrow * 64;
        a2 = cvt8(*(const float4*)(hp + lk * 8),      *(const float4*)(hp + lk * 8 + 4));
        a3 = cvt8(*(const float4*)(hp + 32 + lk * 8), *(const float4*)(hp + 32 + lk * 8 + 4));
    }

    // coordinate update (first wave, one thread per node)
    if (t < 64) {
        const int n = n0 + t;
        if (n < N_NODES) {
            const int deg = offsets[n + 1] - offsets[n];
            const float inv = 1.0f / fmaxf((float)deg, 1.0f);
            const float4 xv = xs[n];
            out_x[(size_t)n * 3 + 0] = coord[(size_t)n * 3 + 0] + xv.x * inv;
            out_x[(size_t)n * 3 + 1] = coord[(size_t)n * 3 + 1] + xv.y * inv;
            out_x[(size_t)n * 3 + 2] = coord[(size_t)n * 3 + 2] + xv.z * inv;
        }
    }

    f32x4 acc[4];

    // ---- node layer 1 (K=128) ----
#pragma unroll
    for (int nt = 0; nt < 4; ++nt) {
        const float b0 = bn1[nt * 16 + lr];
        acc[nt] = (f32x4){b0, b0, b0, b0};
        const __bf16* bp = Wn1p + (size_t)(nt * 16 + lr) * 128 + lk * 8;
        acc[nt] = __builtin_amdgcn_mfma_f32_16x16x32_bf16(a0, *(const bf16x8*)(bp),      acc[nt], 0, 0, 0);
        acc[nt] = __builtin_amdgcn_mfma_f32_16x16x32_bf16(a1, *(const bf16x8*)(bp + 32), acc[nt], 0, 0, 0);
        acc[nt] = __builtin_amdgcn_mfma_f32_16x16x32_bf16(a2, *(const bf16x8*)(bp + 64), acc[nt], 0, 0, 0);
        acc[nt] = __builtin_amdgcn_mfma_f32_16x16x32_bf16(a3, *(const bf16x8*)(bp + 96), acc[nt], 0, 0, 0);
    }
#pragma unroll
    for (int nt = 0; nt < 4; ++nt) {
        const int col = nt * 16 + lr;
#pragma unroll
        for (int rr = 0; rr < 4; ++rr)
            sT[(w * 16 + lk * 4 + rr) * STR2 + col] = (__bf16)silu_f(acc[nt][rr]);
    }

    // ---- node layer 2 (K=64), direct stores ----
    {
        const bf16x8 b0f = *(const bf16x8*)&sT[(w * 16 + lr) * STR2 + lk * 8];
        const bf16x8 b1f = *(const bf16x8*)&sT[(w * 16 + lr) * STR2 + 32 + lk * 8];
#pragma unroll
        for (int nt = 0; nt < 4; ++nt) {
            const float b0 = bn2[nt * 16 + lr];
            acc[nt] = (f32x4){b0, b0, b0, b0};
            const __bf16* bp = Wn2p + (size_t)(nt * 16 + lr) * 64 + lk * 8;
            acc[nt] = __builtin_amdgcn_mfma_f32_16x16x32_bf16(b0f, *(const bf16x8*)(bp),      acc[nt], 0, 0, 0);
            acc[nt] = __builtin_amdgcn_mfma_f32_16x16x32_bf16(b1f, *(const bf16x8*)(bp + 32), acc[nt], 0, 0, 0);
        }
#pragma unroll
        for (int nt = 0; nt < 4; ++nt) {
            const int col = nt * 16 + lr;
#pragma unroll
            for (int rr = 0; rr < 4; ++rr) {
                const int row = n0 + w * 16 + lk * 4 + rr;
                if (row < N_NODES)
                    out_h[(size_t)row * 64 + col] = acc[nt][rr];
            }
        }
    }
}

// ================= fallback path (atomics, round-2 proven) =================
__global__ __launch_bounds__(256, 4)
void egnn_edge_mfma_atomic(const float* __restrict__ node_feat,
                           const float* __restrict__ coord,
                           const int* __restrict__ src,
                           const int* __restrict__ dst,
                           const float* __restrict__ We1,
                           const float* __restrict__ be1,
                           const float* __restrict__ be2,
                           const float* __restrict__ bx1,
                           const float* __restrict__ Wx2,
                           const __bf16* __restrict__ We1p,
                           const __bf16* __restrict__ We2p,
                           const __bf16* __restrict__ Wx1p,
                           float* __restrict__ h_neigh,
                           float* __restrict__ x_sum,
                           float* __restrict__ deg)
{
    __shared__ __bf16 sFb[64 * STR1];
    __shared__ __bf16 sT [64 * STR2];
    __shared__ __bf16 sM [64 * STR2];
    __shared__ float  sRad[64];
    __shared__ float  sXd[64][3];
    __shared__ int    sDst[64];

    const int t  = threadIdx.x;
    const int e0 = blockIdx.x * 64;

    {
        const int e = t >> 2, sub = t & 3;
        const int gs = src[e0 + e];
        const int gd = dst[e0 + e];
        const float4* rs = (const float4*)(node_feat + (size_t)gs * 64) + sub * 4;
        const float4* rd = (const float4*)(node_feat + (size_t)gd * 64) + sub * 4;
#pragma unroll
        for (int q = 0; q < 4; ++q) {
            float4 a = rs[q];
            float4 b = rd[q];
            *(bf16x4*)&sFb[e * STR1 + sub * 16 + 4 * q] =
                (bf16x4){(__bf16)a.x, (__bf16)a.y, (__bf16)a.z, (__bf16)a.w};
            *(bf16x4*)&sFb[e * STR1 + 64 + sub * 16 + 4 * q] =
                (bf16x4){(__bf16)b.x, (__bf16)b.y, (__bf16)b.z, (__bf16)b.w};
        }
    }
    if (t < 64) {
        const int e  = t;
        const int gs = src[e0 + e];
        const int gd = dst[e0 + e];
        float dx = coord[(size_t)gs * 3 + 0] - coord[(size_t)gd * 3 + 0];
        float dy = coord[(size_t)gs * 3 + 1] - coord[(size_t)gd * 3 + 1];
        float dz = coord[(size_t)gs * 3 + 2] - coord[(size_t)gd * 3 + 2];
        float radial = dx * dx + dy * dy + dz * dz;
        sRad[e] = radial;
        float inv = 1.0f / (sqrtf(radial) + EPS_F);
        sXd[e][0] = dx * inv; sXd[e][1] = dy * inv; sXd[e][2] = dz * inv;
        sDst[e] = gd;
    }
    __syncthreads();

    const int lane = t & 63;
    const int w    = t >> 6;
    const int lr   = lane & 15;
    const int lk   = lane >> 4;

    f32x4 acc[4];
    {
#pragma unroll
        for (int nt = 0; nt < 4; ++nt) {
            const int col = nt * 16 + lr;
            const float b0 = be1[col];
            const float wr = We1[128 * 64 + col];
#pragma unroll
            for (int r = 0; r < 4; ++r)
                acc[nt][r] = b0 + sRad[w * 16 + lk * 4 + r] * wr;
        }
        const int arow = w * 16 + lr;
#pragma unroll
        for (int ks = 0; ks < 4; ++ks) {
            bf16x8 a = *(const bf16x8*)&sFb[arow * STR1 + ks * 32 + lk * 8];
#pragma unroll
            for (int nt = 0; nt < 4; ++nt) {
                bf16x8 b = *(const bf16x8*)&We1p[(nt * 16 + lr) * 128 + ks * 32 + lk * 8];
                acc[nt] = __builtin_amdgcn_mfma_f32_16x16x32_bf16(a, b, acc[nt], 0, 0, 0);
            }
        }
#pragma unroll
        for (int nt = 0; nt < 4; ++nt) {
            const int col = nt * 16 + lr;
#pragma unroll
            for (int r = 0; r < 4; ++r) {
                const int row = w * 16 + lk * 4 + r;
                sT[row * STR2 + col] = (__bf16)silu_f(acc[nt][r]);
            }
        }
    }
    __syncthreads();
    {
#pragma unroll
        for (int nt = 0; nt < 4; ++nt) {
            const float b0 = be2[nt * 16 + lr];
            acc[nt] = (f32x4){b0, b0, b0, b0};
        }
        const int arow = w * 16 + lr;
#pragma unroll
        for (int ks = 0; ks < 2; ++ks) {
            bf16x8 a = *(const bf16x8*)&sT[arow * STR2 + ks * 32 + lk * 8];
#pragma unroll
            for (int nt = 0; nt < 4; ++nt) {
                bf16x8 b = *(const bf16x8*)&We2p[(nt * 16 + lr) * 64 + ks * 32 + lk * 8];
                acc[nt] = __builtin_amdgcn_mfma_f32_16x16x32_bf16(a, b, acc[nt], 0, 0, 0);
            }
        }
#pragma unroll
        for (int nt = 0; nt < 4; ++nt) {
            const int col = nt * 16 + lr;
#pragma unroll
            for (int r = 0; r < 4; ++r) {
                const int row = w * 16 + lk * 4 + r;
                const float v = silu_f(acc[nt][r]);
                sM[row * STR2 + col] = (__bf16)v;
                atomicAdd(&h_neigh[(size_t)sDst[row] * 64 + col], v);
            }
        }
    }
    __syncthreads();
    {
#pragma unroll
        for (int nt = 0; nt < 4; ++nt) {
            const float b0 = bx1[nt * 16 + lr];
            acc[nt] = (f32x4){b0, b0, b0, b0};
        }
        const int arow = w * 16 + lr;
#pragma unroll
        for (int ks = 0; ks < 2; ++ks) {
            bf16x8 a = *(const bf16x8*)&sM[arow * STR2 + ks * 32 + lk * 8];
#pragma unroll
            for (int nt = 0; nt < 4; ++nt) {
                bf16x8 b = *(const bf16x8*)&Wx1p[(nt * 16 + lr) * 64 + ks * 32 + lk * 8];
                acc[nt] = __builtin_amdgcn_mfma_f32_16x16x32_bf16(a, b, acc[nt], 0, 0, 0);
            }
        }
        float p[4] = {0.f, 0.f, 0.f, 0.f};
#pragma unroll
        for (int nt = 0; nt < 4; ++nt) {
            const float wv = Wx2[nt * 16 + lr];
#pragma unroll
            for (int r = 0; r < 4; ++r)
                p[r] += silu_f(acc[nt][r]) * wv;
        }
#pragma unroll
        for (int off = 1; off < 16; off <<= 1)
#pragma unroll
            for (int r = 0; r < 4; ++r)
                p[r] += __shfl_xor(p[r], off);
        if (lr == 0) {
#pragma unroll
            for (int r = 0; r < 4; ++r) {
                const int e  = w * 16 + lk * 4 + r;
                const int gd = sDst[e];
                const float coef = p[r];
                atomicAdd(&x_sum[(size_t)gd * 3 + 0], coef * sXd[e][0]);
                atomicAdd(&x_sum[(size_t)gd * 3 + 1], coef * sXd[e][1]);
                atomicAdd(&x_sum[(size_t)gd * 3 + 2], coef * sXd[e][2]);
                atomicAdd(&deg[gd], 1.0f);
            }
        }
    }
}

template<int KDIM>
__device__ __forceinline__ void tile_gemm64(const float* __restrict__ A, int astride,
                                            const float* __restrict__ B,
                                            float acc[4][4], int t)
{
    const int tx = t & 15;
    const int ty = t >> 4;
#pragma unroll
    for (int i = 0; i < 4; ++i)
#pragma unroll
        for (int j = 0; j < 4; ++j) acc[i][j] = 0.0f;

    for (int k = 0; k < KDIM; k += 4) {
        float bv[4][4];
#pragma unroll
        for (int kk = 0; kk < 4; ++kk) {
            float4 bq = *(const float4*)(B + (size_t)(k + kk) * 64 + tx * 4);
            bv[kk][0] = bq.x; bv[kk][1] = bq.y; bv[kk][2] = bq.z; bv[kk][3] = bq.w;
        }
#pragma unroll
        for (int i = 0; i < 4; ++i) {
            float4 aq = *(const float4*)(A + (size_t)(ty * 4 + i) * astride + k);
            float av[4] = {aq.x, aq.y, aq.z, aq.w};
#pragma unroll
            for (int kk = 0; kk < 4; ++kk)
#pragma unroll
                for (int j = 0; j < 4; ++j)
                    acc[i][j] = fmaf(av[kk], bv[kk][j], acc[i][j]);
        }
    }
}

__global__ __launch_bounds__(256, 2)
void egnn_node_kernel(const float* __restrict__ node_feat,
                      const float* __restrict__ coord,
                      const float* __restrict__ Wn1, const float* __restrict__ bn1,
                      const float* __restrict__ Wn2, const float* __restrict__ bn2,
                      const float* __restrict__ h_neigh,
                      const float* __restrict__ x_sum,
                      const float* __restrict__ deg,
                      float* __restrict__ out_h,
                      float* __restrict__ out_x)
{
    __shared__ float sF[64][132];
    __shared__ float sT2[64][68];

    const int t  = threadIdx.x;
    const int n0 = blockIdx.x * 64;

    {
        const int r = t >> 2;
        const int sub = t & 3;
        const int n = n0 + r;
        if (n < N_NODES) {
            const float* rowsrc = (sub < 2) ? (node_feat + (size_t)n * 64 + sub * 32)
                                            : (h_neigh  + (size_t)n * 64 + (sub - 2) * 32);
#pragma unroll
            for (int q = 0; q < 8; ++q)
                *(float4*)&sF[r][sub * 32 + 4 * q] = *(const float4*)(rowsrc + 4 * q);
        } else {
#pragma unroll
            for (int q = 0; q < 8; ++q)
                *(float4*)&sF[r][sub * 32 + 4 * q] = make_float4(0.f, 0.f, 0.f, 0.f);
        }
    }
    __syncthreads();

    const int tx = t & 15;
    const int ty = t >> 4;
    float acc[4][4];

    tile_gemm64<128>(&sF[0][0], 132, Wn1, acc, t);
    {
        float4 bq = *(const float4*)(bn1 + tx * 4);
        float bv[4] = {bq.x, bq.y, bq.z, bq.w};
#pragma unroll
        for (int i = 0; i < 4; ++i) {
            float4 o;
            o.x = silu_f(acc[i][0] + bv[0]);
            o.y = silu_f(acc[i][1] + bv[1]);
            o.z = silu_f(acc[i][2] + bv[2]);
            o.w = silu_f(acc[i][3] + bv[3]);
            *(float4*)&sT2[ty * 4 + i][tx * 4] = o;
        }
    }
    __syncthreads();

    tile_gemm64<64>(&sT2[0][0], 68, Wn2, acc, t);
    {
        float4 bq = *(const float4*)(bn2 + tx * 4);
        float bv[4] = {bq.x, bq.y, bq.z, bq.w};
#pragma unroll
        for (int i = 0; i < 4; ++i) {
            const int n = n0 + ty * 4 + i;
            if (n < N_NODES) {
                float4 o;
                o.x = acc[i][0] + bv[0];
                o.y = acc[i][1] + bv[1];
                o.z = acc[i][2] + bv[2];
                o.w = acc[i][3] + bv[3];
                *(float4*)&out_h[(size_t)n * 64 + tx * 4] = o;
            }
        }
    }

    if (t < 64) {
        const int n = n0 + t;
        if (n < N_NODES) {
            const float d = deg[n];
            const float inv = 1.0f / fmaxf(d, 1.0f);
#pragma unroll
            for (int c = 0; c < 3; ++c)
                out_x[(size_t)n * 3 + c] = coord[(size_t)n * 3 + c]
                                         + x_sum[(size_t)n * 3 + c] * inv;
        }
    }
}

// ================= host =================
extern "C" void kernel_launch(void* const* d_in, const int* in_sizes, int n_in,
                              void* d_out, int out_size, void* d_ws, size_t ws_size,
                              hipStream_t stream) {
    const float* node_feat = (const float*)d_in[0];
    const float* coord     = (const float*)d_in[1];
    const int*   src       = (const int*)d_in[2];
    const int*   dst       = (const int*)d_in[3];
    const float* We1 = (const float*)d_in[4];
    const float* be1 = (const float*)d_in[5];
    const float* We2 = (const float*)d_in[6];
    const float* be2 = (const float*)d_in[7];
    const float* Wx1 = (const float*)d_in[8];
    const float* bx1 = (const float*)d_in[9];
    const float* Wx2 = (const float*)d_in[10];
    const float* Wn1 = (const float*)d_in[11];
    const float* bn1 = (const float*)d_in[12];
    const float* Wn2 = (const float*)d_in[13];
    const float* bn2 = (const float*)d_in[14];

    float* out_h = (float*)d_out;
    float* out_x = out_h + (size_t)N_NODES * 64;

    // ---- workspace layout (fast path) ----
    char* ws = (char*)d_ws;
    size_t off = 0;
    auto take = [&](size_t bytes) { char* p = ws + off; off = (off + bytes + 255) & ~(size_t)255; return p; };

    float*  h_neigh = (float*)take((size_t)N_NODES * 64 * 4);   // zeroed
    float*  xs      = (float*)take((size_t)N_NODES * 16);       // zeroed (contiguous)
    int2*   edge_p  = (int2*)take((size_t)N_EDGES * 8);
    float4* geom    = (float4*)take((size_t)N_EDGES * 16);
    __bf16* nfb     = (__bf16*)take((size_t)N_NODES * 64 * 2);
    __bf16* P1b     = (__bf16*)take((size_t)N_NODES * 64 * 2);
    __bf16* P2b     = (__bf16*)take((size_t)N_NODES * 64 * 2);
    int*    offsets = (int*)take((size_t)(N_NODES + 1) * 4);
    int*    cursor  = (int*)take((size_t)N_NODES * 4);
    int*    cnt     = (int*)take((size_t)N_NODES * 4);
    int*    excl    = (int*)take((size_t)N_NODES * 4);
    int*    bsum    = (int*)take(1024);
    int*    bpre    = (int*)take(1024);
    __bf16* We1p    = (__bf16*)take(64 * 128 * 2);
    __bf16* We2p    = (__bf16*)take(64 * 64 * 2);
    __bf16* Wx1p    = (__bf16*)take(64 * 64 * 2);
    __bf16* Wn1p    = (__bf16*)take(64 * 128 * 2);
    __bf16* Wn2p    = (__bf16*)take(64 * 64 * 2);
    const size_t needed = off;

    if (ws_size >= needed) {
        hipMemsetAsync(h_neigh, 0, (size_t)N_NODES * 64 * 4 + (size_t)N_NODES * 16, stream);
        hipMemsetAsync(cnt, 0, (size_t)N_NODES * 4, stream);

        prep_kernel<<<2048, 256, 0, stream>>>(node_feat, We1, We2, Wx1, Wn1, Wn2,
                                              nfb, We1p, We2p, Wx1p, Wn1p, Wn2p);
        pgemm_kernel<<<(N_NODES + 63) / 64, 256, 0, stream>>>(nfb, We1p, be1, P1b, P2b);

        const int nb = (N_NODES + 255) / 256;   // 196
        hist_kernel<<<(N_EDGES + 255) / 256, 256, 0, stream>>>(dst, cnt);
        scan1_kernel<<<nb, 256, 0, stream>>>(cnt, excl, bsum);
        scan2_kernel<<<1, 256, 0, stream>>>(bsum, bpre, nb);
        scan3_kernel<<<nb, 256, 0, stream>>>(excl, bpre, offsets, cursor);
        fill_v3<<<(N_EDGES + 255) / 256, 256, 0, stream>>>(src, dst, coord, cursor,
                                                           edge_p, geom);

        egnn_edge_mfma_v6<<<N_EDGES / 64, 256, 0, stream>>>(
            P1b, P2b, edge_p, geom,
            We1, be2, bx1, Wx2,
            We2p, Wx1p,
            h_neigh, xs);

        egnn_node_mfma_v5<<<(N_NODES + 63) / 64, 256, 0, stream>>>(
            nfb, coord, offsets, h_neigh, (const float4*)xs,
            bn1, bn2, Wn1p, Wn2p, out_h, out_x);
    } else {
        // ======== fallback: atomic path ========
        float* fh_neigh = (float*)d_ws;
        float* fx_sum   = fh_neigh + (size_t)N_NODES * 64;
        float* fdeg     = fx_sum + (size_t)N_NODES * 3;
        __bf16* fnfb    = (__bf16*)(fdeg + N_NODES);
        __bf16* fWe1p   = fnfb + (size_t)N_NODES * 64;
        __bf16* fWe2p   = fWe1p + 64 * 128;
        __bf16* fWx1p   = fWe2p + 64 * 64;
        __bf16* fWn1p   = fWx1p + 64 * 64;
        __bf16* fWn2p   = fWn1p + 64 * 128;

        hipMemsetAsync(d_ws, 0, (size_t)N_NODES * 68 * sizeof(float), stream);
        prep_kernel<<<2048, 256, 0, stream>>>(node_feat, We1, We2, Wx1, Wn1, Wn2,
                                              fnfb, fWe1p, fWe2p, fWx1p, fWn1p, fWn2p);
        egnn_edge_mfma_atomic<<<N_EDGES / 64, 256, 0, stream>>>(
            node_feat, coord, src, dst,
            We1, be1, be2, bx1, Wx2,
            fWe1p, fWe2p, fWx1p,
            fh_neigh, fx_sum, fdeg);
        egnn_node_kernel<<<(N_NODES + 63) / 64, 256, 0, stream>>>(
            node_feat, coord, Wn1, bn1, Wn2, bn2,
            fh_neigh, fx_sum, fdeg, out_h, out_x);
    }
}